// Round 2
// baseline (630.341 us; speedup 1.0000x reference)
//
#include <hip/hip_runtime.h>
#include <hip/hip_bf16.h>
#include <math.h>

#define N_NODES 100000
#define N_EDGES 1600000
#define F_INN   32
#define F_EE    8
#define HD      64
#define E_SL    (N_EDGES + N_NODES)   // edges + self loops
#define NEG_SLOPE 0.2f
#define MEAN_BLOCKS 256
#define SCAN_BLOCK 512
#define N_SCAN_BLOCKS ((N_NODES + SCAN_BLOCK - 1) / SCAN_BLOCK)   // 196
#define SHARD_W (N_NODES / 8)         // 12500 nodes per XCD shard
#define NPB 32                        // nodes per block in dense kernels (3125 blocks)

// two-level counting sort: 8 XCD shards x 10 sub-buckets = 80 fine buckets.
// Fine buckets shrink the scatter's dirty L2 window to ~340KB (vs 3.4MB with
// 8 shards), so output lines stay resident until fully written — r1 showed 6x
// writeback amplification (168MB vs 27MB ideal) from exactly that thrash.
#define NSUB 10                       // sub-buckets per XCD
#define NBKT 80                       // total fine buckets
#define BKT_W (N_NODES / NBKT)        // 1250 nodes per bucket
#define BKT_NBLK 800
#define BKT_CHUNK (N_EDGES / BKT_NBLK)   // 2000 edges per block
#define BKT_CAP 22000                 // mean 20000 + 14 sigma — overflow prob ~0
#define SCAT_BLOCKS 2048

// ---------- helpers ----------
__device__ __forceinline__ float waveReduceSum(float v) {
#pragma unroll
    for (int off = 32; off > 0; off >>= 1) v += __shfl_down(v, off, 64);
    return v;
}
__device__ __forceinline__ float bf_lo(uint u) { return __uint_as_float(u << 16); }
__device__ __forceinline__ float bf_hi(uint u) { return __uint_as_float(u & 0xffff0000u); }
__device__ __forceinline__ uint pack_bf2(float a, float b) {
    __hip_bfloat16 ha = __float2bfloat16(a), hb = __float2bfloat16(b);
    unsigned short ua, ub;
    __builtin_memcpy(&ua, &ha, 2); __builtin_memcpy(&ub, &hb, 2);
    return (uint)ua | ((uint)ub << 16);
}

// ---------- K1: we_vec[l][k] = dot(edge_w[l][k,:], att_edge[l,:]) ----------
__global__ void k_init_small(const float* __restrict__ edge_w, const float* __restrict__ att_edge,
                             float* __restrict__ we_vec) {
    int t = threadIdx.x;
    if (t < 16) {
        int l = t >> 3, k = t & 7;
        const float* We = edge_w + l * F_EE * HD + k * HD;
        const float* ae = att_edge + l * HD;
        float s = 0.0f;
#pragma unroll
        for (int j = 0; j < HD; ++j) s += We[j] * ae[j];
        we_vec[l * 8 + k] = s;
    }
}

// ---------- K1b: fold encoder into layer-0 projection: Wc = enc_w@W0, bc = enc_b@W0 ----------
__global__ __launch_bounds__(256) void k_fuse_w(const float* __restrict__ enc_w,
                                                const float* __restrict__ enc_b,
                                                const float* __restrict__ W0,
                                                float* __restrict__ Wc, float* __restrict__ bc) {
    int t = threadIdx.x;
    for (int idx = t; idx < F_INN * HD; idx += 256) {
        int r = idx >> 6, c = idx & 63;
        float s = 0.0f;
#pragma unroll
        for (int k = 0; k < HD; ++k) s += enc_w[r * HD + k] * W0[k * HD + c];
        Wc[idx] = s;
    }
    if (t < HD) {
        float s = 0.0f;
#pragma unroll
        for (int k = 0; k < HD; ++k) s += enc_b[k] * W0[k * HD + t];
        bc[t] = s;
    }
}

// ---------- K2a: fused — mean partials, deg histogram, edge records {src, packed bf16 ed01} ----------
__global__ __launch_bounds__(256) void k_mean_edterm(const float* __restrict__ eattr,
                                                     const int* __restrict__ src,
                                                     const int* __restrict__ dst,
                                                     const float* __restrict__ we_vec,
                                                     float* __restrict__ partials,
                                                     int2* __restrict__ rec_agg,
                                                     int* __restrict__ deg) {
    __shared__ float sw[16];
    int t = threadIdx.x;
    if (t < 16) sw[t] = we_vec[t];
    __syncthreads();
    float p[8];
#pragma unroll
    for (int k = 0; k < 8; ++k) p[k] = 0.0f;
    for (int e = blockIdx.x * blockDim.x + t; e < N_EDGES; e += gridDim.x * blockDim.x) {
        const float4* row = (const float4*)(eattr + (size_t)e * F_EE);
        float4 r0 = row[0], r1 = row[1];
        p[0] += r0.x; p[1] += r0.y; p[2] += r0.z; p[3] += r0.w;
        p[4] += r1.x; p[5] += r1.y; p[6] += r1.z; p[7] += r1.w;
        float ed0 = r0.x * sw[0] + r0.y * sw[1] + r0.z * sw[2] + r0.w * sw[3]
                  + r1.x * sw[4] + r1.y * sw[5] + r1.z * sw[6] + r1.w * sw[7];
        float ed1 = r0.x * sw[8] + r0.y * sw[9] + r0.z * sw[10] + r0.w * sw[11]
                  + r1.x * sw[12] + r1.y * sw[13] + r1.z * sw[14] + r1.w * sw[15];
        rec_agg[e] = make_int2(src[e], (int)pack_bf2(ed0, ed1));
        atomicAdd(&deg[dst[e]], 1);   // fused histogram (deg pre-initialized to 1)
    }
#pragma unroll
    for (int k = 0; k < 8; ++k) p[k] = waveReduceSum(p[k]);
    int wave = t >> 6;
    if ((t & 63) == 0) {
        float* dstp = partials + ((size_t)blockIdx.x * 4 + wave) * 8;
#pragma unroll
        for (int k = 0; k < 8; ++k) dstp[k] = p[k];
    }
}

// ---------- K2b: finish mean; ltp = packed bf16 {loop_term0, loop_term1} ----------
__global__ __launch_bounds__(256) void k_mean_final(const float* __restrict__ partials,
                                                    const float* __restrict__ we_vec,
                                                    uint* __restrict__ ltp) {
    __shared__ float red[256];
    __shared__ float mean8[8];
    __shared__ float lt[2];
    int t = threadIdx.x;
    int k = t & 7;
    int chunk = t >> 3;
    float s = 0.0f;
    for (int i = chunk; i < MEAN_BLOCKS * 4; i += 32) s += partials[(size_t)i * 8 + k];
    red[t] = s;
    __syncthreads();
    if (t < 8) {
        float acc = 0.0f;
#pragma unroll
        for (int c = 0; c < 32; ++c) acc += red[c * 8 + t];
        mean8[t] = acc * (1.0f / N_EDGES);
    }
    __syncthreads();
    if (t < 2) {
        float acc = 0.0f;
#pragma unroll
        for (int kk = 0; kk < 8; ++kk) acc += mean8[kk] * we_vec[t * 8 + kk];
        lt[t] = acc;
    }
    __syncthreads();
    if (t == 0) ltp[0] = pack_bf2(lt[0], lt[1]);
}

// ---------- CSR build ----------
__global__ void k_deg_init(int* __restrict__ deg, int* __restrict__ bkt_cnt) {
    int i = blockIdx.x * 256 + threadIdx.x;
    if (i < N_NODES) deg[i] = 1;   // self-loop
    if (i < NBKT) bkt_cnt[i] = 0;  // block 0 zeroes the bucket counters
}

__global__ __launch_bounds__(SCAN_BLOCK) void k_scan1(const int* __restrict__ deg,
                                                      int* __restrict__ row_ptr,
                                                      int* __restrict__ blk_sums) {
    __shared__ int sd[SCAN_BLOCK];
    int t = threadIdx.x;
    int i = blockIdx.x * SCAN_BLOCK + t;
    int v = (i < N_NODES) ? deg[i] : 0;
    sd[t] = v;
    for (int off = 1; off < SCAN_BLOCK; off <<= 1) {
        __syncthreads();
        int x = (t >= off) ? sd[t - off] : 0;
        __syncthreads();
        sd[t] += x;
    }
    __syncthreads();
    if (i < N_NODES) row_ptr[i] = sd[t] - v;
    if (t == SCAN_BLOCK - 1) blk_sums[blockIdx.x] = sd[t];
}

__global__ __launch_bounds__(256) void k_scan2(int* __restrict__ blk_sums,
                                               int* __restrict__ blk_off) {
    __shared__ int sd[256];
    int t = threadIdx.x;
    int v = (t < N_SCAN_BLOCKS) ? blk_sums[t] : 0;
    sd[t] = v;
    for (int off = 1; off < 256; off <<= 1) {
        __syncthreads();
        int x = (t >= off) ? sd[t - off] : 0;
        __syncthreads();
        sd[t] += x;
    }
    __syncthreads();
    if (t < N_SCAN_BLOCKS) blk_off[t] = sd[t] - v;
}

// finalize row_ptr, init cursor, write self-loop records directly into agg/dec
__global__ void k_scan3(int* __restrict__ row_ptr, const int* __restrict__ blk_off,
                        const int* __restrict__ deg, int* __restrict__ cursor,
                        const uint* __restrict__ ltp,
                        int2* __restrict__ agg, int2* __restrict__ dec) {
    int i = blockIdx.x * 256 + threadIdx.x;
    if (i < N_NODES) {
        int r = row_ptr[i] + blk_off[i / SCAN_BLOCK];
        row_ptr[i] = r;
        cursor[i] = r;
        int last = r + deg[i] - 1;          // self-loop goes in the LAST slot
        agg[last] = make_int2(i, (int)ltp[0]);
        dec[last] = make_int2(i, -1);
    }
    if (i == 0) row_ptr[N_NODES] = E_SL;
}

// kA: counting-sort bucketing — read dst ONCE, scatter (edge_id, local_dst)
// into 80 fine buckets (10 per XCD). Two-phase per block: LDS histogram ->
// one global atomic per (block,bucket) -> LDS-cursor scatter. Chunk stays
// L1-resident for the second read.
__global__ __launch_bounds__(256) void k_bucket(const int* __restrict__ dst,
                                                int* __restrict__ bkt_e,
                                                unsigned short* __restrict__ bkt_d,
                                                int* __restrict__ bkt_cnt) {
    __shared__ int hist[NBKT];
    __shared__ int base[NBKT];
    int t = threadIdx.x;
    if (t < NBKT) hist[t] = 0;
    __syncthreads();
    int e0 = blockIdx.x * BKT_CHUNK;
    for (int i = t; i < BKT_CHUNK; i += 256) {
        int d = dst[e0 + i];
        atomicAdd(&hist[d / BKT_W], 1);
    }
    __syncthreads();
    if (t < NBKT) base[t] = atomicAdd(&bkt_cnt[t], hist[t]);
    __syncthreads();
    if (t < NBKT) hist[t] = 0;   // reuse as intra-block cursor
    __syncthreads();
    for (int i = t; i < BKT_CHUNK; i += 256) {
        int e = e0 + i;
        int d = dst[e];
        int b = d / BKT_W;
        int pos = base[b] + atomicAdd(&hist[b], 1);
        bkt_e[(size_t)b * BKT_CAP + pos] = e;
        // local dst relative to the XCD shard (fits u16: < 12500)
        bkt_d[(size_t)b * BKT_CAP + pos] = (unsigned short)(d - (b / NSUB) * SHARD_W);
    }
}

// kB: fused scatter+build. XCD-pinned blocks walk their XCD's 10 sub-buckets
// IN ORDER — the dirty agg/dec window per sub-bucket is ~340KB (vs 3.4MB for
// a whole shard), so output lines stay L2-resident until fully written.
// rec_agg gathered with NT loads (L3-resident; keeps them out of L2).
__global__ __launch_bounds__(256) void k_scatter_build(const int* __restrict__ bkt_cnt,
                                                       const int* __restrict__ bkt_e,
                                                       const unsigned short* __restrict__ bkt_d,
                                                       const int2* __restrict__ rec_agg,
                                                       int* __restrict__ cursor,
                                                       int2* __restrict__ agg,
                                                       int2* __restrict__ dec) {
    int xcd = blockIdx.x & 7;
    int lo = xcd * SHARD_W;
    int bid = blockIdx.x >> 3;                // block index within XCD
    int stride = (SCAT_BLOCKS / 8) * 256;     // threads per XCD
    for (int k = 0; k < NSUB; ++k) {
        int b = xcd * NSUB + k;
        int cnt = bkt_cnt[b];
        const int* be = bkt_e + (size_t)b * BKT_CAP;
        const unsigned short* bd = bkt_d + (size_t)b * BKT_CAP;
        int npair = cnt >> 1;
        for (int i = bid * 256 + threadIdx.x; i < npair; i += stride) {
            long long ee = __builtin_nontemporal_load((const long long*)be + i);
            uint dd = __builtin_nontemporal_load((const uint*)bd + i);
            int e0v = (int)(uint)ee, e1v = (int)(ee >> 32);
            int d0 = lo + (int)(dd & 0xffffu);
            int d1 = lo + (int)(dd >> 16);
            int pos0 = atomicAdd(&cursor[d0], 1);
            int pos1 = atomicAdd(&cursor[d1], 1);
            long long r0 = __builtin_nontemporal_load((const long long*)rec_agg + e0v);
            long long r1 = __builtin_nontemporal_load((const long long*)rec_agg + e1v);
            int2 ra0 = make_int2((int)(uint)r0, (int)(r0 >> 32));
            int2 ra1 = make_int2((int)(uint)r1, (int)(r1 >> 32));
            agg[pos0] = ra0;
            dec[pos0] = make_int2(ra0.x, e0v);
            agg[pos1] = ra1;
            dec[pos1] = make_int2(ra1.x, e1v);
        }
        if ((cnt & 1) && bid == 0 && threadIdx.x == 0) {
            int i = cnt - 1;
            int e = be[i];
            int d = lo + (int)bd[i];
            int pos = atomicAdd(&cursor[d], 1);
            int2 ra = rec_agg[e];
            agg[pos] = ra;
            dec[pos] = make_int2(ra.x, e);
        }
    }
}

// ---------- K3: layer-0 projection xp = x@Wc + bc — weight column in VGPRs, x broadcast via LDS ----------
__global__ __launch_bounds__(256) void k_xp0(const float* __restrict__ x,
                                             const float* __restrict__ Wc,
                                             const float* __restrict__ bc,
                                             const float* __restrict__ a_src,
                                             const float* __restrict__ a_dst,
                                             __hip_bfloat16* __restrict__ xpb,
                                             float* __restrict__ s_src,
                                             float* __restrict__ s_dst) {
    __shared__ float xr[NPB * F_INN];  // 4 KB
    int t = threadIdx.x;
    int j = t & 63, wv = t >> 6;
    float4 w[F_INN / 4];               // 8 VGPR float4s = weight column j
#pragma unroll
    for (int kk = 0; kk < F_INN / 4; ++kk) {
        w[kk].x = Wc[(4 * kk + 0) * HD + j];
        w[kk].y = Wc[(4 * kk + 1) * HD + j];
        w[kk].z = Wc[(4 * kk + 2) * HD + j];
        w[kk].w = Wc[(4 * kk + 3) * HD + j];
    }
    int n0 = blockIdx.x * NPB;
    ((float4*)xr)[t] = ((const float4*)(x + (size_t)n0 * F_INN))[t];  // 256*16B = 4KB exact
    __syncthreads();
    float asj = a_src[j], adj = a_dst[j], bcj = bc[j];
    for (int n = wv; n < NPB; n += 4) {
        const float4* hx = (const float4*)&xr[n * F_INN];
        float acc = bcj;
#pragma unroll
        for (int kk = 0; kk < F_INN / 4; ++kk) {
            float4 hv = hx[kk];   // wave-uniform broadcast ds_read_b128
            acc += hv.x * w[kk].x + hv.y * w[kk].y + hv.z * w[kk].z + hv.w * w[kk].w;
        }
        int node = n0 + n;
        xpb[(size_t)node * HD + j] = __float2bfloat16(acc);
        float ts = waveReduceSum(acc * asj);
        float td = waveReduceSum(acc * adj);
        if (j == 0) { s_src[node] = ts; s_dst[node] = td; }
    }
}

// ---------- K4: xp(bf16) = h @ W (layer 1) — weight column in VGPRs ----------
__global__ __launch_bounds__(256) void k_xp(const float* __restrict__ h, const float* __restrict__ W,
                                            const float* __restrict__ a_src, const float* __restrict__ a_dst,
                                            __hip_bfloat16* __restrict__ xpb, float* __restrict__ s_src,
                                            float* __restrict__ s_dst) {
    __shared__ float hr[NPB * HD];     // 8 KB
    int t = threadIdx.x;
    int j = t & 63, wv = t >> 6;
    float4 w[HD / 4];                  // 16 float4s = 64 VGPRs
#pragma unroll
    for (int kk = 0; kk < HD / 4; ++kk) {
        w[kk].x = W[(4 * kk + 0) * HD + j];
        w[kk].y = W[(4 * kk + 1) * HD + j];
        w[kk].z = W[(4 * kk + 2) * HD + j];
        w[kk].w = W[(4 * kk + 3) * HD + j];
    }
    int n0 = blockIdx.x * NPB;
#pragma unroll
    for (int i = 0; i < 2; ++i)
        ((float4*)hr)[t + i * 256] = ((const float4*)(h + (size_t)n0 * HD))[t + i * 256];
    __syncthreads();
    float asj = a_src[j], adj = a_dst[j];
    for (int n = wv; n < NPB; n += 4) {
        const float4* hx = (const float4*)&hr[n * HD];
        float acc = 0.0f;
#pragma unroll
        for (int kk = 0; kk < HD / 4; ++kk) {
            float4 hv = hx[kk];   // broadcast ds_read_b128
            acc += hv.x * w[kk].x + hv.y * w[kk].y + hv.z * w[kk].z + hv.w * w[kk].w;
        }
        int node = n0 + n;
        xpb[(size_t)node * HD + j] = __float2bfloat16(acc);
        float ts = waveReduceSum(acc * asj);
        float td = waveReduceSum(acc * adj);
        if (j == 0) { s_src[node] = ts; s_dst[node] = td; }
    }
}

// ---------- K5: gather-aggregate — wave/node, 16-lane groups, 8 edges/iter in flight ----------
template <int LAYER>
__global__ __launch_bounds__(256) void k_aggregate(const int* __restrict__ row_ptr,
                                                   const int2* __restrict__ agg,
                                                   const float* __restrict__ s_src,
                                                   const float* __restrict__ s_dst,
                                                   const uint2* __restrict__ xpr,   // bf16 x4 per lane
                                                   const float* __restrict__ bias,
                                                   float* __restrict__ h) {
    int t = threadIdx.x;
    int node = blockIdx.x * 4 + (t >> 6);    // grid exact: N/4
    int lane = t & 63;
    int g = lane >> 4, li = lane & 15;
    int start = row_ptr[node], end = row_ptr[node + 1];
    float sd = s_dst[node];
    float ax = 0.0f, ay = 0.0f, az = 0.0f, aw = 0.0f, den = 0.0f;
    int i = start;
    for (; i + 8 <= end; i += 8) {
        int2 r0 = agg[i + g];
        int2 r1 = agg[i + 4 + g];
        int sp0 = r0.x, sp1 = r1.x;
        uint2 u0 = xpr[(size_t)sp0 * 16 + li];
        uint2 u1 = xpr[(size_t)sp1 * 16 + li];
        float a0 = s_src[sp0] + sd + (LAYER == 0 ? bf_lo((uint)r0.y) : bf_hi((uint)r0.y));
        float a1 = s_src[sp1] + sd + (LAYER == 0 ? bf_lo((uint)r1.y) : bf_hi((uint)r1.y));
        a0 = a0 > 0.0f ? a0 : NEG_SLOPE * a0;
        a1 = a1 > 0.0f ? a1 : NEG_SLOPE * a1;
        float ex0 = __expf(a0), ex1 = __expf(a1);
        den += ex0 + ex1;
        ax += ex0 * bf_lo(u0.x) + ex1 * bf_lo(u1.x);
        ay += ex0 * bf_hi(u0.x) + ex1 * bf_hi(u1.x);
        az += ex0 * bf_lo(u0.y) + ex1 * bf_lo(u1.y);
        aw += ex0 * bf_hi(u0.y) + ex1 * bf_hi(u1.y);
    }
    for (; i < end; i += 4) {
        int idx = i + g;
        bool valid = idx < end;
        int2 r = agg[valid ? idx : end - 1];
        int sp = r.x;
        uint2 u = xpr[(size_t)sp * 16 + li];
        float a = s_src[sp] + sd + (LAYER == 0 ? bf_lo((uint)r.y) : bf_hi((uint)r.y));
        a = a > 0.0f ? a : NEG_SLOPE * a;
        float ex = valid ? __expf(a) : 0.0f;
        den += ex;
        ax += ex * bf_lo(u.x);
        ay += ex * bf_hi(u.x);
        az += ex * bf_lo(u.y);
        aw += ex * bf_hi(u.y);
    }
    den += __shfl_down(den, 32, 64); ax += __shfl_down(ax, 32, 64);
    ay  += __shfl_down(ay, 32, 64); az += __shfl_down(az, 32, 64);
    aw  += __shfl_down(aw, 32, 64);
    den += __shfl_down(den, 16, 64); ax += __shfl_down(ax, 16, 64);
    ay  += __shfl_down(ay, 16, 64); az += __shfl_down(az, 16, 64);
    aw  += __shfl_down(aw, 16, 64);
    if (lane < 16) {
        float inv = 1.0f / (den + 1e-16f);
        float4 b4 = ((const float4*)bias)[li];
        float4 v;
        v.x = fmaxf(ax * inv + b4.x, 0.0f);
        v.y = fmaxf(ay * inv + b4.y, 0.0f);
        v.z = fmaxf(az * inv + b4.z, 0.0f);
        v.w = fmaxf(aw * inv + b4.w, 0.0f);
        ((float4*)(h + (size_t)node * HD))[li] = v;
    }
}

// ---------- K6: u1(bf16)=h@W1a, u2(f32)=h@W1b — both weight columns in VGPRs ----------
// (u2 aliases h: tile staged to LDS before any write)
__global__ __launch_bounds__(256) void k_umm(const float* __restrict__ h, const float* __restrict__ w1,
                                             __hip_bfloat16* __restrict__ u1b, float* __restrict__ u2) {
    __shared__ float hr[NPB * HD];     // 8 KB
    int t = threadIdx.x;
    int j = t & 63, wv = t >> 6;
    float4 wa[HD / 4], wb[HD / 4];     // 128 VGPRs
#pragma unroll
    for (int kk = 0; kk < HD / 4; ++kk) {
        wa[kk].x = w1[(4 * kk + 0) * HD + j];
        wa[kk].y = w1[(4 * kk + 1) * HD + j];
        wa[kk].z = w1[(4 * kk + 2) * HD + j];
        wa[kk].w = w1[(4 * kk + 3) * HD + j];
        wb[kk].x = w1[(HD + 4 * kk + 0) * HD + j];
        wb[kk].y = w1[(HD + 4 * kk + 1) * HD + j];
        wb[kk].z = w1[(HD + 4 * kk + 2) * HD + j];
        wb[kk].w = w1[(HD + 4 * kk + 3) * HD + j];
    }
    int n0 = blockIdx.x * NPB;
#pragma unroll
    for (int i = 0; i < 2; ++i)
        ((float4*)hr)[t + i * 256] = ((const float4*)(h + (size_t)n0 * HD))[t + i * 256];
    __syncthreads();
    for (int n = wv; n < NPB; n += 4) {
        const float4* hx = (const float4*)&hr[n * HD];
        float a1 = 0.0f, a2 = 0.0f;
#pragma unroll
        for (int kk = 0; kk < HD / 4; ++kk) {
            float4 hv = hx[kk];   // broadcast ds_read_b128
            a1 += hv.x * wa[kk].x + hv.y * wa[kk].y + hv.z * wa[kk].z + hv.w * wa[kk].w;
            a2 += hv.x * wb[kk].x + hv.y * wb[kk].y + hv.z * wb[kk].z + hv.w * wb[kk].w;
        }
        int node = n0 + n;
        u1b[(size_t)node * HD + j] = __float2bfloat16(a1);
        u2[(size_t)node * HD + j] = a2;
    }
}

// ---------- K7: CSR decode — wave/node, 16-lane groups, 8 edges/iter, width-16 reduce ----------
__global__ __launch_bounds__(256) void k_decode_csr(const int* __restrict__ row_ptr,
                                                    const int2* __restrict__ dec,
                                                    const uint2* __restrict__ u1r,  // bf16 x4 per lane
                                                    const float* __restrict__ u2,
                                                    const float* __restrict__ b1,
                                                    const float* __restrict__ w2,
                                                    const float* __restrict__ b2,
                                                    float* __restrict__ out) {
    int t = threadIdx.x;
    int node = blockIdx.x * 4 + (t >> 6);    // grid exact: N/4
    int lane = t & 63;
    int g = lane >> 4, li = lane & 15;
    float4 c4 = ((const float4*)(u2 + (size_t)node * HD))[li];
    float4 b14 = ((const float4*)b1)[li];
    float4 w4 = ((const float4*)w2)[li];
    c4.x += b14.x; c4.y += b14.y; c4.z += b14.z; c4.w += b14.w;
    float bb = b2[0];
    int start = row_ptr[node], end = row_ptr[node + 1];
    int i = start;
    for (; i + 8 <= end; i += 8) {
        int2 e0 = dec[i + g];
        int2 e1 = dec[i + 4 + g];
        uint2 ua = u1r[(size_t)e0.x * 16 + li];
        uint2 ub = u1r[(size_t)e1.x * 16 + li];
        float p0 = fmaxf(bf_lo(ua.x) + c4.x, 0.0f) * w4.x
                 + fmaxf(bf_hi(ua.x) + c4.y, 0.0f) * w4.y
                 + fmaxf(bf_lo(ua.y) + c4.z, 0.0f) * w4.z
                 + fmaxf(bf_hi(ua.y) + c4.w, 0.0f) * w4.w;
        float p1 = fmaxf(bf_lo(ub.x) + c4.x, 0.0f) * w4.x
                 + fmaxf(bf_hi(ub.x) + c4.y, 0.0f) * w4.y
                 + fmaxf(bf_lo(ub.y) + c4.z, 0.0f) * w4.z
                 + fmaxf(bf_hi(ub.y) + c4.w, 0.0f) * w4.w;
#pragma unroll
        for (int off = 8; off > 0; off >>= 1) {
            p0 += __shfl_down(p0, off, 16);
            p1 += __shfl_down(p1, off, 16);
        }
        if (li == 0) {
            if (e0.y >= 0) out[e0.y] = 1.0f / (1.0f + __expf(-(p0 + bb)));
            if (e1.y >= 0) out[e1.y] = 1.0f / (1.0f + __expf(-(p1 + bb)));
        }
    }
    for (; i < end; i += 4) {
        int idx = i + g;
        bool valid = idx < end;
        int2 e = dec[valid ? idx : end - 1];
        uint2 u = u1r[(size_t)e.x * 16 + li];
        float p = fmaxf(bf_lo(u.x) + c4.x, 0.0f) * w4.x
                + fmaxf(bf_hi(u.x) + c4.y, 0.0f) * w4.y
                + fmaxf(bf_lo(u.y) + c4.z, 0.0f) * w4.z
                + fmaxf(bf_hi(u.y) + c4.w, 0.0f) * w4.w;
#pragma unroll
        for (int off = 8; off > 0; off >>= 1) p += __shfl_down(p, off, 16);
        if (li == 0 && valid && e.y >= 0)
            out[e.y] = 1.0f / (1.0f + __expf(-(p + bb)));
    }
}

extern "C" void kernel_launch(void* const* d_in, const int* in_sizes, int n_in,
                              void* d_out, int out_size, void* d_ws, size_t ws_size,
                              hipStream_t stream) {
    const float* x        = (const float*)d_in[0];
    const int*   eidx     = (const int*)d_in[1];
    const float* eattr    = (const float*)d_in[2];
    const float* enc_w    = (const float*)d_in[3];
    const float* enc_b    = (const float*)d_in[4];
    const float* gat_w    = (const float*)d_in[5];
    const float* att_src  = (const float*)d_in[6];
    const float* att_dst  = (const float*)d_in[7];
    const float* edge_w   = (const float*)d_in[8];
    const float* att_edge = (const float*)d_in[9];
    const float* gat_b    = (const float*)d_in[10];
    const float* lp_w1    = (const float*)d_in[11];
    const float* lp_b1    = (const float*)d_in[12];
    const float* lp_w2    = (const float*)d_in[13];
    const float* lp_b2    = (const float*)d_in[14];
    float* out = (float*)d_out;

    const int* src = eidx;
    const int* dst = eidx + N_EDGES;

    // ---- workspace layout ----
    float* ws = (float*)d_ws;
    float*  h       = ws;                                   // N*64 f32 (u2 after k_umm)
    int2*   rec_agg = (int2*)h;                             // E int2 (alias; dead before aggregate<0>)
    // bucket arrays alias the tail of the h region (bytes [12.8MB, 23.4MB) of 25.6MB):
    // live only between k_bucket and k_scatter_build, both before k_aggregate<0> writes h.
    int*    bkt_e   = (int*)(rec_agg + N_EDGES);            // NBKT*BKT_CAP int   (7.04MB)
    unsigned short* bkt_d = (unsigned short*)(bkt_e + NBKT * BKT_CAP);  // NBKT*BKT_CAP u16 (3.52MB)
    __hip_bfloat16* xpb = (__hip_bfloat16*)(h + (size_t)N_NODES * HD);  // N*64 bf16 (u1b after k_umm)
    int2*   agg     = (int2*)((char*)xpb + (size_t)N_NODES * HD * 2);   // E_SL int2 (13.6MB)
    int2*   dec     = agg + E_SL;                           // E_SL int2 (13.6MB)
    float*  fsmall    = (float*)(dec + E_SL);
    float*  s_src     = fsmall;                             // N
    float*  s_dst     = s_src + N_NODES;                    // N
    float*  partials  = s_dst + N_NODES;                    // MEAN_BLOCKS*4*8
    float*  we_vec    = partials + MEAN_BLOCKS * 4 * 8;     // 16
    uint*   ltp       = (uint*)(we_vec + 16);               // 1
    float*  Wc        = (float*)(ltp + 1);                  // 32*64
    float*  bc        = Wc + F_INN * HD;                    // 64
    int*    row_ptr   = (int*)(bc + HD);                    // N+1
    int*    cursor    = row_ptr + N_NODES + 1;              // N
    int*    deg       = cursor + N_NODES;                   // N
    int*    blk_sums  = deg + N_NODES;                      // N_SCAN_BLOCKS
    int*    blk_off   = blk_sums + N_SCAN_BLOCKS;           // N_SCAN_BLOCKS
    int*    bkt_cnt   = blk_off + N_SCAN_BLOCKS;            // NBKT

    const int NB_N256 = (N_NODES + 255) / 256;   // 391
    const int NB_AGG  = N_NODES / 4;             // 25000
    const int NB_DENSE = N_NODES / NPB;          // 3125

    // small precomputes + edge-ordered records (+fused deg histogram)
    k_init_small<<<1, 64, 0, stream>>>(edge_w, att_edge, we_vec);
    k_fuse_w<<<1, 256, 0, stream>>>(enc_w, enc_b, gat_w, Wc, bc);
    k_deg_init<<<NB_N256, 256, 0, stream>>>(deg, bkt_cnt);
    k_mean_edterm<<<MEAN_BLOCKS, 256, 0, stream>>>(eattr, src, dst, we_vec,
                                                   partials, rec_agg, deg);
    k_mean_final<<<1, 256, 0, stream>>>(partials, we_vec, ltp);

    // CSR build: single-read fine bucketing -> scan -> XCD-local ordered scatter+build
    k_bucket<<<BKT_NBLK, 256, 0, stream>>>(dst, bkt_e, bkt_d, bkt_cnt);
    k_scan1<<<N_SCAN_BLOCKS, SCAN_BLOCK, 0, stream>>>(deg, row_ptr, blk_sums);
    k_scan2<<<1, 256, 0, stream>>>(blk_sums, blk_off);
    k_scan3<<<NB_N256, 256, 0, stream>>>(row_ptr, blk_off, deg, cursor, ltp, agg, dec);
    k_scatter_build<<<SCAT_BLOCKS, 256, 0, stream>>>(bkt_cnt, bkt_e, bkt_d,
                                                     rec_agg, cursor, agg, dec);

    // layer-0 projection (encoder folded into Wc/bc)
    k_xp0<<<NB_DENSE, 256, 0, stream>>>(x, Wc, bc, att_src, att_dst, xpb, s_src, s_dst);
    k_aggregate<0><<<NB_AGG, 256, 0, stream>>>(row_ptr, agg, s_src, s_dst,
                                               (const uint2*)xpb, gat_b, h);
    // GAT layer 1
    k_xp<<<NB_DENSE, 256, 0, stream>>>(h, gat_w + HD * HD, att_src + HD, att_dst + HD,
                                       xpb, s_src, s_dst);
    k_aggregate<1><<<NB_AGG, 256, 0, stream>>>(row_ptr, agg, s_src, s_dst,
                                               (const uint2*)xpb, gat_b + HD, h);

    // decoder: u1(bf16) -> xpb buffer, u2(fp32) -> h buffer
    k_umm<<<NB_DENSE, 256, 0, stream>>>(h, lp_w1, xpb, h);
    k_decode_csr<<<NB_AGG, 256, 0, stream>>>(row_ptr, dec, (const uint2*)xpb, h,
                                             lp_b1, lp_w2, lp_b2, out);
}

// Round 3
// 526.263 us; speedup vs baseline: 1.1978x; 1.1978x over previous
//
#include <hip/hip_runtime.h>
#include <hip/hip_bf16.h>
#include <math.h>

#define N_NODES 100000
#define N_EDGES 1600000
#define F_INN   32
#define F_EE    8
#define HD      64
#define E_SL    (N_EDGES + N_NODES)   // edges + self loops
#define NEG_SLOPE 0.2f
#define SCAN_BLOCK 512
#define N_SCAN_BLOCKS ((N_NODES + SCAN_BLOCK - 1) / SCAN_BLOCK)   // 196
#define NPB 32                        // nodes per block in dense kernels (3125 blocks)

// dst-range bucketing fused into the edge pass. 250 buckets of 400 nodes each;
// each bucket is counting-sorted IN LDS by one block and written out as a fully
// contiguous coalesced stream — r1/r2 showed the scatter approach pays 3-6x
// write-allocate/writeback amplification (168MB r1 / 88+84MB r2 vs 27MB ideal).
#define NBKT 250
#define BKT_W (N_NODES / NBKT)        // 400 nodes per bucket
#define BKT_CAP 7200                  // mean 6400 + 10 sigma — overflow prob ~1e-13
#define ME_UNR 10
#define ME_BLOCKS (N_EDGES / (256 * ME_UNR))   // 625
#define PART_CH (ME_BLOCKS * 4)       // 2500 wave partials
#define SB_THREADS 512
#define SEL_CAP (BKT_CAP + BKT_W)     // 7600

typedef int intv4 __attribute__((ext_vector_type(4)));

// ---------- helpers ----------
__device__ __forceinline__ float waveReduceSum(float v) {
#pragma unroll
    for (int off = 32; off > 0; off >>= 1) v += __shfl_down(v, off, 64);
    return v;
}
__device__ __forceinline__ float bf_lo(uint u) { return __uint_as_float(u << 16); }
__device__ __forceinline__ float bf_hi(uint u) { return __uint_as_float(u & 0xffff0000u); }
__device__ __forceinline__ uint pack_bf2(float a, float b) {
    __hip_bfloat16 ha = __float2bfloat16(a), hb = __float2bfloat16(b);
    unsigned short ua, ub;
    __builtin_memcpy(&ua, &ha, 2); __builtin_memcpy(&ub, &hb, 2);
    return (uint)ua | ((uint)ub << 16);
}

// ---------- K1: we_vec[l][k] = dot(edge_w[l][k,:], att_edge[l,:]) ----------
__global__ void k_init_small(const float* __restrict__ edge_w, const float* __restrict__ att_edge,
                             float* __restrict__ we_vec) {
    int t = threadIdx.x;
    if (t < 16) {
        int l = t >> 3, k = t & 7;
        const float* We = edge_w + l * F_EE * HD + k * HD;
        const float* ae = att_edge + l * HD;
        float s = 0.0f;
#pragma unroll
        for (int j = 0; j < HD; ++j) s += We[j] * ae[j];
        we_vec[l * 8 + k] = s;
    }
}

// ---------- K1b: fold encoder into layer-0 projection: Wc = enc_w@W0, bc = enc_b@W0 ----------
__global__ __launch_bounds__(256) void k_fuse_w(const float* __restrict__ enc_w,
                                                const float* __restrict__ enc_b,
                                                const float* __restrict__ W0,
                                                float* __restrict__ Wc, float* __restrict__ bc) {
    int t = threadIdx.x;
    for (int idx = t; idx < F_INN * HD; idx += 256) {
        int r = idx >> 6, c = idx & 63;
        float s = 0.0f;
#pragma unroll
        for (int k = 0; k < HD; ++k) s += enc_w[r * HD + k] * W0[k * HD + c];
        Wc[idx] = s;
    }
    if (t < HD) {
        float s = 0.0f;
#pragma unroll
        for (int k = 0; k < HD; ++k) s += enc_b[k] * W0[k * HD + t];
        bc[t] = s;
    }
}

// ---------- K2a: fused — mean partials, deg histogram, edge-term compute, bucket scatter ----------
// Each block owns a 2560-edge chunk: records held in registers, LDS 250-bin
// histogram -> one global atomic per (block,bucket) -> NT 16B record stores.
__global__ __launch_bounds__(256) void k_mean_edterm(const float* __restrict__ eattr,
                                                     const int* __restrict__ src,
                                                     const int* __restrict__ dst,
                                                     const float* __restrict__ we_vec,
                                                     float* __restrict__ partials,
                                                     int* __restrict__ bkt,
                                                     int* __restrict__ bkt_cnt,
                                                     int* __restrict__ deg) {
    __shared__ float sw[16];
    __shared__ int hist[NBKT];
    __shared__ int base[NBKT];
    int t = threadIdx.x;
    if (t < 16) sw[t] = we_vec[t];
    if (t < NBKT) hist[t] = 0;
    __syncthreads();
    float p[8];
#pragma unroll
    for (int k = 0; k < 8; ++k) p[k] = 0.0f;
    int e0 = blockIdx.x * (256 * ME_UNR);
    int rs[ME_UNR]; uint rp[ME_UNR]; int rb[ME_UNR];   // rb = (bucket<<16)|d_local
#pragma unroll
    for (int u = 0; u < ME_UNR; ++u) {
        int e = e0 + u * 256 + t;
        const float4* row = (const float4*)(eattr + (size_t)e * F_EE);
        float4 r0 = row[0], r1 = row[1];
        p[0] += r0.x; p[1] += r0.y; p[2] += r0.z; p[3] += r0.w;
        p[4] += r1.x; p[5] += r1.y; p[6] += r1.z; p[7] += r1.w;
        float ed0 = r0.x * sw[0] + r0.y * sw[1] + r0.z * sw[2] + r0.w * sw[3]
                  + r1.x * sw[4] + r1.y * sw[5] + r1.z * sw[6] + r1.w * sw[7];
        float ed1 = r0.x * sw[8] + r0.y * sw[9] + r0.z * sw[10] + r0.w * sw[11]
                  + r1.x * sw[12] + r1.y * sw[13] + r1.z * sw[14] + r1.w * sw[15];
        rs[u] = src[e];
        rp[u] = pack_bf2(ed0, ed1);
        int d = dst[e];
        int b = d / BKT_W;
        rb[u] = (b << 16) | (d - b * BKT_W);
        atomicAdd(&deg[d], 1);            // fused histogram (deg pre-initialized to 1)
        atomicAdd(&hist[b], 1);
    }
    __syncthreads();
    if (t < NBKT) base[t] = atomicAdd(&bkt_cnt[t], hist[t]);
    __syncthreads();
    if (t < NBKT) hist[t] = 0;            // reuse as intra-block cursor
    __syncthreads();
#pragma unroll
    for (int u = 0; u < ME_UNR; ++u) {
        int e = e0 + u * 256 + t;
        int b = rb[u] >> 16, dl = rb[u] & 0xFFFF;
        int pos = base[b] + atomicAdd(&hist[b], 1);
        intv4 rec; rec[0] = rs[u]; rec[1] = (int)rp[u]; rec[2] = e; rec[3] = dl;
        __builtin_nontemporal_store(rec, (intv4*)(bkt + ((size_t)b * BKT_CAP + pos) * 4));
    }
#pragma unroll
    for (int k = 0; k < 8; ++k) p[k] = waveReduceSum(p[k]);
    int wave = t >> 6;
    if ((t & 63) == 0) {
        float* dstp = partials + ((size_t)blockIdx.x * 4 + wave) * 8;
#pragma unroll
        for (int k = 0; k < 8; ++k) dstp[k] = p[k];
    }
}

// ---------- K2b: finish mean; ltp = packed bf16 {loop_term0, loop_term1} ----------
__global__ __launch_bounds__(256) void k_mean_final(const float* __restrict__ partials,
                                                    const float* __restrict__ we_vec,
                                                    uint* __restrict__ ltp) {
    __shared__ float red[256];
    __shared__ float mean8[8];
    __shared__ float lt[2];
    int t = threadIdx.x;
    int k = t & 7;
    int chunk = t >> 3;
    float s = 0.0f;
    for (int i = chunk; i < PART_CH; i += 32) s += partials[(size_t)i * 8 + k];
    red[t] = s;
    __syncthreads();
    if (t < 8) {
        float acc = 0.0f;
#pragma unroll
        for (int c = 0; c < 32; ++c) acc += red[c * 8 + t];
        mean8[t] = acc * (1.0f / N_EDGES);
    }
    __syncthreads();
    if (t < 2) {
        float acc = 0.0f;
#pragma unroll
        for (int kk = 0; kk < 8; ++kk) acc += mean8[kk] * we_vec[t * 8 + kk];
        lt[t] = acc;
    }
    __syncthreads();
    if (t == 0) ltp[0] = pack_bf2(lt[0], lt[1]);
}

// ---------- CSR build ----------
__global__ void k_deg_init(int* __restrict__ deg, int* __restrict__ bkt_cnt) {
    int i = blockIdx.x * 256 + threadIdx.x;
    if (i < N_NODES) deg[i] = 1;   // self-loop
    if (i < NBKT) bkt_cnt[i] = 0;
}

__global__ __launch_bounds__(SCAN_BLOCK) void k_scan1(const int* __restrict__ deg,
                                                      int* __restrict__ row_ptr,
                                                      int* __restrict__ blk_sums) {
    __shared__ int sd[SCAN_BLOCK];
    int t = threadIdx.x;
    int i = blockIdx.x * SCAN_BLOCK + t;
    int v = (i < N_NODES) ? deg[i] : 0;
    sd[t] = v;
    for (int off = 1; off < SCAN_BLOCK; off <<= 1) {
        __syncthreads();
        int x = (t >= off) ? sd[t - off] : 0;
        __syncthreads();
        sd[t] += x;
    }
    __syncthreads();
    if (i < N_NODES) row_ptr[i] = sd[t] - v;
    if (t == SCAN_BLOCK - 1) blk_sums[blockIdx.x] = sd[t];
}

__global__ __launch_bounds__(256) void k_scan2(int* __restrict__ blk_sums,
                                               int* __restrict__ blk_off) {
    __shared__ int sd[256];
    int t = threadIdx.x;
    int v = (t < N_SCAN_BLOCKS) ? blk_sums[t] : 0;
    sd[t] = v;
    for (int off = 1; off < 256; off <<= 1) {
        __syncthreads();
        int x = (t >= off) ? sd[t - off] : 0;
        __syncthreads();
        sd[t] += x;
    }
    __syncthreads();
    if (t < N_SCAN_BLOCKS) blk_off[t] = sd[t] - v;
}

// finalize row_ptr only (self-loop records are placed by k_sort_build)
__global__ void k_scan3(int* __restrict__ row_ptr, const int* __restrict__ blk_off) {
    int i = blockIdx.x * 256 + threadIdx.x;
    if (i < N_NODES) row_ptr[i] += blk_off[i / SCAN_BLOCK];
    if (i == 0) row_ptr[N_NODES] = E_SL;
}

// kB: one block per bucket. Counting-sort the bucket's ~6400 records in LDS
// (per-node hist -> scan -> u16 rank array with self-loop slots interleaved),
// then write agg/dec as FULLY CONTIGUOUS coalesced streams. Random reads are
// confined to the block's own L2-resident ~102KB bucket; zero global atomics.
__global__ __launch_bounds__(SB_THREADS) void k_sort_build(const int* __restrict__ bkt_cnt,
                                                           const int* __restrict__ bkt,
                                                           const int* __restrict__ row_ptr,
                                                           const uint* __restrict__ ltp,
                                                           int2* __restrict__ agg,
                                                           int2* __restrict__ dec) {
    __shared__ int S[BKT_W];                 // inclusive scan of per-node counts
    __shared__ int cur[BKT_W];               // hist, then rank cursor
    __shared__ unsigned short sel[SEL_CAP];  // local position -> record idx | selfloop
    int b = blockIdx.x;
    int t = threadIdx.x;
    int cnt = bkt_cnt[b];
    const intv4* bp = (const intv4*)(bkt + (size_t)b * BKT_CAP * 4);
    if (t < BKT_W) cur[t] = 0;
    __syncthreads();
    for (int i = t; i < cnt; i += SB_THREADS) {
        intv4 v = bp[i];                     // streams bucket into L2
        atomicAdd(&cur[v[3]], 1);
    }
    __syncthreads();
    if (t < BKT_W) S[t] = cur[t];
    for (int off = 1; off < BKT_W; off <<= 1) {
        __syncthreads();
        int x = (t >= off && t < BKT_W) ? S[t - off] : 0;
        __syncthreads();
        if (t < BKT_W) S[t] += x;
    }
    __syncthreads();
    if (t < BKT_W) {
        cur[t] = 0;
        sel[S[t] + t] = (unsigned short)(0x8000 | t);   // self-loop slot (segment end)
    }
    __syncthreads();
    for (int i = t; i < cnt; i += SB_THREADS) {
        int dl = bp[i][3];                   // L2 re-read
        int r = atomicAdd(&cur[dl], 1);
        int nb = (dl == 0) ? 0 : S[dl - 1];
        sel[nb + dl + r] = (unsigned short)i;
    }
    __syncthreads();
    int n0 = b * BKT_W;
    int gb = row_ptr[n0];
    int total = cnt + BKT_W;
    uint lt = ltp[0];
    for (int p = t; p < total; p += SB_THREADS) {
        unsigned short v = sel[p];
        int2 a, d2;
        if (v & 0x8000) {
            int node = n0 + (v & 0x7fff);
            a = make_int2(node, (int)lt);
            d2 = make_int2(node, -1);
        } else {
            intv4 r = bp[v];                 // random read within L2-resident bucket
            a = make_int2(r[0], r[1]);
            d2 = make_int2(r[0], r[2]);
        }
        agg[gb + p] = a;                     // contiguous coalesced streams
        dec[gb + p] = d2;
    }
}

// ---------- K3: layer-0 projection xp = x@Wc + bc — weight column in VGPRs, x broadcast via LDS ----------
__global__ __launch_bounds__(256) void k_xp0(const float* __restrict__ x,
                                             const float* __restrict__ Wc,
                                             const float* __restrict__ bc,
                                             const float* __restrict__ a_src,
                                             const float* __restrict__ a_dst,
                                             __hip_bfloat16* __restrict__ xpb,
                                             float* __restrict__ s_src,
                                             float* __restrict__ s_dst) {
    __shared__ float xr[NPB * F_INN];  // 4 KB
    int t = threadIdx.x;
    int j = t & 63, wv = t >> 6;
    float4 w[F_INN / 4];               // 8 VGPR float4s = weight column j
#pragma unroll
    for (int kk = 0; kk < F_INN / 4; ++kk) {
        w[kk].x = Wc[(4 * kk + 0) * HD + j];
        w[kk].y = Wc[(4 * kk + 1) * HD + j];
        w[kk].z = Wc[(4 * kk + 2) * HD + j];
        w[kk].w = Wc[(4 * kk + 3) * HD + j];
    }
    int n0 = blockIdx.x * NPB;
    ((float4*)xr)[t] = ((const float4*)(x + (size_t)n0 * F_INN))[t];  // 256*16B = 4KB exact
    __syncthreads();
    float asj = a_src[j], adj = a_dst[j], bcj = bc[j];
    for (int n = wv; n < NPB; n += 4) {
        const float4* hx = (const float4*)&xr[n * F_INN];
        float acc = bcj;
#pragma unroll
        for (int kk = 0; kk < F_INN / 4; ++kk) {
            float4 hv = hx[kk];   // wave-uniform broadcast ds_read_b128
            acc += hv.x * w[kk].x + hv.y * w[kk].y + hv.z * w[kk].z + hv.w * w[kk].w;
        }
        int node = n0 + n;
        xpb[(size_t)node * HD + j] = __float2bfloat16(acc);
        float ts = waveReduceSum(acc * asj);
        float td = waveReduceSum(acc * adj);
        if (j == 0) { s_src[node] = ts; s_dst[node] = td; }
    }
}

// ---------- K4: xp(bf16) = h @ W (layer 1) — weight column in VGPRs ----------
__global__ __launch_bounds__(256) void k_xp(const float* __restrict__ h, const float* __restrict__ W,
                                            const float* __restrict__ a_src, const float* __restrict__ a_dst,
                                            __hip_bfloat16* __restrict__ xpb, float* __restrict__ s_src,
                                            float* __restrict__ s_dst) {
    __shared__ float hr[NPB * HD];     // 8 KB
    int t = threadIdx.x;
    int j = t & 63, wv = t >> 6;
    float4 w[HD / 4];                  // 16 float4s = 64 VGPRs
#pragma unroll
    for (int kk = 0; kk < HD / 4; ++kk) {
        w[kk].x = W[(4 * kk + 0) * HD + j];
        w[kk].y = W[(4 * kk + 1) * HD + j];
        w[kk].z = W[(4 * kk + 2) * HD + j];
        w[kk].w = W[(4 * kk + 3) * HD + j];
    }
    int n0 = blockIdx.x * NPB;
#pragma unroll
    for (int i = 0; i < 2; ++i)
        ((float4*)hr)[t + i * 256] = ((const float4*)(h + (size_t)n0 * HD))[t + i * 256];
    __syncthreads();
    float asj = a_src[j], adj = a_dst[j];
    for (int n = wv; n < NPB; n += 4) {
        const float4* hx = (const float4*)&hr[n * HD];
        float acc = 0.0f;
#pragma unroll
        for (int kk = 0; kk < HD / 4; ++kk) {
            float4 hv = hx[kk];   // broadcast ds_read_b128
            acc += hv.x * w[kk].x + hv.y * w[kk].y + hv.z * w[kk].z + hv.w * w[kk].w;
        }
        int node = n0 + n;
        xpb[(size_t)node * HD + j] = __float2bfloat16(acc);
        float ts = waveReduceSum(acc * asj);
        float td = waveReduceSum(acc * adj);
        if (j == 0) { s_src[node] = ts; s_dst[node] = td; }
    }
}

// ---------- K5: gather-aggregate — wave/node, 16-lane groups, 8 edges/iter in flight ----------
template <int LAYER>
__global__ __launch_bounds__(256) void k_aggregate(const int* __restrict__ row_ptr,
                                                   const int2* __restrict__ agg,
                                                   const float* __restrict__ s_src,
                                                   const float* __restrict__ s_dst,
                                                   const uint2* __restrict__ xpr,   // bf16 x4 per lane
                                                   const float* __restrict__ bias,
                                                   float* __restrict__ h) {
    int t = threadIdx.x;
    int node = blockIdx.x * 4 + (t >> 6);    // grid exact: N/4
    int lane = t & 63;
    int g = lane >> 4, li = lane & 15;
    int start = row_ptr[node], end = row_ptr[node + 1];
    float sd = s_dst[node];
    float ax = 0.0f, ay = 0.0f, az = 0.0f, aw = 0.0f, den = 0.0f;
    int i = start;
    for (; i + 8 <= end; i += 8) {
        int2 r0 = agg[i + g];
        int2 r1 = agg[i + 4 + g];
        int sp0 = r0.x, sp1 = r1.x;
        uint2 u0 = xpr[(size_t)sp0 * 16 + li];
        uint2 u1 = xpr[(size_t)sp1 * 16 + li];
        float a0 = s_src[sp0] + sd + (LAYER == 0 ? bf_lo((uint)r0.y) : bf_hi((uint)r0.y));
        float a1 = s_src[sp1] + sd + (LAYER == 0 ? bf_lo((uint)r1.y) : bf_hi((uint)r1.y));
        a0 = a0 > 0.0f ? a0 : NEG_SLOPE * a0;
        a1 = a1 > 0.0f ? a1 : NEG_SLOPE * a1;
        float ex0 = __expf(a0), ex1 = __expf(a1);
        den += ex0 + ex1;
        ax += ex0 * bf_lo(u0.x) + ex1 * bf_lo(u1.x);
        ay += ex0 * bf_hi(u0.x) + ex1 * bf_hi(u1.x);
        az += ex0 * bf_lo(u0.y) + ex1 * bf_lo(u1.y);
        aw += ex0 * bf_hi(u0.y) + ex1 * bf_hi(u1.y);
    }
    for (; i < end; i += 4) {
        int idx = i + g;
        bool valid = idx < end;
        int2 r = agg[valid ? idx : end - 1];
        int sp = r.x;
        uint2 u = xpr[(size_t)sp * 16 + li];
        float a = s_src[sp] + sd + (LAYER == 0 ? bf_lo((uint)r.y) : bf_hi((uint)r.y));
        a = a > 0.0f ? a : NEG_SLOPE * a;
        float ex = valid ? __expf(a) : 0.0f;
        den += ex;
        ax += ex * bf_lo(u.x);
        ay += ex * bf_hi(u.x);
        az += ex * bf_lo(u.y);
        aw += ex * bf_hi(u.y);
    }
    den += __shfl_down(den, 32, 64); ax += __shfl_down(ax, 32, 64);
    ay  += __shfl_down(ay, 32, 64); az += __shfl_down(az, 32, 64);
    aw  += __shfl_down(aw, 32, 64);
    den += __shfl_down(den, 16, 64); ax += __shfl_down(ax, 16, 64);
    ay  += __shfl_down(ay, 16, 64); az += __shfl_down(az, 16, 64);
    aw  += __shfl_down(aw, 16, 64);
    if (lane < 16) {
        float inv = 1.0f / (den + 1e-16f);
        float4 b4 = ((const float4*)bias)[li];
        float4 v;
        v.x = fmaxf(ax * inv + b4.x, 0.0f);
        v.y = fmaxf(ay * inv + b4.y, 0.0f);
        v.z = fmaxf(az * inv + b4.z, 0.0f);
        v.w = fmaxf(aw * inv + b4.w, 0.0f);
        ((float4*)(h + (size_t)node * HD))[li] = v;
    }
}

// ---------- K6: u1(bf16)=h@W1a, u2(f32)=h@W1b — both weight columns in VGPRs ----------
// (u2 aliases h: tile staged to LDS before any write)
__global__ __launch_bounds__(256) void k_umm(const float* __restrict__ h, const float* __restrict__ w1,
                                             __hip_bfloat16* __restrict__ u1b, float* __restrict__ u2) {
    __shared__ float hr[NPB * HD];     // 8 KB
    int t = threadIdx.x;
    int j = t & 63, wv = t >> 6;
    float4 wa[HD / 4], wb[HD / 4];     // 128 VGPRs
#pragma unroll
    for (int kk = 0; kk < HD / 4; ++kk) {
        wa[kk].x = w1[(4 * kk + 0) * HD + j];
        wa[kk].y = w1[(4 * kk + 1) * HD + j];
        wa[kk].z = w1[(4 * kk + 2) * HD + j];
        wa[kk].w = w1[(4 * kk + 3) * HD + j];
        wb[kk].x = w1[(HD + 4 * kk + 0) * HD + j];
        wb[kk].y = w1[(HD + 4 * kk + 1) * HD + j];
        wb[kk].z = w1[(HD + 4 * kk + 2) * HD + j];
        wb[kk].w = w1[(HD + 4 * kk + 3) * HD + j];
    }
    int n0 = blockIdx.x * NPB;
#pragma unroll
    for (int i = 0; i < 2; ++i)
        ((float4*)hr)[t + i * 256] = ((const float4*)(h + (size_t)n0 * HD))[t + i * 256];
    __syncthreads();
    for (int n = wv; n < NPB; n += 4) {
        const float4* hx = (const float4*)&hr[n * HD];
        float a1 = 0.0f, a2 = 0.0f;
#pragma unroll
        for (int kk = 0; kk < HD / 4; ++kk) {
            float4 hv = hx[kk];   // broadcast ds_read_b128
            a1 += hv.x * wa[kk].x + hv.y * wa[kk].y + hv.z * wa[kk].z + hv.w * wa[kk].w;
            a2 += hv.x * wb[kk].x + hv.y * wb[kk].y + hv.z * wb[kk].z + hv.w * wb[kk].w;
        }
        int node = n0 + n;
        u1b[(size_t)node * HD + j] = __float2bfloat16(a1);
        u2[(size_t)node * HD + j] = a2;
    }
}

// ---------- K7: CSR decode — wave/node, 16-lane groups, 8 edges/iter, width-16 reduce ----------
__global__ __launch_bounds__(256) void k_decode_csr(const int* __restrict__ row_ptr,
                                                    const int2* __restrict__ dec,
                                                    const uint2* __restrict__ u1r,  // bf16 x4 per lane
                                                    const float* __restrict__ u2,
                                                    const float* __restrict__ b1,
                                                    const float* __restrict__ w2,
                                                    const float* __restrict__ b2,
                                                    float* __restrict__ out) {
    int t = threadIdx.x;
    int node = blockIdx.x * 4 + (t >> 6);    // grid exact: N/4
    int lane = t & 63;
    int g = lane >> 4, li = lane & 15;
    float4 c4 = ((const float4*)(u2 + (size_t)node * HD))[li];
    float4 b14 = ((const float4*)b1)[li];
    float4 w4 = ((const float4*)w2)[li];
    c4.x += b14.x; c4.y += b14.y; c4.z += b14.z; c4.w += b14.w;
    float bb = b2[0];
    int start = row_ptr[node], end = row_ptr[node + 1];
    int i = start;
    for (; i + 8 <= end; i += 8) {
        int2 e0 = dec[i + g];
        int2 e1 = dec[i + 4 + g];
        uint2 ua = u1r[(size_t)e0.x * 16 + li];
        uint2 ub = u1r[(size_t)e1.x * 16 + li];
        float p0 = fmaxf(bf_lo(ua.x) + c4.x, 0.0f) * w4.x
                 + fmaxf(bf_hi(ua.x) + c4.y, 0.0f) * w4.y
                 + fmaxf(bf_lo(ua.y) + c4.z, 0.0f) * w4.z
                 + fmaxf(bf_hi(ua.y) + c4.w, 0.0f) * w4.w;
        float p1 = fmaxf(bf_lo(ub.x) + c4.x, 0.0f) * w4.x
                 + fmaxf(bf_hi(ub.x) + c4.y, 0.0f) * w4.y
                 + fmaxf(bf_lo(ub.y) + c4.z, 0.0f) * w4.z
                 + fmaxf(bf_hi(ub.y) + c4.w, 0.0f) * w4.w;
#pragma unroll
        for (int off = 8; off > 0; off >>= 1) {
            p0 += __shfl_down(p0, off, 16);
            p1 += __shfl_down(p1, off, 16);
        }
        if (li == 0) {
            if (e0.y >= 0) out[e0.y] = 1.0f / (1.0f + __expf(-(p0 + bb)));
            if (e1.y >= 0) out[e1.y] = 1.0f / (1.0f + __expf(-(p1 + bb)));
        }
    }
    for (; i < end; i += 4) {
        int idx = i + g;
        bool valid = idx < end;
        int2 e = dec[valid ? idx : end - 1];
        uint2 u = u1r[(size_t)e.x * 16 + li];
        float p = fmaxf(bf_lo(u.x) + c4.x, 0.0f) * w4.x
                + fmaxf(bf_hi(u.x) + c4.y, 0.0f) * w4.y
                + fmaxf(bf_lo(u.y) + c4.z, 0.0f) * w4.z
                + fmaxf(bf_hi(u.y) + c4.w, 0.0f) * w4.w;
#pragma unroll
        for (int off = 8; off > 0; off >>= 1) p += __shfl_down(p, off, 16);
        if (li == 0 && valid && e.y >= 0)
            out[e.y] = 1.0f / (1.0f + __expf(-(p + bb)));
    }
}

extern "C" void kernel_launch(void* const* d_in, const int* in_sizes, int n_in,
                              void* d_out, int out_size, void* d_ws, size_t ws_size,
                              hipStream_t stream) {
    const float* x        = (const float*)d_in[0];
    const int*   eidx     = (const int*)d_in[1];
    const float* eattr    = (const float*)d_in[2];
    const float* enc_w    = (const float*)d_in[3];
    const float* enc_b    = (const float*)d_in[4];
    const float* gat_w    = (const float*)d_in[5];
    const float* att_src  = (const float*)d_in[6];
    const float* att_dst  = (const float*)d_in[7];
    const float* edge_w   = (const float*)d_in[8];
    const float* att_edge = (const float*)d_in[9];
    const float* gat_b    = (const float*)d_in[10];
    const float* lp_w1    = (const float*)d_in[11];
    const float* lp_b1    = (const float*)d_in[12];
    const float* lp_w2    = (const float*)d_in[13];
    const float* lp_b2    = (const float*)d_in[14];
    float* out = (float*)d_out;

    const int* src = eidx;
    const int* dst = eidx + N_EDGES;

    // ---- workspace layout ----
    float* ws = (float*)d_ws;
    float*  h       = ws;                                   // N*64 f32 (u2 after k_umm)
    // bucket records (16B AoS) alias h AND xpb (28.8MB of their combined 38.4MB):
    // live only from k_mean_edterm to k_sort_build — before k_xp0 writes xpb and
    // before k_aggregate<0> writes h.
    int*    bkt     = (int*)h;                              // NBKT*BKT_CAP*16B = 28.8MB
    __hip_bfloat16* xpb = (__hip_bfloat16*)(h + (size_t)N_NODES * HD);  // N*64 bf16 (u1b after k_umm)
    int2*   agg     = (int2*)((char*)xpb + (size_t)N_NODES * HD * 2);   // E_SL int2 (13.6MB)
    int2*   dec     = agg + E_SL;                           // E_SL int2 (13.6MB)
    float*  fsmall    = (float*)(dec + E_SL);
    float*  s_src     = fsmall;                             // N
    float*  s_dst     = s_src + N_NODES;                    // N
    float*  partials  = s_dst + N_NODES;                    // PART_CH*8 (20000)
    float*  we_vec    = partials + PART_CH * 8;             // 16
    uint*   ltp       = (uint*)(we_vec + 16);               // 1
    float*  Wc        = (float*)(ltp + 1);                  // 32*64
    float*  bc        = Wc + F_INN * HD;                    // 64
    int*    row_ptr   = (int*)(bc + HD);                    // N+1
    int*    deg       = row_ptr + N_NODES + 1;              // N
    int*    blk_sums  = deg + N_NODES;                      // N_SCAN_BLOCKS
    int*    blk_off   = blk_sums + N_SCAN_BLOCKS;           // N_SCAN_BLOCKS
    int*    bkt_cnt   = blk_off + N_SCAN_BLOCKS;            // NBKT

    const int NB_N256 = (N_NODES + 255) / 256;   // 391
    const int NB_AGG  = N_NODES / 4;             // 25000
    const int NB_DENSE = N_NODES / NPB;          // 3125

    // small precomputes + fused edge pass (mean partials, deg hist, bucket scatter)
    k_init_small<<<1, 64, 0, stream>>>(edge_w, att_edge, we_vec);
    k_fuse_w<<<1, 256, 0, stream>>>(enc_w, enc_b, gat_w, Wc, bc);
    k_deg_init<<<NB_N256, 256, 0, stream>>>(deg, bkt_cnt);
    k_mean_edterm<<<ME_BLOCKS, 256, 0, stream>>>(eattr, src, dst, we_vec,
                                                 partials, bkt, bkt_cnt, deg);
    k_mean_final<<<1, 256, 0, stream>>>(partials, we_vec, ltp);

    // CSR build: scan -> per-bucket LDS counting sort with coalesced record output
    k_scan1<<<N_SCAN_BLOCKS, SCAN_BLOCK, 0, stream>>>(deg, row_ptr, blk_sums);
    k_scan2<<<1, 256, 0, stream>>>(blk_sums, blk_off);
    k_scan3<<<NB_N256, 256, 0, stream>>>(row_ptr, blk_off);
    k_sort_build<<<NBKT, SB_THREADS, 0, stream>>>(bkt_cnt, bkt, row_ptr, ltp, agg, dec);

    // layer-0 projection (encoder folded into Wc/bc)
    k_xp0<<<NB_DENSE, 256, 0, stream>>>(x, Wc, bc, att_src, att_dst, xpb, s_src, s_dst);
    k_aggregate<0><<<NB_AGG, 256, 0, stream>>>(row_ptr, agg, s_src, s_dst,
                                               (const uint2*)xpb, gat_b, h);
    // GAT layer 1
    k_xp<<<NB_DENSE, 256, 0, stream>>>(h, gat_w + HD * HD, att_src + HD, att_dst + HD,
                                       xpb, s_src, s_dst);
    k_aggregate<1><<<NB_AGG, 256, 0, stream>>>(row_ptr, agg, s_src, s_dst,
                                               (const uint2*)xpb, gat_b + HD, h);

    // decoder: u1(bf16) -> xpb buffer, u2(fp32) -> h buffer
    k_umm<<<NB_DENSE, 256, 0, stream>>>(h, lp_w1, xpb, h);
    k_decode_csr<<<NB_AGG, 256, 0, stream>>>(row_ptr, dec, (const uint2*)xpb, h,
                                             lp_b1, lp_w2, lp_b2, out);
}

// Round 4
// 468.297 us; speedup vs baseline: 1.3460x; 1.1238x over previous
//
#include <hip/hip_runtime.h>
#include <hip/hip_bf16.h>
#include <math.h>

#define N_NODES 100000
#define N_EDGES 1600000
#define F_INN   32
#define F_EE    8
#define HD      64
#define E_SL    (N_EDGES + N_NODES)   // edges + self loops
#define NEG_SLOPE 0.2f
#define NPB 32                        // nodes per block in dense kernels (3125 blocks)

// dst-range bucketing fused into the edge pass. 250 buckets of 400 nodes.
// Records are staged + bucket-sorted in LDS, then flushed with wave-contiguous
// int4 stores (interior lines full-line, no allocate-fetch) — r3 showed 4.3x
// write amplification (110MB vs 25.6MB) from scattered per-record 16B NT stores.
#define NBKT 250
#define BKT_W (N_NODES / NBKT)        // 400 nodes per bucket
#define BKT_CAP 7200                  // mean 6400 + 10 sigma — overflow prob ~1e-13
#define ME_UNR 10
#define ME_CHUNK (256 * ME_UNR)       // 2560 edges per block
#define ME_BLOCKS (N_EDGES / ME_CHUNK)   // 625
#define PART_CH (ME_BLOCKS * 4)       // 2500 wave partials
#define SB_THREADS 512
#define SEL_CAP (BKT_CAP + BKT_W)     // 7600

// ---------- helpers ----------
__device__ __forceinline__ float waveReduceSum(float v) {
#pragma unroll
    for (int off = 32; off > 0; off >>= 1) v += __shfl_down(v, off, 64);
    return v;
}
__device__ __forceinline__ float bf_lo(uint u) { return __uint_as_float(u << 16); }
__device__ __forceinline__ float bf_hi(uint u) { return __uint_as_float(u & 0xffff0000u); }
__device__ __forceinline__ uint pack_bf2(float a, float b) {
    __hip_bfloat16 ha = __float2bfloat16(a), hb = __float2bfloat16(b);
    unsigned short ua, ub;
    __builtin_memcpy(&ua, &ha, 2); __builtin_memcpy(&ub, &hb, 2);
    return (uint)ua | ((uint)ub << 16);
}

// ---------- K1: we_vec[l][k] = dot(edge_w[l][k,:], att_edge[l,:]) ----------
__global__ void k_init_small(const float* __restrict__ edge_w, const float* __restrict__ att_edge,
                             float* __restrict__ we_vec) {
    int t = threadIdx.x;
    if (t < 16) {
        int l = t >> 3, k = t & 7;
        const float* We = edge_w + l * F_EE * HD + k * HD;
        const float* ae = att_edge + l * HD;
        float s = 0.0f;
#pragma unroll
        for (int j = 0; j < HD; ++j) s += We[j] * ae[j];
        we_vec[l * 8 + k] = s;
    }
}

// ---------- K1b: fold encoder into layer-0 projection: Wc = enc_w@W0, bc = enc_b@W0 ----------
__global__ __launch_bounds__(256) void k_fuse_w(const float* __restrict__ enc_w,
                                                const float* __restrict__ enc_b,
                                                const float* __restrict__ W0,
                                                float* __restrict__ Wc, float* __restrict__ bc) {
    int t = threadIdx.x;
    for (int idx = t; idx < F_INN * HD; idx += 256) {
        int r = idx >> 6, c = idx & 63;
        float s = 0.0f;
#pragma unroll
        for (int k = 0; k < HD; ++k) s += enc_w[r * HD + k] * W0[k * HD + c];
        Wc[idx] = s;
    }
    if (t < HD) {
        float s = 0.0f;
#pragma unroll
        for (int k = 0; k < HD; ++k) s += enc_b[k] * W0[k * HD + t];
        bc[t] = s;
    }
}

// ---------- K0: zero bucket counters ----------
__global__ void k_zero(int* __restrict__ bkt_pos) {
    int t = threadIdx.x;
    if (t < NBKT) bkt_pos[t] = 0;
}

// ---------- K2a: fused — mean partials, edge-term compute, LDS-sorted bucket flush ----------
// Per 2560-edge chunk: records kept in registers, LDS 250-bin histogram ->
// exclusive scan -> one global reservation per (block,bucket) -> records placed
// bucket-sorted in LDS -> per-bucket WAVE-CONTIGUOUS int4 flush (full-line
// interior writes, partial only at the two chunk-boundary lines).
__global__ __launch_bounds__(256) void k_mean_edterm(const float* __restrict__ eattr,
                                                     const int* __restrict__ src,
                                                     const int* __restrict__ dst,
                                                     const float* __restrict__ we_vec,
                                                     float* __restrict__ partials,
                                                     int* __restrict__ bkt,
                                                     int* __restrict__ bkt_pos) {
    __shared__ float sw[16];
    __shared__ int hist[NBKT];     // count, then LDS cursor, then chunk size
    __shared__ int lstart[256];    // scan array -> exclusive LDS record offsets
    __shared__ int gstart[NBKT];   // reserved global record offsets
    __shared__ int recs[ME_CHUNK * 4];   // 40 KB staged records
    int t = threadIdx.x;
    if (t < 16) sw[t] = we_vec[t];
    if (t < NBKT) hist[t] = 0;
    __syncthreads();
    float p[8];
#pragma unroll
    for (int k = 0; k < 8; ++k) p[k] = 0.0f;
    int e0 = blockIdx.x * ME_CHUNK;
    int rs[ME_UNR]; uint rp[ME_UNR]; int rb[ME_UNR];   // rb = (bucket<<16)|d_local
#pragma unroll
    for (int u = 0; u < ME_UNR; ++u) {
        int e = e0 + u * 256 + t;
        const float4* row = (const float4*)(eattr + (size_t)e * F_EE);
        float4 r0 = row[0], r1 = row[1];
        p[0] += r0.x; p[1] += r0.y; p[2] += r0.z; p[3] += r0.w;
        p[4] += r1.x; p[5] += r1.y; p[6] += r1.z; p[7] += r1.w;
        float ed0 = r0.x * sw[0] + r0.y * sw[1] + r0.z * sw[2] + r0.w * sw[3]
                  + r1.x * sw[4] + r1.y * sw[5] + r1.z * sw[6] + r1.w * sw[7];
        float ed1 = r0.x * sw[8] + r0.y * sw[9] + r0.z * sw[10] + r0.w * sw[11]
                  + r1.x * sw[12] + r1.y * sw[13] + r1.z * sw[14] + r1.w * sw[15];
        rs[u] = src[e];
        rp[u] = pack_bf2(ed0, ed1);
        int d = dst[e];
        int b = d / BKT_W;
        rb[u] = (b << 16) | (d - b * BKT_W);
        atomicAdd(&hist[b], 1);
    }
    __syncthreads();
    // exclusive scan of per-bucket counts -> LDS chunk offsets
    lstart[t] = (t < NBKT) ? hist[t] : 0;
    __syncthreads();
    for (int off = 1; off < 256; off <<= 1) {
        int x = (t >= off) ? lstart[t - off] : 0;
        __syncthreads();
        lstart[t] += x;
        __syncthreads();
    }
    if (t < NBKT) {
        int v = hist[t];
        gstart[t] = atomicAdd(&bkt_pos[t], v);   // exact reservation, no padding
        lstart[t] -= v;                          // inclusive -> exclusive
        hist[t] = 0;                             // reuse as placement cursor
    }
    __syncthreads();
    // place records bucket-sorted into LDS
#pragma unroll
    for (int u = 0; u < ME_UNR; ++u) {
        int b = rb[u] >> 16, dl = rb[u] & 0xFFFF;
        int l = atomicAdd(&hist[b], 1);
        int e = e0 + u * 256 + t;
        ((int4*)recs)[lstart[b] + l] = make_int4(rs[u], (int)rp[u], e, dl);
    }
    __syncthreads();
    // per-bucket wave-contiguous flush: one int4 store instruction covers the
    // whole chunk -> interior 128B lines are written full (no allocate-fetch)
    int w = t >> 6, lane = t & 63;
    int4* gb4 = (int4*)bkt;
    for (int b = w; b < NBKT; b += 4) {
        int n = hist[b];
        int ls = lstart[b];
        int gs = gstart[b];
        for (int off = lane; off < n; off += 64)
            if (gs + off < BKT_CAP)
                gb4[(size_t)b * BKT_CAP + gs + off] = ((const int4*)recs)[ls + off];
    }
#pragma unroll
    for (int k = 0; k < 8; ++k) p[k] = waveReduceSum(p[k]);
    if ((t & 63) == 0) {
        float* dstp = partials + ((size_t)blockIdx.x * 4 + w) * 8;
#pragma unroll
        for (int k = 0; k < 8; ++k) dstp[k] = p[k];
    }
}

// ---------- K2b: finish mean; ltp = packed bf16 {loop_term0, loop_term1} ----------
__global__ __launch_bounds__(256) void k_mean_final(const float* __restrict__ partials,
                                                    const float* __restrict__ we_vec,
                                                    uint* __restrict__ ltp) {
    __shared__ float red[256];
    __shared__ float mean8[8];
    __shared__ float lt[2];
    int t = threadIdx.x;
    int k = t & 7;
    int chunk = t >> 3;
    float s = 0.0f;
    for (int i = chunk; i < PART_CH; i += 32) s += partials[(size_t)i * 8 + k];
    red[t] = s;
    __syncthreads();
    if (t < 8) {
        float acc = 0.0f;
#pragma unroll
        for (int c = 0; c < 32; ++c) acc += red[c * 8 + t];
        mean8[t] = acc * (1.0f / N_EDGES);
    }
    __syncthreads();
    if (t < 2) {
        float acc = 0.0f;
#pragma unroll
        for (int kk = 0; kk < 8; ++kk) acc += mean8[kk] * we_vec[t * 8 + kk];
        lt[t] = acc;
    }
    __syncthreads();
    if (t == 0) ltp[0] = pack_bf2(lt[0], lt[1]);
}

// ---------- K2c: scan bucket counts -> bucket CSR bases (deg/scan kernels are gone) ----------
__global__ void k_bktscan(const int* __restrict__ bkt_pos, int* __restrict__ bktbase,
                          int* __restrict__ row_ptr) {
    __shared__ int sd[256];
    int t = threadIdx.x;
    int v = (t < NBKT) ? min(bkt_pos[t], BKT_CAP) + BKT_W : 0;
    sd[t] = v;
    __syncthreads();
    for (int off = 1; off < 256; off <<= 1) {
        int x = (t >= off) ? sd[t - off] : 0;
        __syncthreads();
        sd[t] += x;
        __syncthreads();
    }
    if (t < NBKT) bktbase[t] = sd[t] - v;
    if (t == 0) row_ptr[N_NODES] = E_SL;
}

// kB: one block per bucket. Counting-sort the bucket's ~6400 records in LDS
// (per-node hist -> scan -> u16 rank array with self-loop slots interleaved),
// write row_ptr for its 400 nodes, then write agg/dec as FULLY CONTIGUOUS
// coalesced streams. Random reads confined to the L2/L3-resident bucket.
__global__ __launch_bounds__(SB_THREADS) void k_sort_build(const int* __restrict__ bkt_pos,
                                                           const int* __restrict__ bkt,
                                                           const int* __restrict__ bktbase,
                                                           const uint* __restrict__ ltp,
                                                           int2* __restrict__ agg,
                                                           int2* __restrict__ dec,
                                                           int* __restrict__ row_ptr) {
    __shared__ int S[BKT_W];                 // inclusive scan of per-node counts
    __shared__ int cur[BKT_W];               // hist, then rank cursor
    __shared__ unsigned short sel[SEL_CAP];  // local position -> record idx | selfloop
    int b = blockIdx.x;
    int t = threadIdx.x;
    int cnt = min(bkt_pos[b], BKT_CAP);
    const int4* bp = (const int4*)bkt + (size_t)b * BKT_CAP;
    if (t < BKT_W) cur[t] = 0;
    __syncthreads();
    for (int i = t; i < cnt; i += SB_THREADS) {
        int4 v = bp[i];                      // streams bucket through L2
        atomicAdd(&cur[v.w], 1);
    }
    __syncthreads();
    if (t < BKT_W) S[t] = cur[t];
    for (int off = 1; off < BKT_W; off <<= 1) {
        __syncthreads();
        int x = (t >= off && t < BKT_W) ? S[t - off] : 0;
        __syncthreads();
        if (t < BKT_W) S[t] += x;
    }
    __syncthreads();
    int n0 = b * BKT_W;
    int gb = bktbase[b];
    if (t < BKT_W) {
        row_ptr[n0 + t] = gb + (t == 0 ? 0 : S[t - 1]) + t;   // excl scan of (cnt+1)
        cur[t] = 0;
        sel[S[t] + t] = (unsigned short)(0x8000 | t);   // self-loop slot (segment end)
    }
    __syncthreads();
    for (int i = t; i < cnt; i += SB_THREADS) {
        int dl = bp[i].w;                    // L2 re-read
        int r = atomicAdd(&cur[dl], 1);
        int nb = (dl == 0) ? 0 : S[dl - 1];
        sel[nb + dl + r] = (unsigned short)i;
    }
    __syncthreads();
    int total = cnt + BKT_W;
    uint lt = ltp[0];
    for (int p = t; p < total; p += SB_THREADS) {
        unsigned short v = sel[p];
        int2 a, d2;
        if (v & 0x8000) {
            int node = n0 + (v & 0x7fff);
            a = make_int2(node, (int)lt);
            d2 = make_int2(node, -1);
        } else {
            int4 r = bp[v];                  // random read within resident bucket
            a = make_int2(r.x, r.y);
            d2 = make_int2(r.x, r.z);
        }
        agg[gb + p] = a;                     // contiguous coalesced streams
        dec[gb + p] = d2;
    }
}

// ---------- K3: layer-0 projection xp = x@Wc + bc — weight column in VGPRs, x broadcast via LDS ----------
__global__ __launch_bounds__(256) void k_xp0(const float* __restrict__ x,
                                             const float* __restrict__ Wc,
                                             const float* __restrict__ bc,
                                             const float* __restrict__ a_src,
                                             const float* __restrict__ a_dst,
                                             __hip_bfloat16* __restrict__ xpb,
                                             float* __restrict__ s_src,
                                             float* __restrict__ s_dst) {
    __shared__ float xr[NPB * F_INN];  // 4 KB
    int t = threadIdx.x;
    int j = t & 63, wv = t >> 6;
    float4 w[F_INN / 4];               // 8 VGPR float4s = weight column j
#pragma unroll
    for (int kk = 0; kk < F_INN / 4; ++kk) {
        w[kk].x = Wc[(4 * kk + 0) * HD + j];
        w[kk].y = Wc[(4 * kk + 1) * HD + j];
        w[kk].z = Wc[(4 * kk + 2) * HD + j];
        w[kk].w = Wc[(4 * kk + 3) * HD + j];
    }
    int n0 = blockIdx.x * NPB;
    ((float4*)xr)[t] = ((const float4*)(x + (size_t)n0 * F_INN))[t];  // 256*16B = 4KB exact
    __syncthreads();
    float asj = a_src[j], adj = a_dst[j], bcj = bc[j];
    for (int n = wv; n < NPB; n += 4) {
        const float4* hx = (const float4*)&xr[n * F_INN];
        float acc = bcj;
#pragma unroll
        for (int kk = 0; kk < F_INN / 4; ++kk) {
            float4 hv = hx[kk];   // wave-uniform broadcast ds_read_b128
            acc += hv.x * w[kk].x + hv.y * w[kk].y + hv.z * w[kk].z + hv.w * w[kk].w;
        }
        int node = n0 + n;
        xpb[(size_t)node * HD + j] = __float2bfloat16(acc);
        float ts = waveReduceSum(acc * asj);
        float td = waveReduceSum(acc * adj);
        if (j == 0) { s_src[node] = ts; s_dst[node] = td; }
    }
}

// ---------- K4: xp(bf16) = h @ W (layer 1) — weight column in VGPRs ----------
__global__ __launch_bounds__(256) void k_xp(const float* __restrict__ h, const float* __restrict__ W,
                                            const float* __restrict__ a_src, const float* __restrict__ a_dst,
                                            __hip_bfloat16* __restrict__ xpb, float* __restrict__ s_src,
                                            float* __restrict__ s_dst) {
    __shared__ float hr[NPB * HD];     // 8 KB
    int t = threadIdx.x;
    int j = t & 63, wv = t >> 6;
    float4 w[HD / 4];                  // 16 float4s = 64 VGPRs
#pragma unroll
    for (int kk = 0; kk < HD / 4; ++kk) {
        w[kk].x = W[(4 * kk + 0) * HD + j];
        w[kk].y = W[(4 * kk + 1) * HD + j];
        w[kk].z = W[(4 * kk + 2) * HD + j];
        w[kk].w = W[(4 * kk + 3) * HD + j];
    }
    int n0 = blockIdx.x * NPB;
#pragma unroll
    for (int i = 0; i < 2; ++i)
        ((float4*)hr)[t + i * 256] = ((const float4*)(h + (size_t)n0 * HD))[t + i * 256];
    __syncthreads();
    float asj = a_src[j], adj = a_dst[j];
    for (int n = wv; n < NPB; n += 4) {
        const float4* hx = (const float4*)&hr[n * HD];
        float acc = 0.0f;
#pragma unroll
        for (int kk = 0; kk < HD / 4; ++kk) {
            float4 hv = hx[kk];   // broadcast ds_read_b128
            acc += hv.x * w[kk].x + hv.y * w[kk].y + hv.z * w[kk].z + hv.w * w[kk].w;
        }
        int node = n0 + n;
        xpb[(size_t)node * HD + j] = __float2bfloat16(acc);
        float ts = waveReduceSum(acc * asj);
        float td = waveReduceSum(acc * adj);
        if (j == 0) { s_src[node] = ts; s_dst[node] = td; }
    }
}

// ---------- K5: gather-aggregate — wave/node, 16-lane groups, 8 edges/iter in flight ----------
template <int LAYER>
__global__ __launch_bounds__(256) void k_aggregate(const int* __restrict__ row_ptr,
                                                   const int2* __restrict__ agg,
                                                   const float* __restrict__ s_src,
                                                   const float* __restrict__ s_dst,
                                                   const uint2* __restrict__ xpr,   // bf16 x4 per lane
                                                   const float* __restrict__ bias,
                                                   float* __restrict__ h) {
    int t = threadIdx.x;
    int node = blockIdx.x * 4 + (t >> 6);    // grid exact: N/4
    int lane = t & 63;
    int g = lane >> 4, li = lane & 15;
    int start = row_ptr[node], end = row_ptr[node + 1];
    float sd = s_dst[node];
    float ax = 0.0f, ay = 0.0f, az = 0.0f, aw = 0.0f, den = 0.0f;
    int i = start;
    for (; i + 8 <= end; i += 8) {
        int2 r0 = agg[i + g];
        int2 r1 = agg[i + 4 + g];
        int sp0 = r0.x, sp1 = r1.x;
        uint2 u0 = xpr[(size_t)sp0 * 16 + li];
        uint2 u1 = xpr[(size_t)sp1 * 16 + li];
        float a0 = s_src[sp0] + sd + (LAYER == 0 ? bf_lo((uint)r0.y) : bf_hi((uint)r0.y));
        float a1 = s_src[sp1] + sd + (LAYER == 0 ? bf_lo((uint)r1.y) : bf_hi((uint)r1.y));
        a0 = a0 > 0.0f ? a0 : NEG_SLOPE * a0;
        a1 = a1 > 0.0f ? a1 : NEG_SLOPE * a1;
        float ex0 = __expf(a0), ex1 = __expf(a1);
        den += ex0 + ex1;
        ax += ex0 * bf_lo(u0.x) + ex1 * bf_lo(u1.x);
        ay += ex0 * bf_hi(u0.x) + ex1 * bf_hi(u1.x);
        az += ex0 * bf_lo(u0.y) + ex1 * bf_lo(u1.y);
        aw += ex0 * bf_hi(u0.y) + ex1 * bf_hi(u1.y);
    }
    for (; i < end; i += 4) {
        int idx = i + g;
        bool valid = idx < end;
        int2 r = agg[valid ? idx : end - 1];
        int sp = r.x;
        uint2 u = xpr[(size_t)sp * 16 + li];
        float a = s_src[sp] + sd + (LAYER == 0 ? bf_lo((uint)r.y) : bf_hi((uint)r.y));
        a = a > 0.0f ? a : NEG_SLOPE * a;
        float ex = valid ? __expf(a) : 0.0f;
        den += ex;
        ax += ex * bf_lo(u.x);
        ay += ex * bf_hi(u.x);
        az += ex * bf_lo(u.y);
        aw += ex * bf_hi(u.y);
    }
    den += __shfl_down(den, 32, 64); ax += __shfl_down(ax, 32, 64);
    ay  += __shfl_down(ay, 32, 64); az += __shfl_down(az, 32, 64);
    aw  += __shfl_down(aw, 32, 64);
    den += __shfl_down(den, 16, 64); ax += __shfl_down(ax, 16, 64);
    ay  += __shfl_down(ay, 16, 64); az += __shfl_down(az, 16, 64);
    aw  += __shfl_down(aw, 16, 64);
    if (lane < 16) {
        float inv = 1.0f / (den + 1e-16f);
        float4 b4 = ((const float4*)bias)[li];
        float4 v;
        v.x = fmaxf(ax * inv + b4.x, 0.0f);
        v.y = fmaxf(ay * inv + b4.y, 0.0f);
        v.z = fmaxf(az * inv + b4.z, 0.0f);
        v.w = fmaxf(aw * inv + b4.w, 0.0f);
        ((float4*)(h + (size_t)node * HD))[li] = v;
    }
}

// ---------- K6: u1(bf16)=h@W1a, u2(f32)=h@W1b — both weight columns in VGPRs ----------
// (u2 aliases h: tile staged to LDS before any write)
__global__ __launch_bounds__(256) void k_umm(const float* __restrict__ h, const float* __restrict__ w1,
                                             __hip_bfloat16* __restrict__ u1b, float* __restrict__ u2) {
    __shared__ float hr[NPB * HD];     // 8 KB
    int t = threadIdx.x;
    int j = t & 63, wv = t >> 6;
    float4 wa[HD / 4], wb[HD / 4];     // 128 VGPRs
#pragma unroll
    for (int kk = 0; kk < HD / 4; ++kk) {
        wa[kk].x = w1[(4 * kk + 0) * HD + j];
        wa[kk].y = w1[(4 * kk + 1) * HD + j];
        wa[kk].z = w1[(4 * kk + 2) * HD + j];
        wa[kk].w = w1[(4 * kk + 3) * HD + j];
        wb[kk].x = w1[(HD + 4 * kk + 0) * HD + j];
        wb[kk].y = w1[(HD + 4 * kk + 1) * HD + j];
        wb[kk].z = w1[(HD + 4 * kk + 2) * HD + j];
        wb[kk].w = w1[(HD + 4 * kk + 3) * HD + j];
    }
    int n0 = blockIdx.x * NPB;
#pragma unroll
    for (int i = 0; i < 2; ++i)
        ((float4*)hr)[t + i * 256] = ((const float4*)(h + (size_t)n0 * HD))[t + i * 256];
    __syncthreads();
    for (int n = wv; n < NPB; n += 4) {
        const float4* hx = (const float4*)&hr[n * HD];
        float a1 = 0.0f, a2 = 0.0f;
#pragma unroll
        for (int kk = 0; kk < HD / 4; ++kk) {
            float4 hv = hx[kk];   // broadcast ds_read_b128
            a1 += hv.x * wa[kk].x + hv.y * wa[kk].y + hv.z * wa[kk].z + hv.w * wa[kk].w;
            a2 += hv.x * wb[kk].x + hv.y * wb[kk].y + hv.z * wb[kk].z + hv.w * wb[kk].w;
        }
        int node = n0 + n;
        u1b[(size_t)node * HD + j] = __float2bfloat16(a1);
        u2[(size_t)node * HD + j] = a2;
    }
}

// ---------- K7: CSR decode — wave/node, 16-lane groups, 8 edges/iter, width-16 reduce ----------
__global__ __launch_bounds__(256) void k_decode_csr(const int* __restrict__ row_ptr,
                                                    const int2* __restrict__ dec,
                                                    const uint2* __restrict__ u1r,  // bf16 x4 per lane
                                                    const float* __restrict__ u2,
                                                    const float* __restrict__ b1,
                                                    const float* __restrict__ w2,
                                                    const float* __restrict__ b2,
                                                    float* __restrict__ out) {
    int t = threadIdx.x;
    int node = blockIdx.x * 4 + (t >> 6);    // grid exact: N/4
    int lane = t & 63;
    int g = lane >> 4, li = lane & 15;
    float4 c4 = ((const float4*)(u2 + (size_t)node * HD))[li];
    float4 b14 = ((const float4*)b1)[li];
    float4 w4 = ((const float4*)w2)[li];
    c4.x += b14.x; c4.y += b14.y; c4.z += b14.z; c4.w += b14.w;
    float bb = b2[0];
    int start = row_ptr[node], end = row_ptr[node + 1];
    int i = start;
    for (; i + 8 <= end; i += 8) {
        int2 e0 = dec[i + g];
        int2 e1 = dec[i + 4 + g];
        uint2 ua = u1r[(size_t)e0.x * 16 + li];
        uint2 ub = u1r[(size_t)e1.x * 16 + li];
        float p0 = fmaxf(bf_lo(ua.x) + c4.x, 0.0f) * w4.x
                 + fmaxf(bf_hi(ua.x) + c4.y, 0.0f) * w4.y
                 + fmaxf(bf_lo(ua.y) + c4.z, 0.0f) * w4.z
                 + fmaxf(bf_hi(ua.y) + c4.w, 0.0f) * w4.w;
        float p1 = fmaxf(bf_lo(ub.x) + c4.x, 0.0f) * w4.x
                 + fmaxf(bf_hi(ub.x) + c4.y, 0.0f) * w4.y
                 + fmaxf(bf_lo(ub.y) + c4.z, 0.0f) * w4.z
                 + fmaxf(bf_hi(ub.y) + c4.w, 0.0f) * w4.w;
#pragma unroll
        for (int off = 8; off > 0; off >>= 1) {
            p0 += __shfl_down(p0, off, 16);
            p1 += __shfl_down(p1, off, 16);
        }
        if (li == 0) {
            if (e0.y >= 0) out[e0.y] = 1.0f / (1.0f + __expf(-(p0 + bb)));
            if (e1.y >= 0) out[e1.y] = 1.0f / (1.0f + __expf(-(p1 + bb)));
        }
    }
    for (; i < end; i += 4) {
        int idx = i + g;
        bool valid = idx < end;
        int2 e = dec[valid ? idx : end - 1];
        uint2 u = u1r[(size_t)e.x * 16 + li];
        float p = fmaxf(bf_lo(u.x) + c4.x, 0.0f) * w4.x
                + fmaxf(bf_hi(u.x) + c4.y, 0.0f) * w4.y
                + fmaxf(bf_lo(u.y) + c4.z, 0.0f) * w4.z
                + fmaxf(bf_hi(u.y) + c4.w, 0.0f) * w4.w;
#pragma unroll
        for (int off = 8; off > 0; off >>= 1) p += __shfl_down(p, off, 16);
        if (li == 0 && valid && e.y >= 0)
            out[e.y] = 1.0f / (1.0f + __expf(-(p + bb)));
    }
}

extern "C" void kernel_launch(void* const* d_in, const int* in_sizes, int n_in,
                              void* d_out, int out_size, void* d_ws, size_t ws_size,
                              hipStream_t stream) {
    const float* x        = (const float*)d_in[0];
    const int*   eidx     = (const int*)d_in[1];
    const float* eattr    = (const float*)d_in[2];
    const float* enc_w    = (const float*)d_in[3];
    const float* enc_b    = (const float*)d_in[4];
    const float* gat_w    = (const float*)d_in[5];
    const float* att_src  = (const float*)d_in[6];
    const float* att_dst  = (const float*)d_in[7];
    const float* edge_w   = (const float*)d_in[8];
    const float* att_edge = (const float*)d_in[9];
    const float* gat_b    = (const float*)d_in[10];
    const float* lp_w1    = (const float*)d_in[11];
    const float* lp_b1    = (const float*)d_in[12];
    const float* lp_w2    = (const float*)d_in[13];
    const float* lp_b2    = (const float*)d_in[14];
    float* out = (float*)d_out;

    const int* src = eidx;
    const int* dst = eidx + N_EDGES;

    // ---- workspace layout ----
    float* ws = (float*)d_ws;
    float*  h       = ws;                                   // N*64 f32 (u2 after k_umm)
    // bucket records (16B AoS) alias h AND xpb (28.8MB of their combined 38.4MB):
    // live only from k_mean_edterm to k_sort_build — before k_xp0 writes xpb and
    // before k_aggregate<0> writes h.
    int*    bkt     = (int*)h;                              // NBKT*BKT_CAP*16B = 28.8MB
    __hip_bfloat16* xpb = (__hip_bfloat16*)(h + (size_t)N_NODES * HD);  // N*64 bf16 (u1b after k_umm)
    int2*   agg     = (int2*)((char*)xpb + (size_t)N_NODES * HD * 2);   // E_SL int2 (13.6MB)
    int2*   dec     = agg + E_SL;                           // E_SL int2 (13.6MB)
    float*  fsmall    = (float*)(dec + E_SL);
    float*  s_src     = fsmall;                             // N
    float*  s_dst     = s_src + N_NODES;                    // N
    float*  partials  = s_dst + N_NODES;                    // PART_CH*8 (20000)
    float*  we_vec    = partials + PART_CH * 8;             // 16
    uint*   ltp       = (uint*)(we_vec + 16);               // 1
    float*  Wc        = (float*)(ltp + 1);                  // 32*64
    float*  bc        = Wc + F_INN * HD;                    // 64
    int*    row_ptr   = (int*)(bc + HD);                    // N+1
    int*    bkt_pos   = row_ptr + N_NODES + 1;              // NBKT
    int*    bktbase   = bkt_pos + NBKT;                     // NBKT

    const int NB_AGG  = N_NODES / 4;             // 25000
    const int NB_DENSE = N_NODES / NPB;          // 3125

    // small precomputes + fused edge pass (mean partials, LDS-sorted bucket flush)
    k_init_small<<<1, 64, 0, stream>>>(edge_w, att_edge, we_vec);
    k_fuse_w<<<1, 256, 0, stream>>>(enc_w, enc_b, gat_w, Wc, bc);
    k_zero<<<1, 256, 0, stream>>>(bkt_pos);
    k_mean_edterm<<<ME_BLOCKS, 256, 0, stream>>>(eattr, src, dst, we_vec,
                                                 partials, bkt, bkt_pos);
    k_mean_final<<<1, 256, 0, stream>>>(partials, we_vec, ltp);

    // CSR build: bucket-count scan -> per-bucket LDS counting sort (writes
    // row_ptr itself — deg histogram and the 100K-node scan kernels are gone)
    k_bktscan<<<1, 256, 0, stream>>>(bkt_pos, bktbase, row_ptr);
    k_sort_build<<<NBKT, SB_THREADS, 0, stream>>>(bkt_pos, bkt, bktbase, ltp,
                                                  agg, dec, row_ptr);

    // layer-0 projection (encoder folded into Wc/bc)
    k_xp0<<<NB_DENSE, 256, 0, stream>>>(x, Wc, bc, att_src, att_dst, xpb, s_src, s_dst);
    k_aggregate<0><<<NB_AGG, 256, 0, stream>>>(row_ptr, agg, s_src, s_dst,
                                               (const uint2*)xpb, gat_b, h);
    // GAT layer 1
    k_xp<<<NB_DENSE, 256, 0, stream>>>(h, gat_w + HD * HD, att_src + HD, att_dst + HD,
                                       xpb, s_src, s_dst);
    k_aggregate<1><<<NB_AGG, 256, 0, stream>>>(row_ptr, agg, s_src, s_dst,
                                               (const uint2*)xpb, gat_b + HD, h);

    // decoder: u1(bf16) -> xpb buffer, u2(fp32) -> h buffer
    k_umm<<<NB_DENSE, 256, 0, stream>>>(h, lp_w1, xpb, h);
    k_decode_csr<<<NB_AGG, 256, 0, stream>>>(row_ptr, dec, (const uint2*)xpb, h,
                                             lp_b1, lp_w2, lp_b2, out);
}

// Round 5
// 461.043 us; speedup vs baseline: 1.3672x; 1.0157x over previous
//
#include <hip/hip_runtime.h>
#include <hip/hip_bf16.h>
#include <math.h>

#define N_NODES 100000
#define N_EDGES 1600000
#define F_INN   32
#define F_EE    8
#define HD      64
#define E_SL    (N_EDGES + N_NODES)   // edges + self loops
#define NEG_SLOPE 0.2f
#define NPB 32                        // nodes per block in dense kernels (3125 blocks)

// dst-range bucketing fused into the edge pass. 250 buckets of 400 nodes.
// Records are 8B {src|dl<<17, pack} — decode no longer needs the edge id
// (it runs in original edge order), so records shrink 16->8B: halves bucket
// traffic and edterm's LDS staging (40->20KB, occupancy x2).
#define NBKT 250
#define BKT_W (N_NODES / NBKT)        // 400 nodes per bucket
#define BKT_CAP 7200                  // mean 6400 + 10 sigma — overflow prob ~1e-13
#define ME_UNR 10
#define ME_CHUNK (256 * ME_UNR)       // 2560 edges per block
#define ME_BLOCKS (N_EDGES / ME_CHUNK)   // 625
#define PART_CH (ME_BLOCKS * 4)       // 2500 wave partials
#define SB_THREADS 512
#define SEL_CAP (BKT_CAP + BKT_W)     // 7600

// ---------- helpers ----------
__device__ __forceinline__ float waveReduceSum(float v) {
#pragma unroll
    for (int off = 32; off > 0; off >>= 1) v += __shfl_down(v, off, 64);
    return v;
}
__device__ __forceinline__ float bf_lo(uint u) { return __uint_as_float(u << 16); }
__device__ __forceinline__ float bf_hi(uint u) { return __uint_as_float(u & 0xffff0000u); }
__device__ __forceinline__ uint pack_bf2(float a, float b) {
    __hip_bfloat16 ha = __float2bfloat16(a), hb = __float2bfloat16(b);
    unsigned short ua, ub;
    __builtin_memcpy(&ua, &ha, 2); __builtin_memcpy(&ub, &hb, 2);
    return (uint)ua | ((uint)ub << 16);
}

// ---------- K1: we_vec[l][k] = dot(edge_w[l][k,:], att_edge[l,:]) ----------
__global__ void k_init_small(const float* __restrict__ edge_w, const float* __restrict__ att_edge,
                             float* __restrict__ we_vec) {
    int t = threadIdx.x;
    if (t < 16) {
        int l = t >> 3, k = t & 7;
        const float* We = edge_w + l * F_EE * HD + k * HD;
        const float* ae = att_edge + l * HD;
        float s = 0.0f;
#pragma unroll
        for (int j = 0; j < HD; ++j) s += We[j] * ae[j];
        we_vec[l * 8 + k] = s;
    }
}

// ---------- K1b: fold encoder into layer-0 projection: Wc = enc_w@W0, bc = enc_b@W0 ----------
__global__ __launch_bounds__(256) void k_fuse_w(const float* __restrict__ enc_w,
                                                const float* __restrict__ enc_b,
                                                const float* __restrict__ W0,
                                                float* __restrict__ Wc, float* __restrict__ bc) {
    int t = threadIdx.x;
    for (int idx = t; idx < F_INN * HD; idx += 256) {
        int r = idx >> 6, c = idx & 63;
        float s = 0.0f;
#pragma unroll
        for (int k = 0; k < HD; ++k) s += enc_w[r * HD + k] * W0[k * HD + c];
        Wc[idx] = s;
    }
    if (t < HD) {
        float s = 0.0f;
#pragma unroll
        for (int k = 0; k < HD; ++k) s += enc_b[k] * W0[k * HD + t];
        bc[t] = s;
    }
}

// ---------- K0: zero bucket counters ----------
__global__ void k_zero(int* __restrict__ bkt_pos) {
    int t = threadIdx.x;
    if (t < NBKT) bkt_pos[t] = 0;
}

// ---------- K2a: fused — mean partials, edge-term compute, LDS-sorted bucket flush ----------
// Per 2560-edge chunk: records kept in registers, LDS 250-bin histogram ->
// exclusive scan -> one global reservation per (block,bucket) -> records placed
// bucket-sorted in LDS -> per-bucket WAVE-CONTIGUOUS uint2 flush.
__global__ __launch_bounds__(256) void k_mean_edterm(const float* __restrict__ eattr,
                                                     const int* __restrict__ src,
                                                     const int* __restrict__ dst,
                                                     const float* __restrict__ we_vec,
                                                     float* __restrict__ partials,
                                                     uint* __restrict__ bkt,
                                                     int* __restrict__ bkt_pos) {
    __shared__ float sw[16];
    __shared__ int hist[NBKT];     // count, then LDS cursor, then chunk size
    __shared__ int lstart[256];    // scan array -> exclusive LDS record offsets
    __shared__ int gstart[NBKT];   // reserved global record offsets
    __shared__ uint recs[ME_CHUNK * 2];   // 20 KB staged 8B records
    int t = threadIdx.x;
    if (t < 16) sw[t] = we_vec[t];
    if (t < NBKT) hist[t] = 0;
    __syncthreads();
    float p[8];
#pragma unroll
    for (int k = 0; k < 8; ++k) p[k] = 0.0f;
    int e0 = blockIdx.x * ME_CHUNK;
    int rs[ME_UNR]; uint rp[ME_UNR]; int rb[ME_UNR];   // rb = (bucket<<16)|d_local
#pragma unroll
    for (int u = 0; u < ME_UNR; ++u) {
        int e = e0 + u * 256 + t;
        const float4* row = (const float4*)(eattr + (size_t)e * F_EE);
        float4 r0 = row[0], r1 = row[1];
        p[0] += r0.x; p[1] += r0.y; p[2] += r0.z; p[3] += r0.w;
        p[4] += r1.x; p[5] += r1.y; p[6] += r1.z; p[7] += r1.w;
        float ed0 = r0.x * sw[0] + r0.y * sw[1] + r0.z * sw[2] + r0.w * sw[3]
                  + r1.x * sw[4] + r1.y * sw[5] + r1.z * sw[6] + r1.w * sw[7];
        float ed1 = r0.x * sw[8] + r0.y * sw[9] + r0.z * sw[10] + r0.w * sw[11]
                  + r1.x * sw[12] + r1.y * sw[13] + r1.z * sw[14] + r1.w * sw[15];
        rs[u] = src[e];
        rp[u] = pack_bf2(ed0, ed1);
        int d = dst[e];
        int b = d / BKT_W;
        rb[u] = (b << 16) | (d - b * BKT_W);
        atomicAdd(&hist[b], 1);
    }
    __syncthreads();
    // exclusive scan of per-bucket counts -> LDS chunk offsets
    lstart[t] = (t < NBKT) ? hist[t] : 0;
    __syncthreads();
    for (int off = 1; off < 256; off <<= 1) {
        int x = (t >= off) ? lstart[t - off] : 0;
        __syncthreads();
        lstart[t] += x;
        __syncthreads();
    }
    if (t < NBKT) {
        int v = hist[t];
        gstart[t] = atomicAdd(&bkt_pos[t], v);   // exact reservation, no padding
        lstart[t] -= v;                          // inclusive -> exclusive
        hist[t] = 0;                             // reuse as placement cursor
    }
    __syncthreads();
    // place records bucket-sorted into LDS: 8B record = {src | dl<<17, pack}
#pragma unroll
    for (int u = 0; u < ME_UNR; ++u) {
        int b = rb[u] >> 16, dl = rb[u] & 0xFFFF;
        int l = atomicAdd(&hist[b], 1);
        ((uint2*)recs)[lstart[b] + l] = make_uint2((uint)rs[u] | ((uint)dl << 17), rp[u]);
    }
    __syncthreads();
    // per-bucket wave-contiguous flush
    int w = t >> 6, lane = t & 63;
    uint2* gb2 = (uint2*)bkt;
    for (int b = w; b < NBKT; b += 4) {
        int n = hist[b];
        int ls = lstart[b];
        int gs = gstart[b];
        for (int off = lane; off < n; off += 64)
            if (gs + off < BKT_CAP)
                gb2[(size_t)b * BKT_CAP + gs + off] = ((const uint2*)recs)[ls + off];
    }
#pragma unroll
    for (int k = 0; k < 8; ++k) p[k] = waveReduceSum(p[k]);
    if ((t & 63) == 0) {
        float* dstp = partials + ((size_t)blockIdx.x * 4 + w) * 8;
#pragma unroll
        for (int k = 0; k < 8; ++k) dstp[k] = p[k];
    }
}

// ---------- K2b: finish mean; ltp = packed bf16 {loop_term0, loop_term1} ----------
__global__ __launch_bounds__(256) void k_mean_final(const float* __restrict__ partials,
                                                    const float* __restrict__ we_vec,
                                                    uint* __restrict__ ltp) {
    __shared__ float red[256];
    __shared__ float mean8[8];
    __shared__ float lt[2];
    int t = threadIdx.x;
    int k = t & 7;
    int chunk = t >> 3;
    float s = 0.0f;
    for (int i = chunk; i < PART_CH; i += 32) s += partials[(size_t)i * 8 + k];
    red[t] = s;
    __syncthreads();
    if (t < 8) {
        float acc = 0.0f;
#pragma unroll
        for (int c = 0; c < 32; ++c) acc += red[c * 8 + t];
        mean8[t] = acc * (1.0f / N_EDGES);
    }
    __syncthreads();
    if (t < 2) {
        float acc = 0.0f;
#pragma unroll
        for (int kk = 0; kk < 8; ++kk) acc += mean8[kk] * we_vec[t * 8 + kk];
        lt[t] = acc;
    }
    __syncthreads();
    if (t == 0) ltp[0] = pack_bf2(lt[0], lt[1]);
}

// ---------- K2c: scan bucket counts -> bucket CSR bases ----------
__global__ void k_bktscan(const int* __restrict__ bkt_pos, int* __restrict__ bktbase,
                          int* __restrict__ row_ptr) {
    __shared__ int sd[256];
    int t = threadIdx.x;
    int v = (t < NBKT) ? min(bkt_pos[t], BKT_CAP) + BKT_W : 0;
    sd[t] = v;
    __syncthreads();
    for (int off = 1; off < 256; off <<= 1) {
        int x = (t >= off) ? sd[t - off] : 0;
        __syncthreads();
        sd[t] += x;
        __syncthreads();
    }
    if (t < NBKT) bktbase[t] = sd[t] - v;
    if (t == 0) row_ptr[N_NODES] = E_SL;
}

// kB: one block per bucket. Counting-sort the bucket's ~6400 8B records in LDS
// (per-node hist -> scan -> u16 rank array with self-loop slots interleaved),
// write row_ptr for its 400 nodes, then write agg as a FULLY CONTIGUOUS
// coalesced stream. dec is gone — decode runs in edge order.
__global__ __launch_bounds__(SB_THREADS) void k_sort_build(const int* __restrict__ bkt_pos,
                                                           const uint* __restrict__ bkt,
                                                           const int* __restrict__ bktbase,
                                                           const uint* __restrict__ ltp,
                                                           int2* __restrict__ agg,
                                                           int* __restrict__ row_ptr) {
    __shared__ int S[BKT_W];                 // inclusive scan of per-node counts
    __shared__ int cur[BKT_W];               // hist, then rank cursor
    __shared__ unsigned short sel[SEL_CAP];  // local position -> record idx | selfloop
    int b = blockIdx.x;
    int t = threadIdx.x;
    int cnt = min(bkt_pos[b], BKT_CAP);
    const uint2* bp = (const uint2*)bkt + (size_t)b * BKT_CAP;
    if (t < BKT_W) cur[t] = 0;
    __syncthreads();
    for (int i = t; i < cnt; i += SB_THREADS) {
        uint2 v = bp[i];                     // streams bucket through L2
        atomicAdd(&cur[v.x >> 17], 1);
    }
    __syncthreads();
    if (t < BKT_W) S[t] = cur[t];
    for (int off = 1; off < BKT_W; off <<= 1) {
        __syncthreads();
        int x = (t >= off && t < BKT_W) ? S[t - off] : 0;
        __syncthreads();
        if (t < BKT_W) S[t] += x;
    }
    __syncthreads();
    int n0 = b * BKT_W;
    int gb = bktbase[b];
    if (t < BKT_W) {
        row_ptr[n0 + t] = gb + (t == 0 ? 0 : S[t - 1]) + t;   // excl scan of (cnt+1)
        cur[t] = 0;
        sel[S[t] + t] = (unsigned short)(0x8000 | t);   // self-loop slot (segment end)
    }
    __syncthreads();
    for (int i = t; i < cnt; i += SB_THREADS) {
        int dl = (int)(bp[i].x >> 17);       // L2 re-read
        int r = atomicAdd(&cur[dl], 1);
        int nb = (dl == 0) ? 0 : S[dl - 1];
        sel[nb + dl + r] = (unsigned short)i;
    }
    __syncthreads();
    int total = cnt + BKT_W;
    uint lt = ltp[0];
    for (int p = t; p < total; p += SB_THREADS) {
        unsigned short v = sel[p];
        int2 a;
        if (v & 0x8000) {
            a = make_int2(n0 + (v & 0x7fff), (int)lt);
        } else {
            uint2 r = bp[v];                 // random read within resident bucket
            a = make_int2((int)(r.x & 0x1FFFFu), (int)r.y);
        }
        agg[gb + p] = a;                     // contiguous coalesced stream
    }
}

// ---------- K3: layer-0 projection xp = x@Wc + bc — weight column in VGPRs, x broadcast via LDS ----------
__global__ __launch_bounds__(256) void k_xp0(const float* __restrict__ x,
                                             const float* __restrict__ Wc,
                                             const float* __restrict__ bc,
                                             const float* __restrict__ a_src,
                                             const float* __restrict__ a_dst,
                                             __hip_bfloat16* __restrict__ xpb,
                                             float* __restrict__ s_src,
                                             float* __restrict__ s_dst) {
    __shared__ float xr[NPB * F_INN];  // 4 KB
    int t = threadIdx.x;
    int j = t & 63, wv = t >> 6;
    float4 w[F_INN / 4];               // 8 VGPR float4s = weight column j
#pragma unroll
    for (int kk = 0; kk < F_INN / 4; ++kk) {
        w[kk].x = Wc[(4 * kk + 0) * HD + j];
        w[kk].y = Wc[(4 * kk + 1) * HD + j];
        w[kk].z = Wc[(4 * kk + 2) * HD + j];
        w[kk].w = Wc[(4 * kk + 3) * HD + j];
    }
    int n0 = blockIdx.x * NPB;
    ((float4*)xr)[t] = ((const float4*)(x + (size_t)n0 * F_INN))[t];  // 256*16B = 4KB exact
    __syncthreads();
    float asj = a_src[j], adj = a_dst[j], bcj = bc[j];
    for (int n = wv; n < NPB; n += 4) {
        const float4* hx = (const float4*)&xr[n * F_INN];
        float acc = bcj;
#pragma unroll
        for (int kk = 0; kk < F_INN / 4; ++kk) {
            float4 hv = hx[kk];   // wave-uniform broadcast ds_read_b128
            acc += hv.x * w[kk].x + hv.y * w[kk].y + hv.z * w[kk].z + hv.w * w[kk].w;
        }
        int node = n0 + n;
        xpb[(size_t)node * HD + j] = __float2bfloat16(acc);
        float ts = waveReduceSum(acc * asj);
        float td = waveReduceSum(acc * adj);
        if (j == 0) { s_src[node] = ts; s_dst[node] = td; }
    }
}

// ---------- K4: xp(bf16) = h @ W (layer 1) — weight column in VGPRs ----------
__global__ __launch_bounds__(256) void k_xp(const float* __restrict__ h, const float* __restrict__ W,
                                            const float* __restrict__ a_src, const float* __restrict__ a_dst,
                                            __hip_bfloat16* __restrict__ xpb, float* __restrict__ s_src,
                                            float* __restrict__ s_dst) {
    __shared__ float hr[NPB * HD];     // 8 KB
    int t = threadIdx.x;
    int j = t & 63, wv = t >> 6;
    float4 w[HD / 4];                  // 16 float4s = 64 VGPRs
#pragma unroll
    for (int kk = 0; kk < HD / 4; ++kk) {
        w[kk].x = W[(4 * kk + 0) * HD + j];
        w[kk].y = W[(4 * kk + 1) * HD + j];
        w[kk].z = W[(4 * kk + 2) * HD + j];
        w[kk].w = W[(4 * kk + 3) * HD + j];
    }
    int n0 = blockIdx.x * NPB;
#pragma unroll
    for (int i = 0; i < 2; ++i)
        ((float4*)hr)[t + i * 256] = ((const float4*)(h + (size_t)n0 * HD))[t + i * 256];
    __syncthreads();
    float asj = a_src[j], adj = a_dst[j];
    for (int n = wv; n < NPB; n += 4) {
        const float4* hx = (const float4*)&hr[n * HD];
        float acc = 0.0f;
#pragma unroll
        for (int kk = 0; kk < HD / 4; ++kk) {
            float4 hv = hx[kk];   // broadcast ds_read_b128
            acc += hv.x * w[kk].x + hv.y * w[kk].y + hv.z * w[kk].z + hv.w * w[kk].w;
        }
        int node = n0 + n;
        xpb[(size_t)node * HD + j] = __float2bfloat16(acc);
        float ts = waveReduceSum(acc * asj);
        float td = waveReduceSum(acc * adj);
        if (j == 0) { s_src[node] = ts; s_dst[node] = td; }
    }
}

// ---------- K5: gather-aggregate — wave/node, 16-lane groups, 8 edges/iter in flight ----------
template <int LAYER>
__global__ __launch_bounds__(256) void k_aggregate(const int* __restrict__ row_ptr,
                                                   const int2* __restrict__ agg,
                                                   const float* __restrict__ s_src,
                                                   const float* __restrict__ s_dst,
                                                   const uint2* __restrict__ xpr,   // bf16 x4 per lane
                                                   const float* __restrict__ bias,
                                                   float* __restrict__ h) {
    int t = threadIdx.x;
    int node = blockIdx.x * 4 + (t >> 6);    // grid exact: N/4
    int lane = t & 63;
    int g = lane >> 4, li = lane & 15;
    int start = row_ptr[node], end = row_ptr[node + 1];
    float sd = s_dst[node];
    float ax = 0.0f, ay = 0.0f, az = 0.0f, aw = 0.0f, den = 0.0f;
    int i = start;
    for (; i + 8 <= end; i += 8) {
        int2 r0 = agg[i + g];
        int2 r1 = agg[i + 4 + g];
        int sp0 = r0.x, sp1 = r1.x;
        uint2 u0 = xpr[(size_t)sp0 * 16 + li];
        uint2 u1 = xpr[(size_t)sp1 * 16 + li];
        float a0 = s_src[sp0] + sd + (LAYER == 0 ? bf_lo((uint)r0.y) : bf_hi((uint)r0.y));
        float a1 = s_src[sp1] + sd + (LAYER == 0 ? bf_lo((uint)r1.y) : bf_hi((uint)r1.y));
        a0 = a0 > 0.0f ? a0 : NEG_SLOPE * a0;
        a1 = a1 > 0.0f ? a1 : NEG_SLOPE * a1;
        float ex0 = __expf(a0), ex1 = __expf(a1);
        den += ex0 + ex1;
        ax += ex0 * bf_lo(u0.x) + ex1 * bf_lo(u1.x);
        ay += ex0 * bf_hi(u0.x) + ex1 * bf_hi(u1.x);
        az += ex0 * bf_lo(u0.y) + ex1 * bf_lo(u1.y);
        aw += ex0 * bf_hi(u0.y) + ex1 * bf_hi(u1.y);
    }
    for (; i < end; i += 4) {
        int idx = i + g;
        bool valid = idx < end;
        int2 r = agg[valid ? idx : end - 1];
        int sp = r.x;
        uint2 u = xpr[(size_t)sp * 16 + li];
        float a = s_src[sp] + sd + (LAYER == 0 ? bf_lo((uint)r.y) : bf_hi((uint)r.y));
        a = a > 0.0f ? a : NEG_SLOPE * a;
        float ex = valid ? __expf(a) : 0.0f;
        den += ex;
        ax += ex * bf_lo(u.x);
        ay += ex * bf_hi(u.x);
        az += ex * bf_lo(u.y);
        aw += ex * bf_hi(u.y);
    }
    den += __shfl_down(den, 32, 64); ax += __shfl_down(ax, 32, 64);
    ay  += __shfl_down(ay, 32, 64); az += __shfl_down(az, 32, 64);
    aw  += __shfl_down(aw, 32, 64);
    den += __shfl_down(den, 16, 64); ax += __shfl_down(ax, 16, 64);
    ay  += __shfl_down(ay, 16, 64); az += __shfl_down(az, 16, 64);
    aw  += __shfl_down(aw, 16, 64);
    if (lane < 16) {
        float inv = 1.0f / (den + 1e-16f);
        float4 b4 = ((const float4*)bias)[li];
        float4 v;
        v.x = fmaxf(ax * inv + b4.x, 0.0f);
        v.y = fmaxf(ay * inv + b4.y, 0.0f);
        v.z = fmaxf(az * inv + b4.z, 0.0f);
        v.w = fmaxf(aw * inv + b4.w, 0.0f);
        ((float4*)(h + (size_t)node * HD))[li] = v;
    }
}

// ---------- K6: u1(bf16)=h@W1a, u2b(bf16)=h@W1b + b1 — both weight columns in VGPRs ----------
__global__ __launch_bounds__(256) void k_umm(const float* __restrict__ h, const float* __restrict__ w1,
                                             const float* __restrict__ b1,
                                             __hip_bfloat16* __restrict__ u1b,
                                             __hip_bfloat16* __restrict__ u2b) {
    __shared__ float hr[NPB * HD];     // 8 KB
    int t = threadIdx.x;
    int j = t & 63, wv = t >> 6;
    float4 wa[HD / 4], wb[HD / 4];     // 128 VGPRs
#pragma unroll
    for (int kk = 0; kk < HD / 4; ++kk) {
        wa[kk].x = w1[(4 * kk + 0) * HD + j];
        wa[kk].y = w1[(4 * kk + 1) * HD + j];
        wa[kk].z = w1[(4 * kk + 2) * HD + j];
        wa[kk].w = w1[(4 * kk + 3) * HD + j];
        wb[kk].x = w1[(HD + 4 * kk + 0) * HD + j];
        wb[kk].y = w1[(HD + 4 * kk + 1) * HD + j];
        wb[kk].z = w1[(HD + 4 * kk + 2) * HD + j];
        wb[kk].w = w1[(HD + 4 * kk + 3) * HD + j];
    }
    float b1j = b1[j];
    int n0 = blockIdx.x * NPB;
#pragma unroll
    for (int i = 0; i < 2; ++i)
        ((float4*)hr)[t + i * 256] = ((const float4*)(h + (size_t)n0 * HD))[t + i * 256];
    __syncthreads();
    for (int n = wv; n < NPB; n += 4) {
        const float4* hx = (const float4*)&hr[n * HD];
        float a1 = 0.0f, a2 = 0.0f;
#pragma unroll
        for (int kk = 0; kk < HD / 4; ++kk) {
            float4 hv = hx[kk];   // broadcast ds_read_b128
            a1 += hv.x * wa[kk].x + hv.y * wa[kk].y + hv.z * wa[kk].z + hv.w * wa[kk].w;
            a2 += hv.x * wb[kk].x + hv.y * wb[kk].y + hv.z * wb[kk].z + hv.w * wb[kk].w;
        }
        int node = n0 + n;
        u1b[(size_t)node * HD + j] = __float2bfloat16(a1);
        u2b[(size_t)node * HD + j] = __float2bfloat16(a2 + b1j);
    }
}

// ---------- K7: edge-order decode — out writes COALESCED (one full line per
// block), dec eliminated. Per edge: two random 128B bf16 row gathers
// (u1[src], u2'[dst]) — r4 showed the CSR decode paid 54MB (8x) scattered-out
// amplification + 13.6MB dec; edge order trades those for L2/L3-absorbed gathers.
__global__ __launch_bounds__(256) void k_decode_edge(const int* __restrict__ src,
                                                     const int* __restrict__ dst,
                                                     const uint2* __restrict__ u1r,
                                                     const uint2* __restrict__ u2r,
                                                     const float* __restrict__ w2,
                                                     const float* __restrict__ b2,
                                                     float* __restrict__ out) {
    __shared__ int sld[64];
    int t = threadIdx.x;
    int e0 = blockIdx.x * 32;            // grid exact: E/32 blocks
    if (t < 32) sld[t] = src[e0 + t];
    else if (t < 64) sld[t] = dst[e0 + t - 32];
    __syncthreads();
    int g = t >> 4, li = t & 15;         // 16 groups of 16 lanes, 2 edges/group
    float4 w4 = ((const float4*)w2)[li];
    float bb = b2[0];
    int sa = sld[g],      da = sld[32 + g];
    int sb = sld[16 + g], db = sld[48 + g];
    uint2 a1 = u1r[(size_t)sa * 16 + li];
    uint2 a2 = u2r[(size_t)da * 16 + li];
    uint2 bq1 = u1r[(size_t)sb * 16 + li];
    uint2 bq2 = u2r[(size_t)db * 16 + li];
    float p0 = fmaxf(bf_lo(a1.x) + bf_lo(a2.x), 0.0f) * w4.x
             + fmaxf(bf_hi(a1.x) + bf_hi(a2.x), 0.0f) * w4.y
             + fmaxf(bf_lo(a1.y) + bf_lo(a2.y), 0.0f) * w4.z
             + fmaxf(bf_hi(a1.y) + bf_hi(a2.y), 0.0f) * w4.w;
    float p1 = fmaxf(bf_lo(bq1.x) + bf_lo(bq2.x), 0.0f) * w4.x
             + fmaxf(bf_hi(bq1.x) + bf_hi(bq2.x), 0.0f) * w4.y
             + fmaxf(bf_lo(bq1.y) + bf_lo(bq2.y), 0.0f) * w4.z
             + fmaxf(bf_hi(bq1.y) + bf_hi(bq2.y), 0.0f) * w4.w;
#pragma unroll
    for (int off = 8; off > 0; off >>= 1) {
        p0 += __shfl_down(p0, off, 16);
        p1 += __shfl_down(p1, off, 16);
    }
    if (li == 0) {
        out[e0 + g]      = 1.0f / (1.0f + __expf(-(p0 + bb)));
        out[e0 + 16 + g] = 1.0f / (1.0f + __expf(-(p1 + bb)));
    }
}

extern "C" void kernel_launch(void* const* d_in, const int* in_sizes, int n_in,
                              void* d_out, int out_size, void* d_ws, size_t ws_size,
                              hipStream_t stream) {
    const float* x        = (const float*)d_in[0];
    const int*   eidx     = (const int*)d_in[1];
    const float* eattr    = (const float*)d_in[2];
    const float* enc_w    = (const float*)d_in[3];
    const float* enc_b    = (const float*)d_in[4];
    const float* gat_w    = (const float*)d_in[5];
    const float* att_src  = (const float*)d_in[6];
    const float* att_dst  = (const float*)d_in[7];
    const float* edge_w   = (const float*)d_in[8];
    const float* att_edge = (const float*)d_in[9];
    const float* gat_b    = (const float*)d_in[10];
    const float* lp_w1    = (const float*)d_in[11];
    const float* lp_b1    = (const float*)d_in[12];
    const float* lp_w2    = (const float*)d_in[13];
    const float* lp_b2    = (const float*)d_in[14];
    float* out = (float*)d_out;

    const int* src = eidx;
    const int* dst = eidx + N_EDGES;

    // ---- workspace layout ----
    float* ws = (float*)d_ws;
    float*  h       = ws;                                   // N*64 f32
    // 8B bucket records alias the h region (14.4MB of 25.6MB): live only from
    // k_mean_edterm to k_sort_build — before k_aggregate<0> writes h.
    uint*   bkt     = (uint*)h;                             // NBKT*BKT_CAP*8B = 14.4MB
    __hip_bfloat16* xpb = (__hip_bfloat16*)(h + (size_t)N_NODES * HD);  // N*64 bf16 (u1b after k_umm)
    int2*   agg     = (int2*)((char*)xpb + (size_t)N_NODES * HD * 2);   // E_SL int2 (13.6MB; u2b after k_umm)
    float*  fsmall    = (float*)(agg + E_SL);
    float*  s_src     = fsmall;                             // N
    float*  s_dst     = s_src + N_NODES;                    // N
    float*  partials  = s_dst + N_NODES;                    // PART_CH*8 (20000)
    float*  we_vec    = partials + PART_CH * 8;             // 16
    uint*   ltp       = (uint*)(we_vec + 16);               // 1
    float*  Wc        = (float*)(ltp + 1);                  // 32*64
    float*  bc        = Wc + F_INN * HD;                    // 64
    int*    row_ptr   = (int*)(bc + HD);                    // N+1
    int*    bkt_pos   = row_ptr + N_NODES + 1;              // NBKT
    int*    bktbase   = bkt_pos + NBKT;                     // NBKT

    const int NB_AGG  = N_NODES / 4;             // 25000
    const int NB_DENSE = N_NODES / NPB;          // 3125
    const int NB_DEC  = N_EDGES / 32;            // 50000

    // small precomputes + fused edge pass (mean partials, LDS-sorted bucket flush)
    k_init_small<<<1, 64, 0, stream>>>(edge_w, att_edge, we_vec);
    k_fuse_w<<<1, 256, 0, stream>>>(enc_w, enc_b, gat_w, Wc, bc);
    k_zero<<<1, 256, 0, stream>>>(bkt_pos);
    k_mean_edterm<<<ME_BLOCKS, 256, 0, stream>>>(eattr, src, dst, we_vec,
                                                 partials, bkt, bkt_pos);
    k_mean_final<<<1, 256, 0, stream>>>(partials, we_vec, ltp);

    // CSR build: bucket-count scan -> per-bucket LDS counting sort
    k_bktscan<<<1, 256, 0, stream>>>(bkt_pos, bktbase, row_ptr);
    k_sort_build<<<NBKT, SB_THREADS, 0, stream>>>(bkt_pos, bkt, bktbase, ltp,
                                                  agg, row_ptr);

    // layer-0 projection (encoder folded into Wc/bc)
    k_xp0<<<NB_DENSE, 256, 0, stream>>>(x, Wc, bc, att_src, att_dst, xpb, s_src, s_dst);
    k_aggregate<0><<<NB_AGG, 256, 0, stream>>>(row_ptr, agg, s_src, s_dst,
                                               (const uint2*)xpb, gat_b, h);
    // GAT layer 1
    k_xp<<<NB_DENSE, 256, 0, stream>>>(h, gat_w + HD * HD, att_src + HD, att_dst + HD,
                                       xpb, s_src, s_dst);
    k_aggregate<1><<<NB_AGG, 256, 0, stream>>>(row_ptr, agg, s_src, s_dst,
                                               (const uint2*)xpb, gat_b + HD, h);

    // decoder: u1b -> xpb buffer, u2b(+b1) -> agg buffer (both dead by now);
    // decode in ORIGINAL edge order (coalesced out, no dec array)
    k_umm<<<NB_DENSE, 256, 0, stream>>>(h, lp_w1, lp_b1, xpb,
                                        (__hip_bfloat16*)agg);
    k_decode_edge<<<NB_DEC, 256, 0, stream>>>(src, dst, (const uint2*)xpb,
                                              (const uint2*)agg, lp_w2, lp_b2, out);
}

// Round 7
// 456.595 us; speedup vs baseline: 1.3805x; 1.0097x over previous
//
#include <hip/hip_runtime.h>
#include <hip/hip_bf16.h>
#include <math.h>

#define N_NODES 100000
#define N_EDGES 1600000
#define F_INN   32
#define F_EE    8
#define HD      64
#define E_SL    (N_EDGES + N_NODES)   // edges + self loops
#define NEG_SLOPE 0.2f
#define NPB 32                        // nodes per block in dense kernels (3125 blocks)

// dst-range bucketing fused into the edge pass. 250 buckets of 400 nodes.
// 8B records {src|dl<<17, pack}; LDS-sorted per block, flushed wave-contiguous.
#define NBKT 250
#define BKT_W (N_NODES / NBKT)        // 400 nodes per bucket
#define BKT_CAP 7200                  // mean 6400 + 10 sigma — overflow prob ~1e-13
#define ME_UNR 10
#define ME_CHUNK (256 * ME_UNR)       // 2560 edges per block
#define ME_BLOCKS (N_EDGES / ME_CHUNK)   // 625
#define PART_CH (ME_BLOCKS * 4)       // 2500 wave partials
#define SB_THREADS 512
#define SEL_CAP (BKT_CAP + BKT_W)     // 7600

// ---------- helpers ----------
__device__ __forceinline__ float waveReduceSum(float v) {
#pragma unroll
    for (int off = 32; off > 0; off >>= 1) v += __shfl_down(v, off, 64);
    return v;
}
__device__ __forceinline__ float bf_lo(uint u) { return __uint_as_float(u << 16); }
__device__ __forceinline__ float bf_hi(uint u) { return __uint_as_float(u & 0xffff0000u); }
__device__ __forceinline__ uint pack_bf2(float a, float b) {
    __hip_bfloat16 ha = __float2bfloat16(a), hb = __float2bfloat16(b);
    unsigned short ua, ub;
    __builtin_memcpy(&ua, &ha, 2); __builtin_memcpy(&ub, &hb, 2);
    return (uint)ua | ((uint)ub << 16);
}

// ---------- K1: merged setup — we_vec, Wc/bc fold, bucket-counter zero ----------
// (was 3 kernels: init_small + fuse_w + zero; all parts independent, 1 block)
__global__ __launch_bounds__(256) void k_setup(const float* __restrict__ edge_w,
                                               const float* __restrict__ att_edge,
                                               const float* __restrict__ enc_w,
                                               const float* __restrict__ enc_b,
                                               const float* __restrict__ W0,
                                               float* __restrict__ we_vec,
                                               float* __restrict__ Wc, float* __restrict__ bc,
                                               int* __restrict__ bkt_pos) {
    int t = threadIdx.x;
    if (t < 16) {
        int l = t >> 3, k = t & 7;
        const float* We = edge_w + l * F_EE * HD + k * HD;
        const float* ae = att_edge + l * HD;
        float s = 0.0f;
#pragma unroll
        for (int j = 0; j < HD; ++j) s += We[j] * ae[j];
        we_vec[l * 8 + k] = s;
    }
    for (int idx = t; idx < F_INN * HD; idx += 256) {
        int r = idx >> 6, c = idx & 63;
        float s = 0.0f;
#pragma unroll
        for (int k = 0; k < HD; ++k) s += enc_w[r * HD + k] * W0[k * HD + c];
        Wc[idx] = s;
    }
    if (t < HD) {
        float s = 0.0f;
#pragma unroll
        for (int k = 0; k < HD; ++k) s += enc_b[k] * W0[k * HD + t];
        bc[t] = s;
    }
    if (t < NBKT) bkt_pos[t] = 0;
}

// ---------- K2a: fused — mean partials, edge-term compute, LDS-sorted bucket flush ----------
__global__ __launch_bounds__(256) void k_mean_edterm(const float* __restrict__ eattr,
                                                     const int* __restrict__ src,
                                                     const int* __restrict__ dst,
                                                     const float* __restrict__ we_vec,
                                                     float* __restrict__ partials,
                                                     uint* __restrict__ bkt,
                                                     int* __restrict__ bkt_pos) {
    __shared__ float sw[16];
    __shared__ int hist[NBKT];     // count, then LDS cursor, then chunk size
    __shared__ int lstart[256];    // scan array -> exclusive LDS record offsets
    __shared__ int gstart[NBKT];   // reserved global record offsets
    __shared__ uint recs[ME_CHUNK * 2];   // 20 KB staged 8B records
    int t = threadIdx.x;
    if (t < 16) sw[t] = we_vec[t];
    if (t < NBKT) hist[t] = 0;
    __syncthreads();
    float p[8];
#pragma unroll
    for (int k = 0; k < 8; ++k) p[k] = 0.0f;
    int e0 = blockIdx.x * ME_CHUNK;
    int rs[ME_UNR]; uint rp[ME_UNR]; int rb[ME_UNR];   // rb = (bucket<<16)|d_local
#pragma unroll
    for (int u = 0; u < ME_UNR; ++u) {
        int e = e0 + u * 256 + t;
        const float4* row = (const float4*)(eattr + (size_t)e * F_EE);
        float4 r0 = row[0], r1 = row[1];
        p[0] += r0.x; p[1] += r0.y; p[2] += r0.z; p[3] += r0.w;
        p[4] += r1.x; p[5] += r1.y; p[6] += r1.z; p[7] += r1.w;
        float ed0 = r0.x * sw[0] + r0.y * sw[1] + r0.z * sw[2] + r0.w * sw[3]
                  + r1.x * sw[4] + r1.y * sw[5] + r1.z * sw[6] + r1.w * sw[7];
        float ed1 = r0.x * sw[8] + r0.y * sw[9] + r0.z * sw[10] + r0.w * sw[11]
                  + r1.x * sw[12] + r1.y * sw[13] + r1.z * sw[14] + r1.w * sw[15];
        rs[u] = src[e];
        rp[u] = pack_bf2(ed0, ed1);
        int d = dst[e];
        int b = d / BKT_W;
        rb[u] = (b << 16) | (d - b * BKT_W);
        atomicAdd(&hist[b], 1);
    }
    __syncthreads();
    // exclusive scan of per-bucket counts -> LDS chunk offsets
    lstart[t] = (t < NBKT) ? hist[t] : 0;
    __syncthreads();
    for (int off = 1; off < 256; off <<= 1) {
        int x = (t >= off) ? lstart[t - off] : 0;
        __syncthreads();
        lstart[t] += x;
        __syncthreads();
    }
    if (t < NBKT) {
        int v = hist[t];
        gstart[t] = atomicAdd(&bkt_pos[t], v);   // exact reservation, no padding
        lstart[t] -= v;                          // inclusive -> exclusive
        hist[t] = 0;                             // reuse as placement cursor
    }
    __syncthreads();
    // place records bucket-sorted into LDS: 8B record = {src | dl<<17, pack}
#pragma unroll
    for (int u = 0; u < ME_UNR; ++u) {
        int b = rb[u] >> 16, dl = rb[u] & 0xFFFF;
        int l = atomicAdd(&hist[b], 1);
        ((uint2*)recs)[lstart[b] + l] = make_uint2((uint)rs[u] | ((uint)dl << 17), rp[u]);
    }
    __syncthreads();
    // per-bucket wave-contiguous flush
    int w = t >> 6, lane = t & 63;
    uint2* gb2 = (uint2*)bkt;
    for (int b = w; b < NBKT; b += 4) {
        int n = hist[b];
        int ls = lstart[b];
        int gs = gstart[b];
        for (int off = lane; off < n; off += 64)
            if (gs + off < BKT_CAP)
                gb2[(size_t)b * BKT_CAP + gs + off] = ((const uint2*)recs)[ls + off];
    }
#pragma unroll
    for (int k = 0; k < 8; ++k) p[k] = waveReduceSum(p[k]);
    if ((t & 63) == 0) {
        float* dstp = partials + ((size_t)blockIdx.x * 4 + w) * 8;
#pragma unroll
        for (int k = 0; k < 8; ++k) dstp[k] = p[k];
    }
}

// ---------- K2b: merged finalize — mean finish + bucket-count scan ----------
// (was 2 kernels: mean_final + bktscan; both single-block, sequential phases)
__global__ __launch_bounds__(256) void k_finalize(const float* __restrict__ partials,
                                                  const float* __restrict__ we_vec,
                                                  const int* __restrict__ bkt_pos,
                                                  uint* __restrict__ ltp,
                                                  int* __restrict__ bktbase,
                                                  int* __restrict__ row_ptr) {
    __shared__ float red[256];
    __shared__ float mean8[8];
    __shared__ float lt[2];
    __shared__ int sd[256];
    int t = threadIdx.x;
    // phase 1: edge_attr mean -> loop terms
    int k = t & 7;
    int chunk = t >> 3;
    float s = 0.0f;
    for (int i = chunk; i < PART_CH; i += 32) s += partials[(size_t)i * 8 + k];
    red[t] = s;
    __syncthreads();
    if (t < 8) {
        float acc = 0.0f;
#pragma unroll
        for (int c = 0; c < 32; ++c) acc += red[c * 8 + t];
        mean8[t] = acc * (1.0f / N_EDGES);
    }
    __syncthreads();
    if (t < 2) {
        float acc = 0.0f;
#pragma unroll
        for (int kk = 0; kk < 8; ++kk) acc += mean8[kk] * we_vec[t * 8 + kk];
        lt[t] = acc;
    }
    __syncthreads();
    if (t == 0) ltp[0] = pack_bf2(lt[0], lt[1]);
    // phase 2: scan bucket counts -> bucket CSR bases
    int v = (t < NBKT) ? min(bkt_pos[t], BKT_CAP) + BKT_W : 0;
    sd[t] = v;
    __syncthreads();
    for (int off = 1; off < 256; off <<= 1) {
        int x = (t >= off) ? sd[t - off] : 0;
        __syncthreads();
        sd[t] += x;
        __syncthreads();
    }
    if (t < NBKT) bktbase[t] = sd[t] - v;
    if (t == 0) row_ptr[N_NODES] = E_SL;
}

// kB: one block per bucket. Counting-sort the bucket's ~6400 8B records in LDS
// (per-node hist -> scan -> u16 rank array with self-loop slots interleaved),
// write row_ptr for its 400 nodes, then write agg as a FULLY CONTIGUOUS
// coalesced stream.
__global__ __launch_bounds__(SB_THREADS) void k_sort_build(const int* __restrict__ bkt_pos,
                                                           const uint* __restrict__ bkt,
                                                           const int* __restrict__ bktbase,
                                                           const uint* __restrict__ ltp,
                                                           int2* __restrict__ agg,
                                                           int* __restrict__ row_ptr) {
    __shared__ int S[BKT_W];                 // inclusive scan of per-node counts
    __shared__ int cur[BKT_W];               // hist, then rank cursor
    __shared__ unsigned short sel[SEL_CAP];  // local position -> record idx | selfloop
    int b = blockIdx.x;
    int t = threadIdx.x;
    int cnt = min(bkt_pos[b], BKT_CAP);
    const uint2* bp = (const uint2*)bkt + (size_t)b * BKT_CAP;
    if (t < BKT_W) cur[t] = 0;
    __syncthreads();
    for (int i = t; i < cnt; i += SB_THREADS) {
        uint2 v = bp[i];                     // streams bucket through L2
        atomicAdd(&cur[v.x >> 17], 1);
    }
    __syncthreads();
    if (t < BKT_W) S[t] = cur[t];
    for (int off = 1; off < BKT_W; off <<= 1) {
        __syncthreads();
        int x = (t >= off && t < BKT_W) ? S[t - off] : 0;
        __syncthreads();
        if (t < BKT_W) S[t] += x;
    }
    __syncthreads();
    int n0 = b * BKT_W;
    int gb = bktbase[b];
    if (t < BKT_W) {
        row_ptr[n0 + t] = gb + (t == 0 ? 0 : S[t - 1]) + t;   // excl scan of (cnt+1)
        cur[t] = 0;
        sel[S[t] + t] = (unsigned short)(0x8000 | t);   // self-loop slot (segment end)
    }
    __syncthreads();
    for (int i = t; i < cnt; i += SB_THREADS) {
        int dl = (int)(bp[i].x >> 17);       // L2 re-read
        int r = atomicAdd(&cur[dl], 1);
        int nb = (dl == 0) ? 0 : S[dl - 1];
        sel[nb + dl + r] = (unsigned short)i;
    }
    __syncthreads();
    int total = cnt + BKT_W;
    uint lt = ltp[0];
    for (int p = t; p < total; p += SB_THREADS) {
        unsigned short v = sel[p];
        int2 a;
        if (v & 0x8000) {
            a = make_int2(n0 + (v & 0x7fff), (int)lt);
        } else {
            uint2 r = bp[v];                 // random read within resident bucket
            a = make_int2((int)(r.x & 0x1FFFFu), (int)r.y);
        }
        agg[gb + p] = a;                     // contiguous coalesced stream
    }
}

// ---------- K3: layer-0 projection xp = x@Wc + bc — weight column in VGPRs, x broadcast via LDS ----------
__global__ __launch_bounds__(256) void k_xp0(const float* __restrict__ x,
                                             const float* __restrict__ Wc,
                                             const float* __restrict__ bc,
                                             const float* __restrict__ a_src,
                                             const float* __restrict__ a_dst,
                                             __hip_bfloat16* __restrict__ xpb,
                                             float* __restrict__ s_src,
                                             float* __restrict__ s_dst) {
    __shared__ float xr[NPB * F_INN];  // 4 KB
    int t = threadIdx.x;
    int j = t & 63, wv = t >> 6;
    float4 w[F_INN / 4];               // 8 VGPR float4s = weight column j
#pragma unroll
    for (int kk = 0; kk < F_INN / 4; ++kk) {
        w[kk].x = Wc[(4 * kk + 0) * HD + j];
        w[kk].y = Wc[(4 * kk + 1) * HD + j];
        w[kk].z = Wc[(4 * kk + 2) * HD + j];
        w[kk].w = Wc[(4 * kk + 3) * HD + j];
    }
    int n0 = blockIdx.x * NPB;
    ((float4*)xr)[t] = ((const float4*)(x + (size_t)n0 * F_INN))[t];  // 256*16B = 4KB exact
    __syncthreads();
    float asj = a_src[j], adj = a_dst[j], bcj = bc[j];
    for (int n = wv; n < NPB; n += 4) {
        const float4* hx = (const float4*)&xr[n * F_INN];
        float acc = bcj;
#pragma unroll
        for (int kk = 0; kk < F_INN / 4; ++kk) {
            float4 hv = hx[kk];   // wave-uniform broadcast ds_read_b128
            acc += hv.x * w[kk].x + hv.y * w[kk].y + hv.z * w[kk].z + hv.w * w[kk].w;
        }
        int node = n0 + n;
        xpb[(size_t)node * HD + j] = __float2bfloat16(acc);
        float ts = waveReduceSum(acc * asj);
        float td = waveReduceSum(acc * adj);
        if (j == 0) { s_src[node] = ts; s_dst[node] = td; }
    }
}

// ---------- K4: xp(bf16) = h @ W (layer 1) — h now bf16 (r5: h was the last
// f32 activation tensor; bf16 halves its 4 HBM trips = ~51MB saved) ----------
__global__ __launch_bounds__(256) void k_xp(const unsigned short* __restrict__ hb,
                                            const float* __restrict__ W,
                                            const float* __restrict__ a_src, const float* __restrict__ a_dst,
                                            __hip_bfloat16* __restrict__ xpb, float* __restrict__ s_src,
                                            float* __restrict__ s_dst) {
    __shared__ unsigned short hr[NPB * HD];   // 4 KB bf16 tile
    int t = threadIdx.x;
    int j = t & 63, wv = t >> 6;
    float4 w[HD / 4];                  // 16 float4s = 64 VGPRs
#pragma unroll
    for (int kk = 0; kk < HD / 4; ++kk) {
        w[kk].x = W[(4 * kk + 0) * HD + j];
        w[kk].y = W[(4 * kk + 1) * HD + j];
        w[kk].z = W[(4 * kk + 2) * HD + j];
        w[kk].w = W[(4 * kk + 3) * HD + j];
    }
    int n0 = blockIdx.x * NPB;
    ((uint4*)hr)[t] = ((const uint4*)(hb + (size_t)n0 * HD))[t];   // 256*16B = 4KB exact
    __syncthreads();
    float asj = a_src[j], adj = a_dst[j];
    for (int n = wv; n < NPB; n += 4) {
        const uint2* hx = (const uint2*)&hr[n * HD];
        float acc = 0.0f;
#pragma unroll
        for (int kk = 0; kk < HD / 4; ++kk) {
            uint2 hv = hx[kk];   // broadcast ds_read_b64: 4 bf16
            acc += bf_lo(hv.x) * w[kk].x + bf_hi(hv.x) * w[kk].y
                 + bf_lo(hv.y) * w[kk].z + bf_hi(hv.y) * w[kk].w;
        }
        int node = n0 + n;
        xpb[(size_t)node * HD + j] = __float2bfloat16(acc);
        float ts = waveReduceSum(acc * asj);
        float td = waveReduceSum(acc * adj);
        if (j == 0) { s_src[node] = ts; s_dst[node] = td; }
    }
}

// ---------- K5: gather-aggregate — wave/node, 16-lane groups, 8 edges/iter; h out bf16 ----------
template <int LAYER>
__global__ __launch_bounds__(256) void k_aggregate(const int* __restrict__ row_ptr,
                                                   const int2* __restrict__ agg,
                                                   const float* __restrict__ s_src,
                                                   const float* __restrict__ s_dst,
                                                   const uint2* __restrict__ xpr,   // bf16 x4 per lane
                                                   const float* __restrict__ bias,
                                                   unsigned short* __restrict__ hb) {
    int t = threadIdx.x;
    int node = blockIdx.x * 4 + (t >> 6);    // grid exact: N/4
    int lane = t & 63;
    int g = lane >> 4, li = lane & 15;
    int start = row_ptr[node], end = row_ptr[node + 1];
    float sd = s_dst[node];
    float ax = 0.0f, ay = 0.0f, az = 0.0f, aw = 0.0f, den = 0.0f;
    int i = start;
    for (; i + 8 <= end; i += 8) {
        int2 r0 = agg[i + g];
        int2 r1 = agg[i + 4 + g];
        int sp0 = r0.x, sp1 = r1.x;
        uint2 u0 = xpr[(size_t)sp0 * 16 + li];
        uint2 u1 = xpr[(size_t)sp1 * 16 + li];
        float a0 = s_src[sp0] + sd + (LAYER == 0 ? bf_lo((uint)r0.y) : bf_hi((uint)r0.y));
        float a1 = s_src[sp1] + sd + (LAYER == 0 ? bf_lo((uint)r1.y) : bf_hi((uint)r1.y));
        a0 = a0 > 0.0f ? a0 : NEG_SLOPE * a0;
        a1 = a1 > 0.0f ? a1 : NEG_SLOPE * a1;
        float ex0 = __expf(a0), ex1 = __expf(a1);
        den += ex0 + ex1;
        ax += ex0 * bf_lo(u0.x) + ex1 * bf_lo(u1.x);
        ay += ex0 * bf_hi(u0.x) + ex1 * bf_hi(u1.x);
        az += ex0 * bf_lo(u0.y) + ex1 * bf_lo(u1.y);
        aw += ex0 * bf_hi(u0.y) + ex1 * bf_hi(u1.y);
    }
    for (; i < end; i += 4) {
        int idx = i + g;
        bool valid = idx < end;
        int2 r = agg[valid ? idx : end - 1];
        int sp = r.x;
        uint2 u = xpr[(size_t)sp * 16 + li];
        float a = s_src[sp] + sd + (LAYER == 0 ? bf_lo((uint)r.y) : bf_hi((uint)r.y));
        a = a > 0.0f ? a : NEG_SLOPE * a;
        float ex = valid ? __expf(a) : 0.0f;
        den += ex;
        ax += ex * bf_lo(u.x);
        ay += ex * bf_hi(u.x);
        az += ex * bf_lo(u.y);
        aw += ex * bf_hi(u.y);
    }
    den += __shfl_down(den, 32, 64); ax += __shfl_down(ax, 32, 64);
    ay  += __shfl_down(ay, 32, 64); az += __shfl_down(az, 32, 64);
    aw  += __shfl_down(aw, 32, 64);
    den += __shfl_down(den, 16, 64); ax += __shfl_down(ax, 16, 64);
    ay  += __shfl_down(ay, 16, 64); az += __shfl_down(az, 16, 64);
    aw  += __shfl_down(aw, 16, 64);
    if (lane < 16) {
        float inv = 1.0f / (den + 1e-16f);
        float4 b4 = ((const float4*)bias)[li];
        uint2 hv;
        hv.x = pack_bf2(fmaxf(ax * inv + b4.x, 0.0f), fmaxf(ay * inv + b4.y, 0.0f));
        hv.y = pack_bf2(fmaxf(az * inv + b4.z, 0.0f), fmaxf(aw * inv + b4.w, 0.0f));
        ((uint2*)(hb + (size_t)node * HD))[li] = hv;
    }
}

// ---------- K6: u1(bf16)=h@W1a, u2b(bf16)=h@W1b + b1 — h in bf16 ----------
__global__ __launch_bounds__(256) void k_umm(const unsigned short* __restrict__ hb,
                                             const float* __restrict__ w1,
                                             const float* __restrict__ b1,
                                             __hip_bfloat16* __restrict__ u1b,
                                             __hip_bfloat16* __restrict__ u2b) {
    __shared__ unsigned short hr[NPB * HD];   // 4 KB bf16 tile
    int t = threadIdx.x;
    int j = t & 63, wv = t >> 6;
    float4 wa[HD / 4], wb[HD / 4];     // 128 VGPRs
#pragma unroll
    for (int kk = 0; kk < HD / 4; ++kk) {
        wa[kk].x = w1[(4 * kk + 0) * HD + j];
        wa[kk].y = w1[(4 * kk + 1) * HD + j];
        wa[kk].z = w1[(4 * kk + 2) * HD + j];
        wa[kk].w = w1[(4 * kk + 3) * HD + j];
        wb[kk].x = w1[(HD + 4 * kk + 0) * HD + j];
        wb[kk].y = w1[(HD + 4 * kk + 1) * HD + j];
        wb[kk].z = w1[(HD + 4 * kk + 2) * HD + j];
        wb[kk].w = w1[(HD + 4 * kk + 3) * HD + j];
    }
    float b1j = b1[j];
    int n0 = blockIdx.x * NPB;
    ((uint4*)hr)[t] = ((const uint4*)(hb + (size_t)n0 * HD))[t];   // 4KB exact
    __syncthreads();
    for (int n = wv; n < NPB; n += 4) {
        const uint2* hx = (const uint2*)&hr[n * HD];
        float a1 = 0.0f, a2 = 0.0f;
#pragma unroll
        for (int kk = 0; kk < HD / 4; ++kk) {
            uint2 hv = hx[kk];   // broadcast ds_read_b64: 4 bf16
            float h0 = bf_lo(hv.x), h1 = bf_hi(hv.x), h2 = bf_lo(hv.y), h3 = bf_hi(hv.y);
            a1 += h0 * wa[kk].x + h1 * wa[kk].y + h2 * wa[kk].z + h3 * wa[kk].w;
            a2 += h0 * wb[kk].x + h1 * wb[kk].y + h2 * wb[kk].z + h3 * wb[kk].w;
        }
        int node = n0 + n;
        u1b[(size_t)node * HD + j] = __float2bfloat16(a1);
        u2b[(size_t)node * HD + j] = __float2bfloat16(a2 + b1j);
    }
}

// ---------- K7: edge-order decode — out writes COALESCED; near compulsory
// per-XCD fill floor (r5: 176MB fetch vs ~205MB compulsory for 25.6MB
// working set x 8 private L2s). Left structurally unchanged. ----------
__global__ __launch_bounds__(256) void k_decode_edge(const int* __restrict__ src,
                                                     const int* __restrict__ dst,
                                                     const uint2* __restrict__ u1r,
                                                     const uint2* __restrict__ u2r,
                                                     const float* __restrict__ w2,
                                                     const float* __restrict__ b2,
                                                     float* __restrict__ out) {
    __shared__ int sld[64];
    int t = threadIdx.x;
    int e0 = blockIdx.x * 32;            // grid exact: E/32 blocks
    if (t < 32) sld[t] = src[e0 + t];
    else if (t < 64) sld[t] = dst[e0 + t - 32];
    __syncthreads();
    int g = t >> 4, li = t & 15;         // 16 groups of 16 lanes, 2 edges/group
    float4 w4 = ((const float4*)w2)[li];
    float bb = b2[0];
    int sa = sld[g],      da = sld[32 + g];
    int sb = sld[16 + g], db = sld[48 + g];
    uint2 a1 = u1r[(size_t)sa * 16 + li];
    uint2 a2 = u2r[(size_t)da * 16 + li];
    uint2 bq1 = u1r[(size_t)sb * 16 + li];
    uint2 bq2 = u2r[(size_t)db * 16 + li];
    float p0 = fmaxf(bf_lo(a1.x) + bf_lo(a2.x), 0.0f) * w4.x
             + fmaxf(bf_hi(a1.x) + bf_hi(a2.x), 0.0f) * w4.y
             + fmaxf(bf_lo(a1.y) + bf_lo(a2.y), 0.0f) * w4.z
             + fmaxf(bf_hi(a1.y) + bf_hi(a2.y), 0.0f) * w4.w;
    float p1 = fmaxf(bf_lo(bq1.x) + bf_lo(bq2.x), 0.0f) * w4.x
             + fmaxf(bf_hi(bq1.x) + bf_hi(bq2.x), 0.0f) * w4.y
             + fmaxf(bf_lo(bq1.y) + bf_lo(bq2.y), 0.0f) * w4.z
             + fmaxf(bf_hi(bq1.y) + bf_hi(bq2.y), 0.0f) * w4.w;
#pragma unroll
    for (int off = 8; off > 0; off >>= 1) {
        p0 += __shfl_down(p0, off, 16);
        p1 += __shfl_down(p1, off, 16);
    }
    if (li == 0) {
        out[e0 + g]      = 1.0f / (1.0f + __expf(-(p0 + bb)));
        out[e0 + 16 + g] = 1.0f / (1.0f + __expf(-(p1 + bb)));
    }
}

extern "C" void kernel_launch(void* const* d_in, const int* in_sizes, int n_in,
                              void* d_out, int out_size, void* d_ws, size_t ws_size,
                              hipStream_t stream) {
    const float* x        = (const float*)d_in[0];
    const int*   eidx     = (const int*)d_in[1];
    const float* eattr    = (const float*)d_in[2];
    const float* enc_w    = (const float*)d_in[3];
    const float* enc_b    = (const float*)d_in[4];
    const float* gat_w    = (const float*)d_in[5];
    const float* att_src  = (const float*)d_in[6];
    const float* att_dst  = (const float*)d_in[7];
    const float* edge_w   = (const float*)d_in[8];
    const float* att_edge = (const float*)d_in[9];
    const float* gat_b    = (const float*)d_in[10];
    const float* lp_w1    = (const float*)d_in[11];
    const float* lp_b1    = (const float*)d_in[12];
    const float* lp_w2    = (const float*)d_in[13];
    const float* lp_b2    = (const float*)d_in[14];
    float* out = (float*)d_out;

    const int* src = eidx;
    const int* dst = eidx + N_EDGES;

    // ---- workspace layout (bytes) ----
    // [0, 14.4MB):  bkt (8B records; live edterm->sort_build)
    //               hb bf16 N*HD = 12.8MB (live aggregate<0> -> umm) aliases it
    // [14.4, 27.2): xpb bf16 N*HD (u1b after umm)
    // [27.2, 40.8): agg E_SL int2 (u2b bf16 after umm — agg dead post agg<1>)
    // [40.8, ...):  small arrays
    char* wsb = (char*)d_ws;
    uint*   bkt = (uint*)wsb;                               // NBKT*BKT_CAP*8B = 14.4MB
    unsigned short* hb = (unsigned short*)wsb;              // N*HD bf16 (12.8MB)
    __hip_bfloat16* xpb = (__hip_bfloat16*)(wsb + (size_t)NBKT * BKT_CAP * 8);
    int2*   agg = (int2*)((char*)xpb + (size_t)N_NODES * HD * 2);   // 13.6MB
    float*  fsmall    = (float*)(agg + E_SL);
    float*  s_src     = fsmall;                             // N
    float*  s_dst     = s_src + N_NODES;                    // N
    float*  partials  = s_dst + N_NODES;                    // PART_CH*8 (20000)
    float*  we_vec    = partials + PART_CH * 8;             // 16
    uint*   ltp       = (uint*)(we_vec + 16);               // 1
    float*  Wc        = (float*)(ltp + 1);                  // 32*64
    float*  bc        = Wc + F_INN * HD;                    // 64
    int*    row_ptr   = (int*)(bc + HD);                    // N+1
    int*    bkt_pos   = row_ptr + N_NODES + 1;              // NBKT
    int*    bktbase   = bkt_pos + NBKT;                     // NBKT

    const int NB_AGG  = N_NODES / 4;             // 25000
    const int NB_DENSE = N_NODES / NPB;          // 3125
    const int NB_DEC  = N_EDGES / 32;            // 50000

    // merged setup (we_vec + Wc/bc + counter zero) then fused edge pass
    k_setup<<<1, 256, 0, stream>>>(edge_w, att_edge, enc_w, enc_b, gat_w,
                                   we_vec, Wc, bc, bkt_pos);
    k_mean_edterm<<<ME_BLOCKS, 256, 0, stream>>>(eattr, src, dst, we_vec,
                                                 partials, bkt, bkt_pos);
    k_finalize<<<1, 256, 0, stream>>>(partials, we_vec, bkt_pos, ltp, bktbase, row_ptr);

    // per-bucket LDS counting sort -> CSR agg records + row_ptr
    k_sort_build<<<NBKT, SB_THREADS, 0, stream>>>(bkt_pos, bkt, bktbase, ltp,
                                                  agg, row_ptr);

    // layer-0 projection (encoder folded into Wc/bc)
    k_xp0<<<NB_DENSE, 256, 0, stream>>>(x, Wc, bc, att_src, att_dst, xpb, s_src, s_dst);
    k_aggregate<0><<<NB_AGG, 256, 0, stream>>>(row_ptr, agg, s_src, s_dst,
                                               (const uint2*)xpb, gat_b, hb);
    // GAT layer 1
    k_xp<<<NB_DENSE, 256, 0, stream>>>(hb, gat_w + HD * HD, att_src + HD, att_dst + HD,
                                       xpb, s_src, s_dst);
    k_aggregate<1><<<NB_AGG, 256, 0, stream>>>(row_ptr, agg, s_src, s_dst,
                                               (const uint2*)xpb, gat_b + HD, hb);

    // decoder: u1b -> xpb buffer, u2b(+b1) -> agg buffer (both dead by now);
    // decode in ORIGINAL edge order (coalesced out)
    k_umm<<<NB_DENSE, 256, 0, stream>>>(hb, lp_w1, lp_b1, xpb,
                                        (__hip_bfloat16*)agg);
    k_decode_edge<<<NB_DEC, 256, 0, stream>>>(src, dst, (const uint2*)xpb,
                                              (const uint2*)agg, lp_w2, lp_b2, out);
}

// Round 8
// 447.372 us; speedup vs baseline: 1.4090x; 1.0206x over previous
//
#include <hip/hip_runtime.h>
#include <hip/hip_bf16.h>
#include <math.h>

#define N_NODES 100000
#define N_EDGES 1600000
#define F_INN   32
#define F_EE    8
#define HD      64
#define E_SL    (N_EDGES + N_NODES)   // edges + self loops
#define NEG_SLOPE 0.2f
#define NPB 32                        // nodes per block in dense kernels (3125 blocks)

// dst-range bucketing fused into the edge pass. 250 buckets of 400 nodes.
// 8B records {src|dl<<17, pack}; LDS-sorted per block, flushed wave-contiguous.
#define NBKT 250
#define BKT_W (N_NODES / NBKT)        // 400 nodes per bucket
#define BKT_CAP 7200                  // mean 6400 + 10 sigma — overflow prob ~1e-13
#define ME_UNR 10
#define ME_CHUNK (256 * ME_UNR)       // 2560 edges per block
#define ME_BLOCKS (N_EDGES / ME_CHUNK)   // 625
#define PART_CH (ME_BLOCKS * 4)       // 2500 wave partials
#define SB_THREADS 512
#define SEL_CAP (BKT_CAP + BKT_W)     // 7600
#define DEC_EPB 64                    // decode: 64 edges/block, 4 per 16-lane group

// ---------- helpers ----------
__device__ __forceinline__ float waveReduceSum(float v) {
#pragma unroll
    for (int off = 32; off > 0; off >>= 1) v += __shfl_down(v, off, 64);
    return v;
}
__device__ __forceinline__ float bf_lo(uint u) { return __uint_as_float(u << 16); }
__device__ __forceinline__ float bf_hi(uint u) { return __uint_as_float(u & 0xffff0000u); }
__device__ __forceinline__ uint pack_bf2(float a, float b) {
    __hip_bfloat16 ha = __float2bfloat16(a), hb = __float2bfloat16(b);
    unsigned short ua, ub;
    __builtin_memcpy(&ua, &ha, 2); __builtin_memcpy(&ub, &hb, 2);
    return (uint)ua | ((uint)ub << 16);
}

// ---------- K1: merged setup — we_vec, Wc/bc fold, bucket-counter zero ----------
__global__ __launch_bounds__(256) void k_setup(const float* __restrict__ edge_w,
                                               const float* __restrict__ att_edge,
                                               const float* __restrict__ enc_w,
                                               const float* __restrict__ enc_b,
                                               const float* __restrict__ W0,
                                               float* __restrict__ we_vec,
                                               float* __restrict__ Wc, float* __restrict__ bc,
                                               int* __restrict__ bkt_pos) {
    int t = threadIdx.x;
    if (t < 16) {
        int l = t >> 3, k = t & 7;
        const float* We = edge_w + l * F_EE * HD + k * HD;
        const float* ae = att_edge + l * HD;
        float s = 0.0f;
#pragma unroll
        for (int j = 0; j < HD; ++j) s += We[j] * ae[j];
        we_vec[l * 8 + k] = s;
    }
    for (int idx = t; idx < F_INN * HD; idx += 256) {
        int r = idx >> 6, c = idx & 63;
        float s = 0.0f;
#pragma unroll
        for (int k = 0; k < HD; ++k) s += enc_w[r * HD + k] * W0[k * HD + c];
        Wc[idx] = s;
    }
    if (t < HD) {
        float s = 0.0f;
#pragma unroll
        for (int k = 0; k < HD; ++k) s += enc_b[k] * W0[k * HD + t];
        bc[t] = s;
    }
    if (t < NBKT) bkt_pos[t] = 0;
}

// ---------- K2a: fused — mean partials, edge-term compute, LDS-sorted bucket flush ----------
__global__ __launch_bounds__(256) void k_mean_edterm(const float* __restrict__ eattr,
                                                     const int* __restrict__ src,
                                                     const int* __restrict__ dst,
                                                     const float* __restrict__ we_vec,
                                                     float* __restrict__ partials,
                                                     uint* __restrict__ bkt,
                                                     int* __restrict__ bkt_pos) {
    __shared__ float sw[16];
    __shared__ int hist[NBKT];     // count, then LDS cursor, then chunk size
    __shared__ int lstart[256];    // scan array -> exclusive LDS record offsets
    __shared__ int gstart[NBKT];   // reserved global record offsets
    __shared__ uint recs[ME_CHUNK * 2];   // 20 KB staged 8B records
    int t = threadIdx.x;
    if (t < 16) sw[t] = we_vec[t];
    if (t < NBKT) hist[t] = 0;
    __syncthreads();
    float p[8];
#pragma unroll
    for (int k = 0; k < 8; ++k) p[k] = 0.0f;
    int e0 = blockIdx.x * ME_CHUNK;
    int rs[ME_UNR]; uint rp[ME_UNR]; int rb[ME_UNR];   // rb = (bucket<<16)|d_local
#pragma unroll
    for (int u = 0; u < ME_UNR; ++u) {
        int e = e0 + u * 256 + t;
        const float4* row = (const float4*)(eattr + (size_t)e * F_EE);
        float4 r0 = row[0], r1 = row[1];
        p[0] += r0.x; p[1] += r0.y; p[2] += r0.z; p[3] += r0.w;
        p[4] += r1.x; p[5] += r1.y; p[6] += r1.z; p[7] += r1.w;
        float ed0 = r0.x * sw[0] + r0.y * sw[1] + r0.z * sw[2] + r0.w * sw[3]
                  + r1.x * sw[4] + r1.y * sw[5] + r1.z * sw[6] + r1.w * sw[7];
        float ed1 = r0.x * sw[8] + r0.y * sw[9] + r0.z * sw[10] + r0.w * sw[11]
                  + r1.x * sw[12] + r1.y * sw[13] + r1.z * sw[14] + r1.w * sw[15];
        rs[u] = src[e];
        rp[u] = pack_bf2(ed0, ed1);
        int d = dst[e];
        int b = d / BKT_W;
        rb[u] = (b << 16) | (d - b * BKT_W);
        atomicAdd(&hist[b], 1);
    }
    __syncthreads();
    // exclusive scan of per-bucket counts -> LDS chunk offsets
    lstart[t] = (t < NBKT) ? hist[t] : 0;
    __syncthreads();
    for (int off = 1; off < 256; off <<= 1) {
        int x = (t >= off) ? lstart[t - off] : 0;
        __syncthreads();
        lstart[t] += x;
        __syncthreads();
    }
    if (t < NBKT) {
        int v = hist[t];
        gstart[t] = atomicAdd(&bkt_pos[t], v);   // exact reservation, no padding
        lstart[t] -= v;                          // inclusive -> exclusive
        hist[t] = 0;                             // reuse as placement cursor
    }
    __syncthreads();
    // place records bucket-sorted into LDS: 8B record = {src | dl<<17, pack}
#pragma unroll
    for (int u = 0; u < ME_UNR; ++u) {
        int b = rb[u] >> 16, dl = rb[u] & 0xFFFF;
        int l = atomicAdd(&hist[b], 1);
        ((uint2*)recs)[lstart[b] + l] = make_uint2((uint)rs[u] | ((uint)dl << 17), rp[u]);
    }
    __syncthreads();
    // per-bucket wave-contiguous flush
    int w = t >> 6, lane = t & 63;
    uint2* gb2 = (uint2*)bkt;
    for (int b = w; b < NBKT; b += 4) {
        int n = hist[b];
        int ls = lstart[b];
        int gs = gstart[b];
        for (int off = lane; off < n; off += 64)
            if (gs + off < BKT_CAP)
                gb2[(size_t)b * BKT_CAP + gs + off] = ((const uint2*)recs)[ls + off];
    }
#pragma unroll
    for (int k = 0; k < 8; ++k) p[k] = waveReduceSum(p[k]);
    if ((t & 63) == 0) {
        float* dstp = partials + ((size_t)blockIdx.x * 4 + w) * 8;
#pragma unroll
        for (int k = 0; k < 8; ++k) dstp[k] = p[k];
    }
}

// ---------- K2b: merged finalize — mean finish + bucket-count scan ----------
__global__ __launch_bounds__(256) void k_finalize(const float* __restrict__ partials,
                                                  const float* __restrict__ we_vec,
                                                  const int* __restrict__ bkt_pos,
                                                  uint* __restrict__ ltp,
                                                  int* __restrict__ bktbase,
                                                  int* __restrict__ row_ptr) {
    __shared__ float red[256];
    __shared__ float mean8[8];
    __shared__ float lt[2];
    __shared__ int sd[256];
    int t = threadIdx.x;
    // phase 1: edge_attr mean -> loop terms
    int k = t & 7;
    int chunk = t >> 3;
    float s = 0.0f;
    for (int i = chunk; i < PART_CH; i += 32) s += partials[(size_t)i * 8 + k];
    red[t] = s;
    __syncthreads();
    if (t < 8) {
        float acc = 0.0f;
#pragma unroll
        for (int c = 0; c < 32; ++c) acc += red[c * 8 + t];
        mean8[t] = acc * (1.0f / N_EDGES);
    }
    __syncthreads();
    if (t < 2) {
        float acc = 0.0f;
#pragma unroll
        for (int kk = 0; kk < 8; ++kk) acc += mean8[kk] * we_vec[t * 8 + kk];
        lt[t] = acc;
    }
    __syncthreads();
    if (t == 0) ltp[0] = pack_bf2(lt[0], lt[1]);
    // phase 2: scan bucket counts -> bucket CSR bases
    int v = (t < NBKT) ? min(bkt_pos[t], BKT_CAP) + BKT_W : 0;
    sd[t] = v;
    __syncthreads();
    for (int off = 1; off < 256; off <<= 1) {
        int x = (t >= off) ? sd[t - off] : 0;
        __syncthreads();
        sd[t] += x;
        __syncthreads();
    }
    if (t < NBKT) bktbase[t] = sd[t] - v;
    if (t == 0) row_ptr[N_NODES] = E_SL;
}

// kB: one block per bucket. Counting-sort the bucket's ~6400 8B records in LDS,
// write row_ptr for its 400 nodes, write agg as fully contiguous stream.
__global__ __launch_bounds__(SB_THREADS) void k_sort_build(const int* __restrict__ bkt_pos,
                                                           const uint* __restrict__ bkt,
                                                           const int* __restrict__ bktbase,
                                                           const uint* __restrict__ ltp,
                                                           int2* __restrict__ agg,
                                                           int* __restrict__ row_ptr) {
    __shared__ int S[BKT_W];                 // inclusive scan of per-node counts
    __shared__ int cur[BKT_W];               // hist, then rank cursor
    __shared__ unsigned short sel[SEL_CAP];  // local position -> record idx | selfloop
    int b = blockIdx.x;
    int t = threadIdx.x;
    int cnt = min(bkt_pos[b], BKT_CAP);
    const uint2* bp = (const uint2*)bkt + (size_t)b * BKT_CAP;
    if (t < BKT_W) cur[t] = 0;
    __syncthreads();
    for (int i = t; i < cnt; i += SB_THREADS) {
        uint2 v = bp[i];                     // streams bucket through L2
        atomicAdd(&cur[v.x >> 17], 1);
    }
    __syncthreads();
    if (t < BKT_W) S[t] = cur[t];
    for (int off = 1; off < BKT_W; off <<= 1) {
        __syncthreads();
        int x = (t >= off && t < BKT_W) ? S[t - off] : 0;
        __syncthreads();
        if (t < BKT_W) S[t] += x;
    }
    __syncthreads();
    int n0 = b * BKT_W;
    int gb = bktbase[b];
    if (t < BKT_W) {
        row_ptr[n0 + t] = gb + (t == 0 ? 0 : S[t - 1]) + t;   // excl scan of (cnt+1)
        cur[t] = 0;
        sel[S[t] + t] = (unsigned short)(0x8000 | t);   // self-loop slot (segment end)
    }
    __syncthreads();
    for (int i = t; i < cnt; i += SB_THREADS) {
        int dl = (int)(bp[i].x >> 17);       // L2 re-read
        int r = atomicAdd(&cur[dl], 1);
        int nb = (dl == 0) ? 0 : S[dl - 1];
        sel[nb + dl + r] = (unsigned short)i;
    }
    __syncthreads();
    int total = cnt + BKT_W;
    uint lt = ltp[0];
    for (int p = t; p < total; p += SB_THREADS) {
        unsigned short v = sel[p];
        int2 a;
        if (v & 0x8000) {
            a = make_int2(n0 + (v & 0x7fff), (int)lt);
        } else {
            uint2 r = bp[v];                 // random read within resident bucket
            a = make_int2((int)(r.x & 0x1FFFFu), (int)r.y);
        }
        agg[gb + p] = a;                     // contiguous coalesced stream
    }
}

// ---------- K3: layer-0 projection xp = x@Wc + bc ----------
__global__ __launch_bounds__(256) void k_xp0(const float* __restrict__ x,
                                             const float* __restrict__ Wc,
                                             const float* __restrict__ bc,
                                             const float* __restrict__ a_src,
                                             const float* __restrict__ a_dst,
                                             __hip_bfloat16* __restrict__ xpb,
                                             float* __restrict__ s_src,
                                             float* __restrict__ s_dst) {
    __shared__ float xr[NPB * F_INN];  // 4 KB
    int t = threadIdx.x;
    int j = t & 63, wv = t >> 6;
    float4 w[F_INN / 4];               // 8 VGPR float4s = weight column j
#pragma unroll
    for (int kk = 0; kk < F_INN / 4; ++kk) {
        w[kk].x = Wc[(4 * kk + 0) * HD + j];
        w[kk].y = Wc[(4 * kk + 1) * HD + j];
        w[kk].z = Wc[(4 * kk + 2) * HD + j];
        w[kk].w = Wc[(4 * kk + 3) * HD + j];
    }
    int n0 = blockIdx.x * NPB;
    ((float4*)xr)[t] = ((const float4*)(x + (size_t)n0 * F_INN))[t];  // 4KB exact
    __syncthreads();
    float asj = a_src[j], adj = a_dst[j], bcj = bc[j];
    for (int n = wv; n < NPB; n += 4) {
        const float4* hx = (const float4*)&xr[n * F_INN];
        float acc = bcj;
#pragma unroll
        for (int kk = 0; kk < F_INN / 4; ++kk) {
            float4 hv = hx[kk];   // wave-uniform broadcast ds_read_b128
            acc += hv.x * w[kk].x + hv.y * w[kk].y + hv.z * w[kk].z + hv.w * w[kk].w;
        }
        int node = n0 + n;
        xpb[(size_t)node * HD + j] = __float2bfloat16(acc);
        float ts = waveReduceSum(acc * asj);
        float td = waveReduceSum(acc * adj);
        if (j == 0) { s_src[node] = ts; s_dst[node] = td; }
    }
}

// ---------- K4: xp(bf16) = h @ W (layer 1) — h bf16 ----------
__global__ __launch_bounds__(256) void k_xp(const unsigned short* __restrict__ hb,
                                            const float* __restrict__ W,
                                            const float* __restrict__ a_src, const float* __restrict__ a_dst,
                                            __hip_bfloat16* __restrict__ xpb, float* __restrict__ s_src,
                                            float* __restrict__ s_dst) {
    __shared__ unsigned short hr[NPB * HD];   // 4 KB bf16 tile
    int t = threadIdx.x;
    int j = t & 63, wv = t >> 6;
    float4 w[HD / 4];                  // 16 float4s = 64 VGPRs
#pragma unroll
    for (int kk = 0; kk < HD / 4; ++kk) {
        w[kk].x = W[(4 * kk + 0) * HD + j];
        w[kk].y = W[(4 * kk + 1) * HD + j];
        w[kk].z = W[(4 * kk + 2) * HD + j];
        w[kk].w = W[(4 * kk + 3) * HD + j];
    }
    int n0 = blockIdx.x * NPB;
    ((uint4*)hr)[t] = ((const uint4*)(hb + (size_t)n0 * HD))[t];   // 4KB exact
    __syncthreads();
    float asj = a_src[j], adj = a_dst[j];
    for (int n = wv; n < NPB; n += 4) {
        const uint2* hx = (const uint2*)&hr[n * HD];
        float acc = 0.0f;
#pragma unroll
        for (int kk = 0; kk < HD / 4; ++kk) {
            uint2 hv = hx[kk];   // broadcast ds_read_b64: 4 bf16
            acc += bf_lo(hv.x) * w[kk].x + bf_hi(hv.x) * w[kk].y
                 + bf_lo(hv.y) * w[kk].z + bf_hi(hv.y) * w[kk].w;
        }
        int node = n0 + n;
        xpb[(size_t)node * HD + j] = __float2bfloat16(acc);
        float ts = waveReduceSum(acc * asj);
        float td = waveReduceSum(acc * adj);
        if (j == 0) { s_src[node] = ts; s_dst[node] = td; }
    }
}

// ---------- K5: gather-aggregate — wave/node, 16-lane groups; r7 analysis:
// latency-bound (HBM 36%, VALU 62%, occ 75%). Main loop now software-pipelined
// 1-deep on the agg record loads: next iteration's records (the head of the
// record->row pointer chase) issue before current iteration's math. ----------
template <int LAYER>
__global__ __launch_bounds__(256) void k_aggregate(const int* __restrict__ row_ptr,
                                                   const int2* __restrict__ agg,
                                                   const float* __restrict__ s_src,
                                                   const float* __restrict__ s_dst,
                                                   const uint2* __restrict__ xpr,   // bf16 x4 per lane
                                                   const float* __restrict__ bias,
                                                   unsigned short* __restrict__ hb) {
    int t = threadIdx.x;
    int node = blockIdx.x * 4 + (t >> 6);    // grid exact: N/4
    int lane = t & 63;
    int g = lane >> 4, li = lane & 15;
    int start = row_ptr[node], end = row_ptr[node + 1];
    float sd = s_dst[node];
    float ax = 0.0f, ay = 0.0f, az = 0.0f, aw = 0.0f, den = 0.0f;
    int i = start;
    if (i + 8 <= end) {
        int2 r0 = agg[i + g];
        int2 r1 = agg[i + 4 + g];
        while (true) {
            int ni = i + 8;
            bool more = ni + 8 <= end;
            int2 nr0, nr1;
            if (more) { nr0 = agg[ni + g]; nr1 = agg[ni + 4 + g]; }   // prefetch next records
            int sp0 = r0.x, sp1 = r1.x;
            uint2 u0 = xpr[(size_t)sp0 * 16 + li];
            uint2 u1 = xpr[(size_t)sp1 * 16 + li];
            float a0 = s_src[sp0] + sd + (LAYER == 0 ? bf_lo((uint)r0.y) : bf_hi((uint)r0.y));
            float a1 = s_src[sp1] + sd + (LAYER == 0 ? bf_lo((uint)r1.y) : bf_hi((uint)r1.y));
            a0 = a0 > 0.0f ? a0 : NEG_SLOPE * a0;
            a1 = a1 > 0.0f ? a1 : NEG_SLOPE * a1;
            float ex0 = __expf(a0), ex1 = __expf(a1);
            den += ex0 + ex1;
            ax += ex0 * bf_lo(u0.x) + ex1 * bf_lo(u1.x);
            ay += ex0 * bf_hi(u0.x) + ex1 * bf_hi(u1.x);
            az += ex0 * bf_lo(u0.y) + ex1 * bf_lo(u1.y);
            aw += ex0 * bf_hi(u0.y) + ex1 * bf_hi(u1.y);
            i = ni;
            if (!more) break;
            r0 = nr0; r1 = nr1;
        }
    }
    for (; i < end; i += 4) {
        int idx = i + g;
        bool valid = idx < end;
        int2 r = agg[valid ? idx : end - 1];
        int sp = r.x;
        uint2 u = xpr[(size_t)sp * 16 + li];
        float a = s_src[sp] + sd + (LAYER == 0 ? bf_lo((uint)r.y) : bf_hi((uint)r.y));
        a = a > 0.0f ? a : NEG_SLOPE * a;
        float ex = valid ? __expf(a) : 0.0f;
        den += ex;
        ax += ex * bf_lo(u.x);
        ay += ex * bf_hi(u.x);
        az += ex * bf_lo(u.y);
        aw += ex * bf_hi(u.y);
    }
    den += __shfl_down(den, 32, 64); ax += __shfl_down(ax, 32, 64);
    ay  += __shfl_down(ay, 32, 64); az += __shfl_down(az, 32, 64);
    aw  += __shfl_down(aw, 32, 64);
    den += __shfl_down(den, 16, 64); ax += __shfl_down(ax, 16, 64);
    ay  += __shfl_down(ay, 16, 64); az += __shfl_down(az, 16, 64);
    aw  += __shfl_down(aw, 16, 64);
    if (lane < 16) {
        float inv = 1.0f / (den + 1e-16f);
        float4 b4 = ((const float4*)bias)[li];
        uint2 hv;
        hv.x = pack_bf2(fmaxf(ax * inv + b4.x, 0.0f), fmaxf(ay * inv + b4.y, 0.0f));
        hv.y = pack_bf2(fmaxf(az * inv + b4.z, 0.0f), fmaxf(aw * inv + b4.w, 0.0f));
        ((uint2*)(hb + (size_t)node * HD))[li] = hv;
    }
}

// ---------- K6: u1(bf16)=h@W1a, u2b(bf16)=h@W1b + b1 — h bf16 ----------
__global__ __launch_bounds__(256) void k_umm(const unsigned short* __restrict__ hb,
                                             const float* __restrict__ w1,
                                             const float* __restrict__ b1,
                                             __hip_bfloat16* __restrict__ u1b,
                                             __hip_bfloat16* __restrict__ u2b) {
    __shared__ unsigned short hr[NPB * HD];   // 4 KB bf16 tile
    int t = threadIdx.x;
    int j = t & 63, wv = t >> 6;
    float4 wa[HD / 4], wb[HD / 4];     // 128 VGPRs
#pragma unroll
    for (int kk = 0; kk < HD / 4; ++kk) {
        wa[kk].x = w1[(4 * kk + 0) * HD + j];
        wa[kk].y = w1[(4 * kk + 1) * HD + j];
        wa[kk].z = w1[(4 * kk + 2) * HD + j];
        wa[kk].w = w1[(4 * kk + 3) * HD + j];
        wb[kk].x = w1[(HD + 4 * kk + 0) * HD + j];
        wb[kk].y = w1[(HD + 4 * kk + 1) * HD + j];
        wb[kk].z = w1[(HD + 4 * kk + 2) * HD + j];
        wb[kk].w = w1[(HD + 4 * kk + 3) * HD + j];
    }
    float b1j = b1[j];
    int n0 = blockIdx.x * NPB;
    ((uint4*)hr)[t] = ((const uint4*)(hb + (size_t)n0 * HD))[t];   // 4KB exact
    __syncthreads();
    for (int n = wv; n < NPB; n += 4) {
        const uint2* hx = (const uint2*)&hr[n * HD];
        float a1 = 0.0f, a2 = 0.0f;
#pragma unroll
        for (int kk = 0; kk < HD / 4; ++kk) {
            uint2 hv = hx[kk];   // broadcast ds_read_b64: 4 bf16
            float h0 = bf_lo(hv.x), h1 = bf_hi(hv.x), h2 = bf_lo(hv.y), h3 = bf_hi(hv.y);
            a1 += h0 * wa[kk].x + h1 * wa[kk].y + h2 * wa[kk].z + h3 * wa[kk].w;
            a2 += h0 * wb[kk].x + h1 * wb[kk].y + h2 * wb[kk].z + h3 * wb[kk].w;
        }
        int node = n0 + n;
        u1b[(size_t)node * HD + j] = __float2bfloat16(a1);
        u2b[(size_t)node * HD + j] = __float2bfloat16(a2 + b1j);
    }
}

// ---------- K7: edge-order decode — r7: latency-bound (HBM 36%, occ 75%).
// Widened to 64 edges/block: 4 edges per 16-lane group = 8 independent 128B
// row-gathers in flight per group (was 4) — doubles outstanding misses at
// identical traffic. out writes stay coalesced. ----------
__global__ __launch_bounds__(256) void k_decode_edge(const int* __restrict__ src,
                                                     const int* __restrict__ dst,
                                                     const uint2* __restrict__ u1r,
                                                     const uint2* __restrict__ u2r,
                                                     const float* __restrict__ w2,
                                                     const float* __restrict__ b2,
                                                     float* __restrict__ out) {
    __shared__ int sld[2 * DEC_EPB];
    int t = threadIdx.x;
    int e0 = blockIdx.x * DEC_EPB;       // grid exact: E/64 blocks
    if (t < DEC_EPB) sld[t] = src[e0 + t];
    else if (t < 2 * DEC_EPB) sld[t] = dst[e0 + t - DEC_EPB];
    __syncthreads();
    int g = t >> 4, li = t & 15;         // 16 groups of 16 lanes, 4 edges/group
    float4 w4 = ((const float4*)w2)[li];
    float bb = b2[0];
    int s0 = sld[g], s1 = sld[g + 16], s2 = sld[g + 32], s3 = sld[g + 48];
    int d0 = sld[DEC_EPB + g],      d1 = sld[DEC_EPB + g + 16];
    int d2 = sld[DEC_EPB + g + 32], d3 = sld[DEC_EPB + g + 48];
    // 8 independent row gathers, issued back-to-back
    uint2 ua = u1r[(size_t)s0 * 16 + li];
    uint2 ub = u1r[(size_t)s1 * 16 + li];
    uint2 uc = u1r[(size_t)s2 * 16 + li];
    uint2 ud = u1r[(size_t)s3 * 16 + li];
    uint2 va = u2r[(size_t)d0 * 16 + li];
    uint2 vb = u2r[(size_t)d1 * 16 + li];
    uint2 vc = u2r[(size_t)d2 * 16 + li];
    uint2 vd = u2r[(size_t)d3 * 16 + li];
    float p0 = fmaxf(bf_lo(ua.x) + bf_lo(va.x), 0.0f) * w4.x
             + fmaxf(bf_hi(ua.x) + bf_hi(va.x), 0.0f) * w4.y
             + fmaxf(bf_lo(ua.y) + bf_lo(va.y), 0.0f) * w4.z
             + fmaxf(bf_hi(ua.y) + bf_hi(va.y), 0.0f) * w4.w;
    float p1 = fmaxf(bf_lo(ub.x) + bf_lo(vb.x), 0.0f) * w4.x
             + fmaxf(bf_hi(ub.x) + bf_hi(vb.x), 0.0f) * w4.y
             + fmaxf(bf_lo(ub.y) + bf_lo(vb.y), 0.0f) * w4.z
             + fmaxf(bf_hi(ub.y) + bf_hi(vb.y), 0.0f) * w4.w;
    float p2 = fmaxf(bf_lo(uc.x) + bf_lo(vc.x), 0.0f) * w4.x
             + fmaxf(bf_hi(uc.x) + bf_hi(vc.x), 0.0f) * w4.y
             + fmaxf(bf_lo(uc.y) + bf_lo(vc.y), 0.0f) * w4.z
             + fmaxf(bf_hi(uc.y) + bf_hi(vc.y), 0.0f) * w4.w;
    float p3 = fmaxf(bf_lo(ud.x) + bf_lo(vd.x), 0.0f) * w4.x
             + fmaxf(bf_hi(ud.x) + bf_hi(vd.x), 0.0f) * w4.y
             + fmaxf(bf_lo(ud.y) + bf_lo(vd.y), 0.0f) * w4.z
             + fmaxf(bf_hi(ud.y) + bf_hi(vd.y), 0.0f) * w4.w;
#pragma unroll
    for (int off = 8; off > 0; off >>= 1) {
        p0 += __shfl_down(p0, off, 16);
        p1 += __shfl_down(p1, off, 16);
        p2 += __shfl_down(p2, off, 16);
        p3 += __shfl_down(p3, off, 16);
    }
    if (li == 0) {
        out[e0 + g]      = 1.0f / (1.0f + __expf(-(p0 + bb)));
        out[e0 + 16 + g] = 1.0f / (1.0f + __expf(-(p1 + bb)));
        out[e0 + 32 + g] = 1.0f / (1.0f + __expf(-(p2 + bb)));
        out[e0 + 48 + g] = 1.0f / (1.0f + __expf(-(p3 + bb)));
    }
}

extern "C" void kernel_launch(void* const* d_in, const int* in_sizes, int n_in,
                              void* d_out, int out_size, void* d_ws, size_t ws_size,
                              hipStream_t stream) {
    const float* x        = (const float*)d_in[0];
    const int*   eidx     = (const int*)d_in[1];
    const float* eattr    = (const float*)d_in[2];
    const float* enc_w    = (const float*)d_in[3];
    const float* enc_b    = (const float*)d_in[4];
    const float* gat_w    = (const float*)d_in[5];
    const float* att_src  = (const float*)d_in[6];
    const float* att_dst  = (const float*)d_in[7];
    const float* edge_w   = (const float*)d_in[8];
    const float* att_edge = (const float*)d_in[9];
    const float* gat_b    = (const float*)d_in[10];
    const float* lp_w1    = (const float*)d_in[11];
    const float* lp_b1    = (const float*)d_in[12];
    const float* lp_w2    = (const float*)d_in[13];
    const float* lp_b2    = (const float*)d_in[14];
    float* out = (float*)d_out;

    const int* src = eidx;
    const int* dst = eidx + N_EDGES;

    // ---- workspace layout (bytes) ----
    // [0, 14.4MB):  bkt (8B records; live edterm->sort_build)
    //               hb bf16 N*HD = 12.8MB (live aggregate<0> -> umm) aliases it
    // [14.4, 27.2): xpb bf16 N*HD (u1b after umm)
    // [27.2, 40.8): agg E_SL int2 (u2b bf16 after umm — agg dead post agg<1>)
    // [40.8, ...):  small arrays
    char* wsb = (char*)d_ws;
    uint*   bkt = (uint*)wsb;                               // NBKT*BKT_CAP*8B = 14.4MB
    unsigned short* hb = (unsigned short*)wsb;              // N*HD bf16 (12.8MB)
    __hip_bfloat16* xpb = (__hip_bfloat16*)(wsb + (size_t)NBKT * BKT_CAP * 8);
    int2*   agg = (int2*)((char*)xpb + (size_t)N_NODES * HD * 2);   // 13.6MB
    float*  fsmall    = (float*)(agg + E_SL);
    float*  s_src     = fsmall;                             // N
    float*  s_dst     = s_src + N_NODES;                    // N
    float*  partials  = s_dst + N_NODES;                    // PART_CH*8 (20000)
    float*  we_vec    = partials + PART_CH * 8;             // 16
    uint*   ltp       = (uint*)(we_vec + 16);               // 1
    float*  Wc        = (float*)(ltp + 1);                  // 32*64
    float*  bc        = Wc + F_INN * HD;                    // 64
    int*    row_ptr   = (int*)(bc + HD);                    // N+1
    int*    bkt_pos   = row_ptr + N_NODES + 1;              // NBKT
    int*    bktbase   = bkt_pos + NBKT;                     // NBKT

    const int NB_AGG  = N_NODES / 4;             // 25000
    const int NB_DENSE = N_NODES / NPB;          // 3125
    const int NB_DEC  = N_EDGES / DEC_EPB;       // 25000

    // merged setup (we_vec + Wc/bc + counter zero) then fused edge pass
    k_setup<<<1, 256, 0, stream>>>(edge_w, att_edge, enc_w, enc_b, gat_w,
                                   we_vec, Wc, bc, bkt_pos);
    k_mean_edterm<<<ME_BLOCKS, 256, 0, stream>>>(eattr, src, dst, we_vec,
                                                 partials, bkt, bkt_pos);
    k_finalize<<<1, 256, 0, stream>>>(partials, we_vec, bkt_pos, ltp, bktbase, row_ptr);

    // per-bucket LDS counting sort -> CSR agg records + row_ptr
    k_sort_build<<<NBKT, SB_THREADS, 0, stream>>>(bkt_pos, bkt, bktbase, ltp,
                                                  agg, row_ptr);

    // layer-0 projection (encoder folded into Wc/bc)
    k_xp0<<<NB_DENSE, 256, 0, stream>>>(x, Wc, bc, att_src, att_dst, xpb, s_src, s_dst);
    k_aggregate<0><<<NB_AGG, 256, 0, stream>>>(row_ptr, agg, s_src, s_dst,
                                               (const uint2*)xpb, gat_b, hb);
    // GAT layer 1
    k_xp<<<NB_DENSE, 256, 0, stream>>>(hb, gat_w + HD * HD, att_src + HD, att_dst + HD,
                                       xpb, s_src, s_dst);
    k_aggregate<1><<<NB_AGG, 256, 0, stream>>>(row_ptr, agg, s_src, s_dst,
                                               (const uint2*)xpb, gat_b + HD, hb);

    // decoder: u1b -> xpb buffer, u2b(+b1) -> agg buffer (both dead by now);
    // decode in ORIGINAL edge order (coalesced out)
    k_umm<<<NB_DENSE, 256, 0, stream>>>(hb, lp_w1, lp_b1, xpb,
                                        (__hip_bfloat16*)agg);
    k_decode_edge<<<NB_DEC, 256, 0, stream>>>(src, dst, (const uint2*)xpb,
                                              (const uint2*)agg, lp_w2, lp_b2, out);
}

// Round 9
// 443.583 us; speedup vs baseline: 1.4210x; 1.0085x over previous
//
#include <hip/hip_runtime.h>
#include <hip/hip_bf16.h>
#include <math.h>

#define N_NODES 100000
#define N_EDGES 1600000
#define F_INN   32
#define F_EE    8
#define HD      64
#define E_SL    (N_EDGES + N_NODES)   // edges + self loops
#define NEG_SLOPE 0.2f
#define NPB 32                        // nodes per block in dense kernels (3125 blocks)

// dst-range bucketing fused into the edge pass. 250 buckets of 400 nodes.
// 8B records {src|dl<<17, pack}; LDS-sorted per block, flushed wave-contiguous.
#define NBKT 250
#define BKT_W (N_NODES / NBKT)        // 400 nodes per bucket
#define BKT_CAP 7200                  // mean 6400 + 10 sigma — overflow prob ~1e-13
#define ME_UNR 10
#define ME_CHUNK (256 * ME_UNR)       // 2560 edges per block
#define ME_BLOCKS (N_EDGES / ME_CHUNK)   // 625
#define PART_CH (ME_BLOCKS * 4)       // 2500 wave partials
#define SB_THREADS 512
#define SEL_CAP (BKT_CAP + BKT_W)     // 7600
#define DEC_EPB 128                   // decode: 128 edges/block, 8 per 16-lane group

// ---------- helpers ----------
__device__ __forceinline__ float waveReduceSum(float v) {
#pragma unroll
    for (int off = 32; off > 0; off >>= 1) v += __shfl_down(v, off, 64);
    return v;
}
__device__ __forceinline__ float bf_lo(uint u) { return __uint_as_float(u << 16); }
__device__ __forceinline__ float bf_hi(uint u) { return __uint_as_float(u & 0xffff0000u); }
__device__ __forceinline__ uint pack_bf2(float a, float b) {
    __hip_bfloat16 ha = __float2bfloat16(a), hb = __float2bfloat16(b);
    unsigned short ua, ub;
    __builtin_memcpy(&ua, &ha, 2); __builtin_memcpy(&ub, &hb, 2);
    return (uint)ua | ((uint)ub << 16);
}

// ---------- K1: merged setup — we_vec, Wc/bc fold, bucket-counter zero ----------
__global__ __launch_bounds__(256) void k_setup(const float* __restrict__ edge_w,
                                               const float* __restrict__ att_edge,
                                               const float* __restrict__ enc_w,
                                               const float* __restrict__ enc_b,
                                               const float* __restrict__ W0,
                                               float* __restrict__ we_vec,
                                               float* __restrict__ Wc, float* __restrict__ bc,
                                               int* __restrict__ bkt_pos) {
    int t = threadIdx.x;
    if (t < 16) {
        int l = t >> 3, k = t & 7;
        const float* We = edge_w + l * F_EE * HD + k * HD;
        const float* ae = att_edge + l * HD;
        float s = 0.0f;
#pragma unroll
        for (int j = 0; j < HD; ++j) s += We[j] * ae[j];
        we_vec[l * 8 + k] = s;
    }
    for (int idx = t; idx < F_INN * HD; idx += 256) {
        int r = idx >> 6, c = idx & 63;
        float s = 0.0f;
#pragma unroll
        for (int k = 0; k < HD; ++k) s += enc_w[r * HD + k] * W0[k * HD + c];
        Wc[idx] = s;
    }
    if (t < HD) {
        float s = 0.0f;
#pragma unroll
        for (int k = 0; k < HD; ++k) s += enc_b[k] * W0[k * HD + t];
        bc[t] = s;
    }
    if (t < NBKT) bkt_pos[t] = 0;
}

// ---------- K2a: fused — mean partials, edge-term compute, LDS-sorted bucket flush ----------
__global__ __launch_bounds__(256) void k_mean_edterm(const float* __restrict__ eattr,
                                                     const int* __restrict__ src,
                                                     const int* __restrict__ dst,
                                                     const float* __restrict__ we_vec,
                                                     float* __restrict__ partials,
                                                     uint* __restrict__ bkt,
                                                     int* __restrict__ bkt_pos) {
    __shared__ float sw[16];
    __shared__ int hist[NBKT];     // count, then LDS cursor, then chunk size
    __shared__ int lstart[256];    // scan array -> exclusive LDS record offsets
    __shared__ int gstart[NBKT];   // reserved global record offsets
    __shared__ uint recs[ME_CHUNK * 2];   // 20 KB staged 8B records
    int t = threadIdx.x;
    if (t < 16) sw[t] = we_vec[t];
    if (t < NBKT) hist[t] = 0;
    __syncthreads();
    float p[8];
#pragma unroll
    for (int k = 0; k < 8; ++k) p[k] = 0.0f;
    int e0 = blockIdx.x * ME_CHUNK;
    int rs[ME_UNR]; uint rp[ME_UNR]; int rb[ME_UNR];   // rb = (bucket<<16)|d_local
#pragma unroll
    for (int u = 0; u < ME_UNR; ++u) {
        int e = e0 + u * 256 + t;
        const float4* row = (const float4*)(eattr + (size_t)e * F_EE);
        float4 r0 = row[0], r1 = row[1];
        p[0] += r0.x; p[1] += r0.y; p[2] += r0.z; p[3] += r0.w;
        p[4] += r1.x; p[5] += r1.y; p[6] += r1.z; p[7] += r1.w;
        float ed0 = r0.x * sw[0] + r0.y * sw[1] + r0.z * sw[2] + r0.w * sw[3]
                  + r1.x * sw[4] + r1.y * sw[5] + r1.z * sw[6] + r1.w * sw[7];
        float ed1 = r0.x * sw[8] + r0.y * sw[9] + r0.z * sw[10] + r0.w * sw[11]
                  + r1.x * sw[12] + r1.y * sw[13] + r1.z * sw[14] + r1.w * sw[15];
        rs[u] = src[e];
        rp[u] = pack_bf2(ed0, ed1);
        int d = dst[e];
        int b = d / BKT_W;
        rb[u] = (b << 16) | (d - b * BKT_W);
        atomicAdd(&hist[b], 1);
    }
    __syncthreads();
    // exclusive scan of per-bucket counts -> LDS chunk offsets
    lstart[t] = (t < NBKT) ? hist[t] : 0;
    __syncthreads();
    for (int off = 1; off < 256; off <<= 1) {
        int x = (t >= off) ? lstart[t - off] : 0;
        __syncthreads();
        lstart[t] += x;
        __syncthreads();
    }
    if (t < NBKT) {
        int v = hist[t];
        gstart[t] = atomicAdd(&bkt_pos[t], v);   // exact reservation, no padding
        lstart[t] -= v;                          // inclusive -> exclusive
        hist[t] = 0;                             // reuse as placement cursor
    }
    __syncthreads();
    // place records bucket-sorted into LDS: 8B record = {src | dl<<17, pack}
#pragma unroll
    for (int u = 0; u < ME_UNR; ++u) {
        int b = rb[u] >> 16, dl = rb[u] & 0xFFFF;
        int l = atomicAdd(&hist[b], 1);
        ((uint2*)recs)[lstart[b] + l] = make_uint2((uint)rs[u] | ((uint)dl << 17), rp[u]);
    }
    __syncthreads();
    // per-bucket wave-contiguous flush
    int w = t >> 6, lane = t & 63;
    uint2* gb2 = (uint2*)bkt;
    for (int b = w; b < NBKT; b += 4) {
        int n = hist[b];
        int ls = lstart[b];
        int gs = gstart[b];
        for (int off = lane; off < n; off += 64)
            if (gs + off < BKT_CAP)
                gb2[(size_t)b * BKT_CAP + gs + off] = ((const uint2*)recs)[ls + off];
    }
#pragma unroll
    for (int k = 0; k < 8; ++k) p[k] = waveReduceSum(p[k]);
    if ((t & 63) == 0) {
        float* dstp = partials + ((size_t)blockIdx.x * 4 + w) * 8;
#pragma unroll
        for (int k = 0; k < 8; ++k) dstp[k] = p[k];
    }
}

// ---------- K2b: merged finalize — mean finish + bucket-count scan ----------
__global__ __launch_bounds__(256) void k_finalize(const float* __restrict__ partials,
                                                  const float* __restrict__ we_vec,
                                                  const int* __restrict__ bkt_pos,
                                                  uint* __restrict__ ltp,
                                                  int* __restrict__ bktbase,
                                                  int* __restrict__ row_ptr) {
    __shared__ float red[256];
    __shared__ float mean8[8];
    __shared__ float lt[2];
    __shared__ int sd[256];
    int t = threadIdx.x;
    // phase 1: edge_attr mean -> loop terms
    int k = t & 7;
    int chunk = t >> 3;
    float s = 0.0f;
    for (int i = chunk; i < PART_CH; i += 32) s += partials[(size_t)i * 8 + k];
    red[t] = s;
    __syncthreads();
    if (t < 8) {
        float acc = 0.0f;
#pragma unroll
        for (int c = 0; c < 32; ++c) acc += red[c * 8 + t];
        mean8[t] = acc * (1.0f / N_EDGES);
    }
    __syncthreads();
    if (t < 2) {
        float acc = 0.0f;
#pragma unroll
        for (int kk = 0; kk < 8; ++kk) acc += mean8[kk] * we_vec[t * 8 + kk];
        lt[t] = acc;
    }
    __syncthreads();
    if (t == 0) ltp[0] = pack_bf2(lt[0], lt[1]);
    // phase 2: scan bucket counts -> bucket CSR bases
    int v = (t < NBKT) ? min(bkt_pos[t], BKT_CAP) + BKT_W : 0;
    sd[t] = v;
    __syncthreads();
    for (int off = 1; off < 256; off <<= 1) {
        int x = (t >= off) ? sd[t - off] : 0;
        __syncthreads();
        sd[t] += x;
        __syncthreads();
    }
    if (t < NBKT) bktbase[t] = sd[t] - v;
    if (t == 0) row_ptr[N_NODES] = E_SL;
}

// kB: one block per bucket. Counting-sort the bucket's ~6400 8B records in LDS,
// write row_ptr for its 400 nodes, write agg as fully contiguous stream.
__global__ __launch_bounds__(SB_THREADS) void k_sort_build(const int* __restrict__ bkt_pos,
                                                           const uint* __restrict__ bkt,
                                                           const int* __restrict__ bktbase,
                                                           const uint* __restrict__ ltp,
                                                           int2* __restrict__ agg,
                                                           int* __restrict__ row_ptr) {
    __shared__ int S[BKT_W];                 // inclusive scan of per-node counts
    __shared__ int cur[BKT_W];               // hist, then rank cursor
    __shared__ unsigned short sel[SEL_CAP];  // local position -> record idx | selfloop
    int b = blockIdx.x;
    int t = threadIdx.x;
    int cnt = min(bkt_pos[b], BKT_CAP);
    const uint2* bp = (const uint2*)bkt + (size_t)b * BKT_CAP;
    if (t < BKT_W) cur[t] = 0;
    __syncthreads();
    for (int i = t; i < cnt; i += SB_THREADS) {
        uint2 v = bp[i];                     // streams bucket through L2
        atomicAdd(&cur[v.x >> 17], 1);
    }
    __syncthreads();
    if (t < BKT_W) S[t] = cur[t];
    for (int off = 1; off < BKT_W; off <<= 1) {
        __syncthreads();
        int x = (t >= off && t < BKT_W) ? S[t - off] : 0;
        __syncthreads();
        if (t < BKT_W) S[t] += x;
    }
    __syncthreads();
    int n0 = b * BKT_W;
    int gb = bktbase[b];
    if (t < BKT_W) {
        row_ptr[n0 + t] = gb + (t == 0 ? 0 : S[t - 1]) + t;   // excl scan of (cnt+1)
        cur[t] = 0;
        sel[S[t] + t] = (unsigned short)(0x8000 | t);   // self-loop slot (segment end)
    }
    __syncthreads();
    for (int i = t; i < cnt; i += SB_THREADS) {
        int dl = (int)(bp[i].x >> 17);       // L2 re-read
        int r = atomicAdd(&cur[dl], 1);
        int nb = (dl == 0) ? 0 : S[dl - 1];
        sel[nb + dl + r] = (unsigned short)i;
    }
    __syncthreads();
    int total = cnt + BKT_W;
    uint lt = ltp[0];
    for (int p = t; p < total; p += SB_THREADS) {
        unsigned short v = sel[p];
        int2 a;
        if (v & 0x8000) {
            a = make_int2(n0 + (v & 0x7fff), (int)lt);
        } else {
            uint2 r = bp[v];                 // random read within resident bucket
            a = make_int2((int)(r.x & 0x1FFFFu), (int)r.y);
        }
        agg[gb + p] = a;                     // contiguous coalesced stream
    }
}

// ---------- K3: layer-0 projection xp = x@Wc + bc ----------
__global__ __launch_bounds__(256) void k_xp0(const float* __restrict__ x,
                                             const float* __restrict__ Wc,
                                             const float* __restrict__ bc,
                                             const float* __restrict__ a_src,
                                             const float* __restrict__ a_dst,
                                             __hip_bfloat16* __restrict__ xpb,
                                             float* __restrict__ s_src,
                                             float* __restrict__ s_dst) {
    __shared__ float xr[NPB * F_INN];  // 4 KB
    int t = threadIdx.x;
    int j = t & 63, wv = t >> 6;
    float4 w[F_INN / 4];               // 8 VGPR float4s = weight column j
#pragma unroll
    for (int kk = 0; kk < F_INN / 4; ++kk) {
        w[kk].x = Wc[(4 * kk + 0) * HD + j];
        w[kk].y = Wc[(4 * kk + 1) * HD + j];
        w[kk].z = Wc[(4 * kk + 2) * HD + j];
        w[kk].w = Wc[(4 * kk + 3) * HD + j];
    }
    int n0 = blockIdx.x * NPB;
    ((float4*)xr)[t] = ((const float4*)(x + (size_t)n0 * F_INN))[t];  // 4KB exact
    __syncthreads();
    float asj = a_src[j], adj = a_dst[j], bcj = bc[j];
    for (int n = wv; n < NPB; n += 4) {
        const float4* hx = (const float4*)&xr[n * F_INN];
        float acc = bcj;
#pragma unroll
        for (int kk = 0; kk < F_INN / 4; ++kk) {
            float4 hv = hx[kk];   // wave-uniform broadcast ds_read_b128
            acc += hv.x * w[kk].x + hv.y * w[kk].y + hv.z * w[kk].z + hv.w * w[kk].w;
        }
        int node = n0 + n;
        xpb[(size_t)node * HD + j] = __float2bfloat16(acc);
        float ts = waveReduceSum(acc * asj);
        float td = waveReduceSum(acc * adj);
        if (j == 0) { s_src[node] = ts; s_dst[node] = td; }
    }
}

// ---------- K4: xp(bf16) = h @ W (layer 1) — h bf16 ----------
__global__ __launch_bounds__(256) void k_xp(const unsigned short* __restrict__ hb,
                                            const float* __restrict__ W,
                                            const float* __restrict__ a_src, const float* __restrict__ a_dst,
                                            __hip_bfloat16* __restrict__ xpb, float* __restrict__ s_src,
                                            float* __restrict__ s_dst) {
    __shared__ unsigned short hr[NPB * HD];   // 4 KB bf16 tile
    int t = threadIdx.x;
    int j = t & 63, wv = t >> 6;
    float4 w[HD / 4];                  // 16 float4s = 64 VGPRs
#pragma unroll
    for (int kk = 0; kk < HD / 4; ++kk) {
        w[kk].x = W[(4 * kk + 0) * HD + j];
        w[kk].y = W[(4 * kk + 1) * HD + j];
        w[kk].z = W[(4 * kk + 2) * HD + j];
        w[kk].w = W[(4 * kk + 3) * HD + j];
    }
    int n0 = blockIdx.x * NPB;
    ((uint4*)hr)[t] = ((const uint4*)(hb + (size_t)n0 * HD))[t];   // 4KB exact
    __syncthreads();
    float asj = a_src[j], adj = a_dst[j];
    for (int n = wv; n < NPB; n += 4) {
        const uint2* hx = (const uint2*)&hr[n * HD];
        float acc = 0.0f;
#pragma unroll
        for (int kk = 0; kk < HD / 4; ++kk) {
            uint2 hv = hx[kk];   // broadcast ds_read_b64: 4 bf16
            acc += bf_lo(hv.x) * w[kk].x + bf_hi(hv.x) * w[kk].y
                 + bf_lo(hv.y) * w[kk].z + bf_hi(hv.y) * w[kk].w;
        }
        int node = n0 + n;
        xpb[(size_t)node * HD + j] = __float2bfloat16(acc);
        float ts = waveReduceSum(acc * asj);
        float td = waveReduceSum(acc * adj);
        if (j == 0) { s_src[node] = ts; s_dst[node] = td; }
    }
}

// ---------- K5: gather-aggregate — wave/node, 16-lane groups. r8: issue-bound
// (VALU 62%, HBM 25%, FETCH at per-XCD fill floor). This round: tail loop
// flattened to ONE predicated 8-wide pass (remainder after main is always <8;
// deg<8 nodes skip main entirely — they were paying 1-2 serial 4-wide iters),
// and 32-bit gather offsets (drops v_mad_u64 address chains). ----------
template <int LAYER>
__global__ __launch_bounds__(256) void k_aggregate(const int* __restrict__ row_ptr,
                                                   const int2* __restrict__ agg,
                                                   const float* __restrict__ s_src,
                                                   const float* __restrict__ s_dst,
                                                   const uint2* __restrict__ xpr,   // bf16 x4 per lane
                                                   const float* __restrict__ bias,
                                                   unsigned short* __restrict__ hb) {
    int t = threadIdx.x;
    int node = blockIdx.x * 4 + (t >> 6);    // grid exact: N/4
    int lane = t & 63;
    int g = lane >> 4, li = lane & 15;
    int start = row_ptr[node], end = row_ptr[node + 1];
    float sd = s_dst[node];
    float ax = 0.0f, ay = 0.0f, az = 0.0f, aw = 0.0f, den = 0.0f;
    int i = start;
    if (i + 8 <= end) {
        int2 r0 = agg[i + g];
        int2 r1 = agg[i + 4 + g];
        while (true) {
            int ni = i + 8;
            bool more = ni + 8 <= end;
            int2 nr0, nr1;
            if (more) { nr0 = agg[ni + g]; nr1 = agg[ni + 4 + g]; }   // prefetch next records
            int sp0 = r0.x, sp1 = r1.x;
            uint2 u0 = xpr[(uint)(sp0 * 16 + li)];
            uint2 u1 = xpr[(uint)(sp1 * 16 + li)];
            float a0 = s_src[sp0] + sd + (LAYER == 0 ? bf_lo((uint)r0.y) : bf_hi((uint)r0.y));
            float a1 = s_src[sp1] + sd + (LAYER == 0 ? bf_lo((uint)r1.y) : bf_hi((uint)r1.y));
            a0 = a0 > 0.0f ? a0 : NEG_SLOPE * a0;
            a1 = a1 > 0.0f ? a1 : NEG_SLOPE * a1;
            float ex0 = __expf(a0), ex1 = __expf(a1);
            den += ex0 + ex1;
            ax += ex0 * bf_lo(u0.x) + ex1 * bf_lo(u1.x);
            ay += ex0 * bf_hi(u0.x) + ex1 * bf_hi(u1.x);
            az += ex0 * bf_lo(u0.y) + ex1 * bf_lo(u1.y);
            aw += ex0 * bf_hi(u0.y) + ex1 * bf_hi(u1.y);
            i = ni;
            if (!more) break;
            r0 = nr0; r1 = nr1;
        }
    }
    if (i < end) {                           // single predicated 8-wide tail pass
        int idx0 = i + g, idx1 = i + 4 + g;
        bool v0 = idx0 < end, v1 = idx1 < end;
        int2 r0 = agg[v0 ? idx0 : start];
        int2 r1 = agg[v1 ? idx1 : start];
        int sp0 = r0.x, sp1 = r1.x;
        uint2 u0 = xpr[(uint)(sp0 * 16 + li)];
        uint2 u1 = xpr[(uint)(sp1 * 16 + li)];
        float a0 = s_src[sp0] + sd + (LAYER == 0 ? bf_lo((uint)r0.y) : bf_hi((uint)r0.y));
        float a1 = s_src[sp1] + sd + (LAYER == 0 ? bf_lo((uint)r1.y) : bf_hi((uint)r1.y));
        a0 = a0 > 0.0f ? a0 : NEG_SLOPE * a0;
        a1 = a1 > 0.0f ? a1 : NEG_SLOPE * a1;
        float ex0 = v0 ? __expf(a0) : 0.0f;
        float ex1 = v1 ? __expf(a1) : 0.0f;
        den += ex0 + ex1;
        ax += ex0 * bf_lo(u0.x) + ex1 * bf_lo(u1.x);
        ay += ex0 * bf_hi(u0.x) + ex1 * bf_hi(u1.x);
        az += ex0 * bf_lo(u0.y) + ex1 * bf_lo(u1.y);
        aw += ex0 * bf_hi(u0.y) + ex1 * bf_hi(u1.y);
    }
    den += __shfl_down(den, 32, 64); ax += __shfl_down(ax, 32, 64);
    ay  += __shfl_down(ay, 32, 64); az += __shfl_down(az, 32, 64);
    aw  += __shfl_down(aw, 32, 64);
    den += __shfl_down(den, 16, 64); ax += __shfl_down(ax, 16, 64);
    ay  += __shfl_down(ay, 16, 64); az += __shfl_down(az, 16, 64);
    aw  += __shfl_down(aw, 16, 64);
    if (lane < 16) {
        float inv = 1.0f / (den + 1e-16f);
        float4 b4 = ((const float4*)bias)[li];
        uint2 hv;
        hv.x = pack_bf2(fmaxf(ax * inv + b4.x, 0.0f), fmaxf(ay * inv + b4.y, 0.0f));
        hv.y = pack_bf2(fmaxf(az * inv + b4.z, 0.0f), fmaxf(aw * inv + b4.w, 0.0f));
        ((uint2*)(hb + (size_t)node * HD))[li] = hv;
    }
}

// ---------- K6: u1(bf16)=h@W1a, u2b(bf16)=h@W1b + b1 — h bf16 ----------
__global__ __launch_bounds__(256) void k_umm(const unsigned short* __restrict__ hb,
                                             const float* __restrict__ w1,
                                             const float* __restrict__ b1,
                                             __hip_bfloat16* __restrict__ u1b,
                                             __hip_bfloat16* __restrict__ u2b) {
    __shared__ unsigned short hr[NPB * HD];   // 4 KB bf16 tile
    int t = threadIdx.x;
    int j = t & 63, wv = t >> 6;
    float4 wa[HD / 4], wb[HD / 4];     // 128 VGPRs
#pragma unroll
    for (int kk = 0; kk < HD / 4; ++kk) {
        wa[kk].x = w1[(4 * kk + 0) * HD + j];
        wa[kk].y = w1[(4 * kk + 1) * HD + j];
        wa[kk].z = w1[(4 * kk + 2) * HD + j];
        wa[kk].w = w1[(4 * kk + 3) * HD + j];
        wb[kk].x = w1[(HD + 4 * kk + 0) * HD + j];
        wb[kk].y = w1[(HD + 4 * kk + 1) * HD + j];
        wb[kk].z = w1[(HD + 4 * kk + 2) * HD + j];
        wb[kk].w = w1[(HD + 4 * kk + 3) * HD + j];
    }
    float b1j = b1[j];
    int n0 = blockIdx.x * NPB;
    ((uint4*)hr)[t] = ((const uint4*)(hb + (size_t)n0 * HD))[t];   // 4KB exact
    __syncthreads();
    for (int n = wv; n < NPB; n += 4) {
        const uint2* hx = (const uint2*)&hr[n * HD];
        float a1 = 0.0f, a2 = 0.0f;
#pragma unroll
        for (int kk = 0; kk < HD / 4; ++kk) {
            uint2 hv = hx[kk];   // broadcast ds_read_b64: 4 bf16
            float h0 = bf_lo(hv.x), h1 = bf_hi(hv.x), h2 = bf_lo(hv.y), h3 = bf_hi(hv.y);
            a1 += h0 * wa[kk].x + h1 * wa[kk].y + h2 * wa[kk].z + h3 * wa[kk].w;
            a2 += h0 * wb[kk].x + h1 * wb[kk].y + h2 * wb[kk].z + h3 * wb[kk].w;
        }
        int node = n0 + n;
        u1b[(size_t)node * HD + j] = __float2bfloat16(a1);
        u2b[(size_t)node * HD + j] = __float2bfloat16(a2 + b1j);
    }
}

// ---------- K7: edge-order decode — widened again (r8 confirmed the MLP
// lever): 128 edges/block, 8 per 16-lane group = 16 independent 128B
// row-gathers in flight per group. out writes stay coalesced. ----------
__global__ __launch_bounds__(256) void k_decode_edge(const int* __restrict__ src,
                                                     const int* __restrict__ dst,
                                                     const uint2* __restrict__ u1r,
                                                     const uint2* __restrict__ u2r,
                                                     const float* __restrict__ w2,
                                                     const float* __restrict__ b2,
                                                     float* __restrict__ out) {
    __shared__ int sld[2 * DEC_EPB];
    int t = threadIdx.x;
    int e0 = blockIdx.x * DEC_EPB;       // grid exact: E/128 blocks
    sld[t] = (t < DEC_EPB) ? src[e0 + t] : dst[e0 + t - DEC_EPB];
    __syncthreads();
    int g = t >> 4, li = t & 15;         // 16 groups of 16 lanes, 8 edges/group
    float4 w4 = ((const float4*)w2)[li];
    float bb = b2[0];
    uint2 u[8], v[8];
#pragma unroll
    for (int k = 0; k < 8; ++k) {        // 16 independent row gathers back-to-back
        int sk = sld[g + 16 * k];
        int dk = sld[DEC_EPB + g + 16 * k];
        u[k] = u1r[(uint)(sk * 16 + li)];
        v[k] = u2r[(uint)(dk * 16 + li)];
    }
    float p[8];
#pragma unroll
    for (int k = 0; k < 8; ++k) {
        p[k] = fmaxf(bf_lo(u[k].x) + bf_lo(v[k].x), 0.0f) * w4.x
             + fmaxf(bf_hi(u[k].x) + bf_hi(v[k].x), 0.0f) * w4.y
             + fmaxf(bf_lo(u[k].y) + bf_lo(v[k].y), 0.0f) * w4.z
             + fmaxf(bf_hi(u[k].y) + bf_hi(v[k].y), 0.0f) * w4.w;
    }
#pragma unroll
    for (int off = 8; off > 0; off >>= 1) {
#pragma unroll
        for (int k = 0; k < 8; ++k) p[k] += __shfl_down(p[k], off, 16);
    }
    if (li == 0) {
#pragma unroll
        for (int k = 0; k < 8; ++k)
            out[e0 + 16 * k + g] = 1.0f / (1.0f + __expf(-(p[k] + bb)));
    }
}

extern "C" void kernel_launch(void* const* d_in, const int* in_sizes, int n_in,
                              void* d_out, int out_size, void* d_ws, size_t ws_size,
                              hipStream_t stream) {
    const float* x        = (const float*)d_in[0];
    const int*   eidx     = (const int*)d_in[1];
    const float* eattr    = (const float*)d_in[2];
    const float* enc_w    = (const float*)d_in[3];
    const float* enc_b    = (const float*)d_in[4];
    const float* gat_w    = (const float*)d_in[5];
    const float* att_src  = (const float*)d_in[6];
    const float* att_dst  = (const float*)d_in[7];
    const float* edge_w   = (const float*)d_in[8];
    const float* att_edge = (const float*)d_in[9];
    const float* gat_b    = (const float*)d_in[10];
    const float* lp_w1    = (const float*)d_in[11];
    const float* lp_b1    = (const float*)d_in[12];
    const float* lp_w2    = (const float*)d_in[13];
    const float* lp_b2    = (const float*)d_in[14];
    float* out = (float*)d_out;

    const int* src = eidx;
    const int* dst = eidx + N_EDGES;

    // ---- workspace layout (bytes) ----
    // [0, 14.4MB):  bkt (8B records; live edterm->sort_build)
    //               hb bf16 N*HD = 12.8MB (live aggregate<0> -> umm) aliases it
    // [14.4, 27.2): xpb bf16 N*HD (u1b after umm)
    // [27.2, 40.8): agg E_SL int2 (u2b bf16 after umm — agg dead post agg<1>)
    // [40.8, ...):  small arrays
    char* wsb = (char*)d_ws;
    uint*   bkt = (uint*)wsb;                               // NBKT*BKT_CAP*8B = 14.4MB
    unsigned short* hb = (unsigned short*)wsb;              // N*HD bf16 (12.8MB)
    __hip_bfloat16* xpb = (__hip_bfloat16*)(wsb + (size_t)NBKT * BKT_CAP * 8);
    int2*   agg = (int2*)((char*)xpb + (size_t)N_NODES * HD * 2);   // 13.6MB
    float*  fsmall    = (float*)(agg + E_SL);
    float*  s_src     = fsmall;                             // N
    float*  s_dst     = s_src + N_NODES;                    // N
    float*  partials  = s_dst + N_NODES;                    // PART_CH*8 (20000)
    float*  we_vec    = partials + PART_CH * 8;             // 16
    uint*   ltp       = (uint*)(we_vec + 16);               // 1
    float*  Wc        = (float*)(ltp + 1);                  // 32*64
    float*  bc        = Wc + F_INN * HD;                    // 64
    int*    row_ptr   = (int*)(bc + HD);                    // N+1
    int*    bkt_pos   = row_ptr + N_NODES + 1;              // NBKT
    int*    bktbase   = bkt_pos + NBKT;                     // NBKT

    const int NB_AGG  = N_NODES / 4;             // 25000
    const int NB_DENSE = N_NODES / NPB;          // 3125
    const int NB_DEC  = N_EDGES / DEC_EPB;       // 12500

    // merged setup (we_vec + Wc/bc + counter zero) then fused edge pass
    k_setup<<<1, 256, 0, stream>>>(edge_w, att_edge, enc_w, enc_b, gat_w,
                                   we_vec, Wc, bc, bkt_pos);
    k_mean_edterm<<<ME_BLOCKS, 256, 0, stream>>>(eattr, src, dst, we_vec,
                                                 partials, bkt, bkt_pos);
    k_finalize<<<1, 256, 0, stream>>>(partials, we_vec, bkt_pos, ltp, bktbase, row_ptr);

    // per-bucket LDS counting sort -> CSR agg records + row_ptr
    k_sort_build<<<NBKT, SB_THREADS, 0, stream>>>(bkt_pos, bkt, bktbase, ltp,
                                                  agg, row_ptr);

    // layer-0 projection (encoder folded into Wc/bc)
    k_xp0<<<NB_DENSE, 256, 0, stream>>>(x, Wc, bc, att_src, att_dst, xpb, s_src, s_dst);
    k_aggregate<0><<<NB_AGG, 256, 0, stream>>>(row_ptr, agg, s_src, s_dst,
                                               (const uint2*)xpb, gat_b, hb);
    // GAT layer 1
    k_xp<<<NB_DENSE, 256, 0, stream>>>(hb, gat_w + HD * HD, att_src + HD, att_dst + HD,
                                       xpb, s_src, s_dst);
    k_aggregate<1><<<NB_AGG, 256, 0, stream>>>(row_ptr, agg, s_src, s_dst,
                                               (const uint2*)xpb, gat_b + HD, hb);

    // decoder: u1b -> xpb buffer, u2b(+b1) -> agg buffer (both dead by now);
    // decode in ORIGINAL edge order (coalesced out)
    k_umm<<<NB_DENSE, 256, 0, stream>>>(hb, lp_w1, lp_b1, xpb,
                                        (__hip_bfloat16*)agg);
    k_decode_edge<<<NB_DEC, 256, 0, stream>>>(src, dst, (const uint2*)xpb,
                                              (const uint2*)agg, lp_w2, lp_b2, out);
}